// Round 1
// baseline (1695.241 us; speedup 1.0000x reference)
//
#include <hip/hip_runtime.h>
#include <math.h>

#define EPS_LN 1e-6f
#define EPS_BN 1e-5f

__device__ __forceinline__ float wave_reduce_sum(float v) {
    #pragma unroll
    for (int m = 32; m >= 1; m >>= 1) v += __shfl_xor(v, m, 64);
    return v;
}
__device__ __forceinline__ float wave_reduce_max(float v) {
    #pragma unroll
    for (int m = 32; m >= 1; m >>= 1) v = fmaxf(v, __shfl_xor(v, m, 64));
    return v;
}

// ---------------- patch embed: dw3x3 s2 + pw 64->128 + BN(d) + hardswish ----
// grid 512 = (b*64 + y), block 256. out t1 image layout (B,128,4096)
__global__ __launch_bounds__(256) void pe_kernel(
    const float* __restrict__ img, const float* __restrict__ dww,
    const float* __restrict__ pww, const float* __restrict__ bn_g,
    const float* __restrict__ bn_b, const float* __restrict__ bn_m,
    const float* __restrict__ bn_v, const int* __restrict__ dptr,
    float* __restrict__ t1) {
    __shared__ float dw[64 * 65];
    int bx = blockIdx.x;
    int b = bx >> 6, y = bx & 63;
    int tid = threadIdx.x;
    int d = *dptr;
    for (int idx = tid; idx < 4096; idx += 256) {
        int ci = idx >> 6, xx = idx & 63;
        const float* ip = img + (size_t)(b * 64 + ci) * 128 * 128;
        float acc = 0.f;
        #pragma unroll
        for (int r = 0; r < 3; ++r) {
            int iy = 2 * y + r;           // pad_lo = 0, pad_hi = 1 (SAME, s=2)
            if (iy >= 128) continue;
            #pragma unroll
            for (int s = 0; s < 3; ++s) {
                int ix = 2 * xx + s;
                if (ix >= 128) continue;
                acc += ip[iy * 128 + ix] * dww[ci * 9 + r * 3 + s];
            }
        }
        dw[ci * 65 + xx] = acc;
    }
    __syncthreads();
    for (int idx = tid; idx < 8192; idx += 256) {
        int co = idx >> 6, xx = idx & 63;
        float acc = 0.f;
        const float* wp = pww + co * 64;
        for (int ci = 0; ci < 64; ++ci)
            acc += dw[ci * 65 + xx] * wp[ci];
        float sc = bn_g[d * 128 + co] * rsqrtf(bn_v[d * 128 + co] + EPS_BN);
        float v = (acc - bn_m[d * 128 + co]) * sc + bn_b[d * 128 + co];
        v = v * fminf(fmaxf(v + 3.f, 0.f), 6.f) * (1.f / 6.f);
        t1[(size_t)(b * 128 + co) * 4096 + y * 64 + xx] = v;
    }
}

// ---------------- ConvPosEnc: x_tok = t1 + dw3x3(t1) + bias ----------------
// grid 2048 = ((b*64+y)*4 + cq), block 256. out x token layout (B,N,128)
__global__ __launch_bounds__(256) void cpe_kernel(
    const float* __restrict__ t1, const float* __restrict__ cw,
    const float* __restrict__ cb, float* __restrict__ xout) {
    int bx = blockIdx.x;
    int cq = bx & 3, y = (bx >> 2) & 63, b = bx >> 8;
    int c0 = cq * 32;
    __shared__ float s[3 * 32 * 65];
    int tid = threadIdx.x;
    for (int idx = tid; idx < 3 * 32 * 64; idx += 256) {
        int xx = idx & 63;
        int cl = (idx >> 6) & 31;
        int dy = idx >> 11;
        int yy = y + dy - 1;
        float v = 0.f;
        if (yy >= 0 && yy < 64)
            v = t1[(size_t)(b * 128 + c0 + cl) * 4096 + yy * 64 + xx];
        s[(dy * 32 + cl) * 65 + xx] = v;
    }
    __syncthreads();
    for (int idx = tid; idx < 32 * 64; idx += 256) {
        int cl = idx & 31;       // c fastest -> coalesced writes
        int xx = idx >> 5;
        int c = c0 + cl;
        float center = s[(32 + cl) * 65 + xx];
        float acc = cb[c];
        #pragma unroll
        for (int dy = 0; dy < 3; ++dy) {
            #pragma unroll
            for (int dx = 0; dx < 3; ++dx) {
                int sx = xx + dx - 1;
                if (sx < 0 || sx >= 64) continue;
                acc += s[(dy * 32 + cl) * 65 + sx] * cw[c * 9 + dy * 3 + dx];
            }
        }
        xout[(size_t)(b * 4096 + y * 64 + xx) * 128 + c] = center + acc;
    }
}

// ---------------- LayerNorm over C=128 with domain params ------------------
// grid 8192, block 256 (4 waves, 1 token per wave)
__global__ __launch_bounds__(256) void ln_kernel(
    const float* __restrict__ src, float* __restrict__ dst,
    const float* __restrict__ g, const float* __restrict__ bb,
    const int* __restrict__ dptr) {
    int d = *dptr;
    int wid = threadIdx.x >> 6, lane = threadIdx.x & 63;
    size_t t = (size_t)blockIdx.x * 4 + wid;
    const float* p = src + t * 128;
    float v0 = p[lane], v1 = p[lane + 64];
    float mean = wave_reduce_sum(v0 + v1) * (1.f / 128.f);
    float d0 = v0 - mean, d1 = v1 - mean;
    float var = wave_reduce_sum(d0 * d0 + d1 * d1) * (1.f / 128.f);
    float rs = rsqrtf(var + EPS_LN);
    dst[t * 128 + lane]      = d0 * rs * g[d * 128 + lane]      + bb[d * 128 + lane];
    dst[t * 128 + lane + 64] = d1 * rs * g[d * 128 + lane + 64] + bb[d * 128 + lane + 64];
}

// ---------------- QKV GEMM: cur(32768x128) @ W(128x384) + b ----------------
// grid (1024, 3), block 256. q -> token layout; k,v -> image layout (transpose via LDS)
__global__ __launch_bounds__(256) void qkv_kernel(
    const float* __restrict__ A, const float* __restrict__ W,
    const float* __restrict__ bias, float* __restrict__ q,
    float* __restrict__ k_img, float* __restrict__ v_img) {
    __shared__ float sm[32 * 130];
    int tb = blockIdx.x * 32;
    int cblk = blockIdx.y;
    int jb = cblk * 128;
    int tid = threadIdx.x;
    for (int idx = tid; idx < 4096; idx += 256) {
        int t = idx >> 7, k = idx & 127;
        sm[t * 130 + k] = A[(size_t)(tb + t) * 128 + k];
    }
    __syncthreads();
    int j = tid & 127, half = tid >> 7;
    float acc[16];
    #pragma unroll
    for (int i = 0; i < 16; ++i) acc[i] = 0.f;
    for (int k = 0; k < 128; ++k) {
        float w = W[k * 384 + jb + j];
        #pragma unroll
        for (int i = 0; i < 16; ++i)
            acc[i] += sm[(half * 16 + i) * 130 + k] * w;
    }
    float bj = bias[jb + j];
    #pragma unroll
    for (int i = 0; i < 16; ++i) acc[i] += bj;
    if (cblk == 0) {
        #pragma unroll
        for (int i = 0; i < 16; ++i)
            q[(size_t)(tb + half * 16 + i) * 128 + j] = acc[i];
    } else {
        __syncthreads();
        #pragma unroll
        for (int i = 0; i < 16; ++i)
            sm[(half * 16 + i) * 130 + j] = acc[i];
        __syncthreads();
        float* dst = (cblk == 1) ? k_img : v_img;
        int b = tb >> 12;
        int nb = tb & 4095;
        #pragma unroll
        for (int it = 0; it < 16; ++it) {
            int c = it * 8 + (tid >> 5);
            int noff = tid & 31;
            dst[(size_t)(b * 128 + c) * 4096 + nb + noff] = sm[noff * 130 + c];
        }
    }
}

// ---------------- softmax over N for each (b,c) row of k_img ---------------
__global__ __launch_bounds__(256) void softmax_kernel(float* __restrict__ k_img) {
    __shared__ float red[4];
    float* p = k_img + (size_t)blockIdx.x * 4096;
    int tid = threadIdx.x;
    float v[16];
    float mx = -1e30f;
    #pragma unroll
    for (int i = 0; i < 16; ++i) {
        v[i] = p[tid + i * 256];
        mx = fmaxf(mx, v[i]);
    }
    mx = wave_reduce_max(mx);
    int wid = tid >> 6, lane = tid & 63;
    if (lane == 0) red[wid] = mx;
    __syncthreads();
    mx = fmaxf(fmaxf(red[0], red[1]), fmaxf(red[2], red[3]));
    __syncthreads();
    float sum = 0.f;
    #pragma unroll
    for (int i = 0; i < 16; ++i) {
        v[i] = expf(v[i] - mx);
        sum += v[i];
    }
    sum = wave_reduce_sum(sum);
    if (lane == 0) red[wid] = sum;
    __syncthreads();
    float inv = 1.f / (red[0] + red[1] + red[2] + red[3]);
    #pragma unroll
    for (int i = 0; i < 16; ++i)
        p[tid + i * 256] = v[i] * inv;
}

// ---------------- kv[b,h,ck,cv] = sum_n k_sm * v ---------------------------
// grid 64 (b*8+h), block 256 = (ck,cv)
__global__ __launch_bounds__(256) void kv_kernel(
    const float* __restrict__ k_img, const float* __restrict__ v_img,
    float* __restrict__ kv) {
    __shared__ float ks[16 * 132], vs[16 * 132];
    int bh = blockIdx.x;
    int b = bh >> 3, h = bh & 7;
    int tid = threadIdx.x;
    int ck = tid >> 4, cv = tid & 15;
    float acc = 0.f;
    const float* kp = k_img + (size_t)(b * 128 + h * 16) * 4096;
    const float* vp = v_img + (size_t)(b * 128 + h * 16) * 4096;
    for (int nb = 0; nb < 4096; nb += 128) {
        for (int idx = tid; idx < 2048; idx += 256) {
            int r = idx >> 7, col = idx & 127;
            ks[r * 132 + col] = kp[(size_t)r * 4096 + nb + col];
            vs[r * 132 + col] = vp[(size_t)r * 4096 + nb + col];
        }
        __syncthreads();
        for (int kk = 0; kk < 128; ++kk)
            acc += ks[ck * 132 + kk] * vs[cv * 132 + kk];
        __syncthreads();
    }
    kv[(size_t)bh * 256 + ck * 16 + cv] = acc;
}

// ---------------- domain gate -> da (B,128) --------------------------------
__global__ __launch_bounds__(256) void gate_kernel(
    const float* __restrict__ dl, const float* __restrict__ w1,
    const float* __restrict__ b1, const float* __restrict__ w2,
    const float* __restrict__ b2, float* __restrict__ da) {
    __shared__ float hid[512];
    __shared__ float raw[1024];
    int tid = threadIdx.x;
    for (int idx = tid; idx < 512; idx += 256) {
        int b = idx >> 6, jj = idx & 63;
        float a = b1[jj];
        #pragma unroll
        for (int dd = 0; dd < 4; ++dd)
            a += dl[b * 4 + dd] * w1[dd * 64 + jj];
        hid[idx] = fmaxf(a, 0.f);
    }
    __syncthreads();
    for (int idx = tid; idx < 1024; idx += 256) {
        int b = idx >> 7, c = idx & 127;
        float a = b2[c];
        for (int jj = 0; jj < 64; ++jj)
            a += hid[b * 64 + jj] * w2[jj * 128 + c];
        raw[idx] = a;
    }
    __syncthreads();
    if (tid < 128) {
        int b = tid >> 4, ch = tid & 15;
        float mx = -1e30f;
        #pragma unroll
        for (int hh = 0; hh < 8; ++hh)
            mx = fmaxf(mx, raw[b * 128 + hh * 16 + ch]);
        float e[8];
        float s = 0.f;
        #pragma unroll
        for (int hh = 0; hh < 8; ++hh) {
            e[hh] = expf(raw[b * 128 + hh * 16 + ch] - mx);
            s += e[hh];
        }
        float inv = 1.f / s;
        #pragma unroll
        for (int hh = 0; hh < 8; ++hh)
            da[b * 128 + hh * 16 + ch] = e[hh] * inv;
    }
}

// ---------------- crpe conv + factor-att combine -> att image layout -------
// grid 1024 = (b*128+c), block 256
__global__ __launch_bounds__(256) void att_kernel(
    const float* __restrict__ q, const float* __restrict__ v_img,
    const float* __restrict__ kv, const float* __restrict__ da,
    const float* __restrict__ w3, const float* __restrict__ b3,
    const float* __restrict__ w5, const float* __restrict__ b5,
    const float* __restrict__ w7, const float* __restrict__ b7,
    float* __restrict__ att) {
    __shared__ float s[64 * 65];
    __shared__ float wsm[49];
    int bx = blockIdx.x;
    int b = bx >> 7, c = bx & 127;
    int h = c >> 4, cvi = c & 15;
    int tid = threadIdx.x;
    const float* vp = v_img + (size_t)(b * 128 + c) * 4096;
    for (int idx = tid; idx < 4096; idx += 256)
        s[(idx >> 6) * 65 + (idx & 63)] = vp[idx];
    int kc; const float* wp; float bias;
    if (c < 32)      { kc = 3; wp = w3 + c * 9;        bias = b3[c]; }
    else if (c < 80) { kc = 5; wp = w5 + (c - 32) * 25; bias = b5[c - 32]; }
    else             { kc = 7; wp = w7 + (c - 80) * 49; bias = b7[c - 80]; }
    if (tid < kc * kc) wsm[tid] = wp[tid];
    float kvr[16];
    #pragma unroll
    for (int ck = 0; ck < 16; ++ck)
        kvr[ck] = kv[((size_t)(b * 8 + h) * 16 + ck) * 16 + cvi];
    float dac = da[b * 128 + c];
    int off = kc >> 1;
    __syncthreads();
    for (int i = 0; i < 16; ++i) {
        int n = tid + i * 256;
        int y = n >> 6, xx = n & 63;
        float acc = bias;
        for (int dy = 0; dy < kc; ++dy) {
            int sy = y + dy - off;
            if (sy < 0 || sy >= 64) continue;
            for (int dx = 0; dx < kc; ++dx) {
                int sx = xx + dx - off;
                if (sx < 0 || sx >= 64) continue;
                acc += s[sy * 65 + sx] * wsm[dy * kc + dx];
            }
        }
        const float* qp = q + (size_t)(b * 4096 + n) * 128 + h * 16;
        float fa = 0.f;
        #pragma unroll
        for (int ck = 0; ck < 16; ++ck)
            fa += qp[ck] * kvr[ck];
        att[(size_t)(b * 128 + c) * 4096 + n] = dac * (0.25f * fa + qp[cvi] * acc);
    }
}

// ---------------- proj GEMM + bias + residual(x) -> out (token layout) -----
// grid 1024, block 256. A = att image layout (staged transposed)
__global__ __launch_bounds__(256) void proj_kernel(
    const float* __restrict__ att, const float* __restrict__ W,
    const float* __restrict__ bias, const float* __restrict__ xres,
    float* __restrict__ out) {
    __shared__ float sm[32 * 130];
    int tb = blockIdx.x * 32;
    int tid = threadIdx.x;
    int b = tb >> 12, nb = tb & 4095;
    for (int idx = tid; idx < 4096; idx += 256) {
        int t = idx & 31, k = idx >> 5;
        sm[t * 130 + k] = att[(size_t)(b * 128 + k) * 4096 + nb + t];
    }
    __syncthreads();
    int j = tid & 127, half = tid >> 7;
    float acc[16];
    #pragma unroll
    for (int i = 0; i < 16; ++i) acc[i] = 0.f;
    for (int k = 0; k < 128; ++k) {
        float w = W[k * 128 + j];
        #pragma unroll
        for (int i = 0; i < 16; ++i)
            acc[i] += sm[(half * 16 + i) * 130 + k] * w;
    }
    float bj = bias[j];
    #pragma unroll
    for (int i = 0; i < 16; ++i) {
        size_t o = (size_t)(tb + half * 16 + i) * 128 + j;
        out[o] = xres[o] + acc[i] + bj;
    }
}

// ---------------- FC1: chunk GEMM 4096x1024 (K=128) + gelu -----------------
// grid (128, 8), block 256
__global__ __launch_bounds__(256) void fc1_kernel(
    const float* __restrict__ A, const float* __restrict__ W,
    const float* __restrict__ bias, float* __restrict__ hid,
    int chunk_base) {
    __shared__ float sm[32 * 128];
    int tb = chunk_base + blockIdx.x * 32;
    int jb = blockIdx.y * 128;
    int tid = threadIdx.x;
    for (int idx = tid; idx < 4096; idx += 256) {
        int t = idx >> 7, k = idx & 127;
        sm[t * 128 + k] = A[(size_t)(tb + t) * 128 + k];
    }
    __syncthreads();
    int j = tid & 127, half = tid >> 7;
    float acc[16];
    #pragma unroll
    for (int i = 0; i < 16; ++i) acc[i] = 0.f;
    for (int k = 0; k < 128; ++k) {
        float w = W[k * 1024 + jb + j];
        #pragma unroll
        for (int i = 0; i < 16; ++i)
            acc[i] += sm[(half * 16 + i) * 128 + k] * w;
    }
    float bj = bias[jb + j];
    int tloc = blockIdx.x * 32 + half * 16;
    #pragma unroll
    for (int i = 0; i < 16; ++i) {
        float a = acc[i] + bj;
        float gl = 0.5f * a * (1.f + erff(a * 0.70710678118654752f));
        hid[(size_t)(tloc + i) * 1024 + jb + j] = gl;
    }
}

// ---------------- FC2: chunk GEMM 4096x128 (K=1024) + bias + residual ------
// grid 128, block 256
__global__ __launch_bounds__(256) void fc2_kernel(
    const float* __restrict__ hid, const float* __restrict__ W,
    const float* __restrict__ bias, float* __restrict__ out,
    int chunk_base) {
    __shared__ float sm[32 * 128];
    int tbl = blockIdx.x * 32;
    int tid = threadIdx.x;
    int j = tid & 127, half = tid >> 7;
    float acc[16];
    #pragma unroll
    for (int i = 0; i < 16; ++i) acc[i] = 0.f;
    for (int kt = 0; kt < 8; ++kt) {
        for (int idx = tid; idx < 4096; idx += 256) {
            int t = idx >> 7, k = idx & 127;
            sm[t * 128 + k] = hid[(size_t)(tbl + t) * 1024 + kt * 128 + k];
        }
        __syncthreads();
        for (int k = 0; k < 128; ++k) {
            float w = W[(kt * 128 + k) * 128 + j];
            #pragma unroll
            for (int i = 0; i < 16; ++i)
                acc[i] += sm[(half * 16 + i) * 128 + k] * w;
        }
        __syncthreads();
    }
    float bj = bias[j];
    #pragma unroll
    for (int i = 0; i < 16; ++i) {
        size_t o = (size_t)(chunk_base + tbl + half * 16 + i) * 128 + j;
        out[o] = out[o] + acc[i] + bj;
    }
}

extern "C" void kernel_launch(void* const* d_in, const int* in_sizes, int n_in,
                              void* d_out, int out_size, void* d_ws, size_t ws_size,
                              hipStream_t stream) {
    const float* img   = (const float*)d_in[0];
    const float* dl    = (const float*)d_in[1];
    const float* pe_dw = (const float*)d_in[2];
    const float* pe_pw = (const float*)d_in[3];
    const float* bn_g  = (const float*)d_in[4];
    const float* bn_b  = (const float*)d_in[5];
    const float* bn_m  = (const float*)d_in[6];
    const float* bn_v  = (const float*)d_in[7];
    const float* cpe_w = (const float*)d_in[8];
    const float* cpe_b = (const float*)d_in[9];
    const float* n1_g  = (const float*)d_in[10];
    const float* n1_b  = (const float*)d_in[11];
    const float* qkv_w = (const float*)d_in[12];
    const float* qkv_b = (const float*)d_in[13];
    const float* w3    = (const float*)d_in[14];
    const float* b3    = (const float*)d_in[15];
    const float* w5    = (const float*)d_in[16];
    const float* b5    = (const float*)d_in[17];
    const float* w7    = (const float*)d_in[18];
    const float* b7    = (const float*)d_in[19];
    const float* dw1   = (const float*)d_in[20];
    const float* db1   = (const float*)d_in[21];
    const float* dw2   = (const float*)d_in[22];
    const float* db2   = (const float*)d_in[23];
    const float* pw    = (const float*)d_in[24];
    const float* pb    = (const float*)d_in[25];
    const float* n2_g  = (const float*)d_in[26];
    const float* n2_b  = (const float*)d_in[27];
    const float* f1w   = (const float*)d_in[28];
    const float* f1b   = (const float*)d_in[29];
    const float* f2w   = (const float*)d_in[30];
    const float* f2b   = (const float*)d_in[31];
    const int*   dptr  = (const int*)d_in[32];
    float* out = (float*)d_out;

    char* ws = (char*)d_ws;
    const size_t SZ = (size_t)8 * 128 * 4096 * 4;   // 16,777,216 bytes
    float* t1    = (float*)(ws);            // also cur / cur2
    float* x     = (float*)(ws + SZ);
    float* q     = (float*)(ws + 2 * SZ);
    float* k_img = (float*)(ws + 3 * SZ);   // also att after kv
    float* v_img = (float*)(ws + 4 * SZ);   // also hid chunk after att
    float* kv    = (float*)(ws + 5 * SZ);
    float* da    = (float*)(ws + 5 * SZ + 65536);

    pe_kernel<<<512, 256, 0, stream>>>(img, pe_dw, pe_pw, bn_g, bn_b, bn_m, bn_v, dptr, t1);
    cpe_kernel<<<2048, 256, 0, stream>>>(t1, cpe_w, cpe_b, x);
    ln_kernel<<<8192, 256, 0, stream>>>(x, t1, n1_g, n1_b, dptr);
    qkv_kernel<<<dim3(1024, 3), 256, 0, stream>>>(t1, qkv_w, qkv_b, q, k_img, v_img);
    softmax_kernel<<<1024, 256, 0, stream>>>(k_img);
    kv_kernel<<<64, 256, 0, stream>>>(k_img, v_img, kv);
    gate_kernel<<<1, 256, 0, stream>>>(dl, dw1, db1, dw2, db2, da);
    att_kernel<<<1024, 256, 0, stream>>>(q, v_img, kv, da, w3, b3, w5, b5, w7, b7, k_img);
    proj_kernel<<<1024, 256, 0, stream>>>(k_img, pw, pb, x, out);
    ln_kernel<<<8192, 256, 0, stream>>>(out, t1, n2_g, n2_b, dptr);
    for (int ch = 0; ch < 8; ++ch) {
        fc1_kernel<<<dim3(128, 8), 256, 0, stream>>>(t1, f1w, f1b, v_img, ch * 4096);
        fc2_kernel<<<128, 256, 0, stream>>>(v_img, f2w, f2b, out, ch * 4096);
    }
}

// Round 2
// 887.032 us; speedup vs baseline: 1.9111x; 1.9111x over previous
//
#include <hip/hip_runtime.h>
#include <math.h>

#define EPS_LN 1e-6f
#define EPS_BN 1e-5f

__device__ __forceinline__ float wave_reduce_sum(float v) {
    #pragma unroll
    for (int m = 32; m >= 1; m >>= 1) v += __shfl_xor(v, m, 64);
    return v;
}
__device__ __forceinline__ float wave_reduce_max(float v) {
    #pragma unroll
    for (int m = 32; m >= 1; m >>= 1) v = fmaxf(v, __shfl_xor(v, m, 64));
    return v;
}

// ---------------- patch embed: dw3x3 s2 + pw 64->128 + BN(d) + hardswish ----
// grid 512 = (b*64 + y), block 256. out t1 image layout (B,128,4096)
__global__ __launch_bounds__(256) void pe_kernel(
    const float* __restrict__ img, const float* __restrict__ dww,
    const float* __restrict__ pww, const float* __restrict__ bn_g,
    const float* __restrict__ bn_b, const float* __restrict__ bn_m,
    const float* __restrict__ bn_v, const int* __restrict__ dptr,
    float* __restrict__ t1) {
    __shared__ float dw[64 * 65];
    int bx = blockIdx.x;
    int b = bx >> 6, y = bx & 63;
    int tid = threadIdx.x;
    int d = *dptr;
    for (int idx = tid; idx < 4096; idx += 256) {
        int ci = idx >> 6, xx = idx & 63;
        const float* ip = img + (size_t)(b * 64 + ci) * 128 * 128;
        float acc = 0.f;
        #pragma unroll
        for (int r = 0; r < 3; ++r) {
            int iy = 2 * y + r;           // pad_lo = 0, pad_hi = 1 (SAME, s=2)
            if (iy >= 128) continue;
            #pragma unroll
            for (int s = 0; s < 3; ++s) {
                int ix = 2 * xx + s;
                if (ix >= 128) continue;
                acc += ip[iy * 128 + ix] * dww[ci * 9 + r * 3 + s];
            }
        }
        dw[ci * 65 + xx] = acc;
    }
    __syncthreads();
    for (int idx = tid; idx < 8192; idx += 256) {
        int co = idx >> 6, xx = idx & 63;
        float acc = 0.f;
        const float* wp = pww + co * 64;
        for (int ci = 0; ci < 64; ++ci)
            acc += dw[ci * 65 + xx] * wp[ci];
        float sc = bn_g[d * 128 + co] * rsqrtf(bn_v[d * 128 + co] + EPS_BN);
        float v = (acc - bn_m[d * 128 + co]) * sc + bn_b[d * 128 + co];
        v = v * fminf(fmaxf(v + 3.f, 0.f), 6.f) * (1.f / 6.f);
        t1[(size_t)(b * 128 + co) * 4096 + y * 64 + xx] = v;
    }
}

// ---------------- ConvPosEnc: x_tok = t1 + dw3x3(t1) + bias ----------------
// grid 2048 = ((b*64+y)*4 + cq), block 256. out x token layout (B,N,128)
__global__ __launch_bounds__(256) void cpe_kernel(
    const float* __restrict__ t1, const float* __restrict__ cw,
    const float* __restrict__ cb, float* __restrict__ xout) {
    int bx = blockIdx.x;
    int cq = bx & 3, y = (bx >> 2) & 63, b = bx >> 8;
    int c0 = cq * 32;
    __shared__ float s[3 * 32 * 65];
    int tid = threadIdx.x;
    for (int idx = tid; idx < 3 * 32 * 64; idx += 256) {
        int xx = idx & 63;
        int cl = (idx >> 6) & 31;
        int dy = idx >> 11;
        int yy = y + dy - 1;
        float v = 0.f;
        if (yy >= 0 && yy < 64)
            v = t1[(size_t)(b * 128 + c0 + cl) * 4096 + yy * 64 + xx];
        s[(dy * 32 + cl) * 65 + xx] = v;
    }
    __syncthreads();
    for (int idx = tid; idx < 32 * 64; idx += 256) {
        int cl = idx & 31;       // c fastest -> coalesced writes
        int xx = idx >> 5;
        int c = c0 + cl;
        float center = s[(32 + cl) * 65 + xx];
        float acc = cb[c];
        #pragma unroll
        for (int dy = 0; dy < 3; ++dy) {
            #pragma unroll
            for (int dx = 0; dx < 3; ++dx) {
                int sx = xx + dx - 1;
                if (sx < 0 || sx >= 64) continue;
                acc += s[(dy * 32 + cl) * 65 + sx] * cw[c * 9 + dy * 3 + dx];
            }
        }
        xout[(size_t)(b * 4096 + y * 64 + xx) * 128 + c] = center + acc;
    }
}

// ---------------- LayerNorm over C=128 with domain params ------------------
// grid 8192, block 256 (4 waves, 1 token per wave)
__global__ __launch_bounds__(256) void ln_kernel(
    const float* __restrict__ src, float* __restrict__ dst,
    const float* __restrict__ g, const float* __restrict__ bb,
    const int* __restrict__ dptr) {
    int d = *dptr;
    int wid = threadIdx.x >> 6, lane = threadIdx.x & 63;
    size_t t = (size_t)blockIdx.x * 4 + wid;
    const float* p = src + t * 128;
    float v0 = p[lane], v1 = p[lane + 64];
    float mean = wave_reduce_sum(v0 + v1) * (1.f / 128.f);
    float d0 = v0 - mean, d1 = v1 - mean;
    float var = wave_reduce_sum(d0 * d0 + d1 * d1) * (1.f / 128.f);
    float rs = rsqrtf(var + EPS_LN);
    dst[t * 128 + lane]      = d0 * rs * g[d * 128 + lane]      + bb[d * 128 + lane];
    dst[t * 128 + lane + 64] = d1 * rs * g[d * 128 + lane + 64] + bb[d * 128 + lane + 64];
}

// ---------------- QKV GEMM: cur(32768x128) @ W(128x384) + b ----------------
// grid (1024, 3), block 256. q -> token layout; k,v -> image layout (transpose via LDS)
__global__ __launch_bounds__(256) void qkv_kernel(
    const float* __restrict__ A, const float* __restrict__ W,
    const float* __restrict__ bias, float* __restrict__ q,
    float* __restrict__ k_img, float* __restrict__ v_img) {
    __shared__ float sm[32 * 130];
    int tb = blockIdx.x * 32;
    int cblk = blockIdx.y;
    int jb = cblk * 128;
    int tid = threadIdx.x;
    for (int idx = tid; idx < 4096; idx += 256) {
        int t = idx >> 7, k = idx & 127;
        sm[t * 130 + k] = A[(size_t)(tb + t) * 128 + k];
    }
    __syncthreads();
    int j = tid & 127, half = tid >> 7;
    float acc[16];
    #pragma unroll
    for (int i = 0; i < 16; ++i) acc[i] = 0.f;
    for (int k = 0; k < 128; ++k) {
        float w = W[k * 384 + jb + j];
        #pragma unroll
        for (int i = 0; i < 16; ++i)
            acc[i] += sm[(half * 16 + i) * 130 + k] * w;
    }
    float bj = bias[jb + j];
    #pragma unroll
    for (int i = 0; i < 16; ++i) acc[i] += bj;
    if (cblk == 0) {
        #pragma unroll
        for (int i = 0; i < 16; ++i)
            q[(size_t)(tb + half * 16 + i) * 128 + j] = acc[i];
    } else {
        __syncthreads();
        #pragma unroll
        for (int i = 0; i < 16; ++i)
            sm[(half * 16 + i) * 130 + j] = acc[i];
        __syncthreads();
        float* dst = (cblk == 1) ? k_img : v_img;
        int b = tb >> 12;
        int nb = tb & 4095;
        #pragma unroll
        for (int it = 0; it < 16; ++it) {
            int c = it * 8 + (tid >> 5);
            int noff = tid & 31;
            dst[(size_t)(b * 128 + c) * 4096 + nb + noff] = sm[noff * 130 + c];
        }
    }
}

// ---------------- softmax over N for each (b,c) row of k_img ---------------
__global__ __launch_bounds__(256) void softmax_kernel(float* __restrict__ k_img) {
    __shared__ float red[4];
    float* p = k_img + (size_t)blockIdx.x * 4096;
    int tid = threadIdx.x;
    float v[16];
    float mx = -1e30f;
    #pragma unroll
    for (int i = 0; i < 16; ++i) {
        v[i] = p[tid + i * 256];
        mx = fmaxf(mx, v[i]);
    }
    mx = wave_reduce_max(mx);
    int wid = tid >> 6, lane = tid & 63;
    if (lane == 0) red[wid] = mx;
    __syncthreads();
    mx = fmaxf(fmaxf(red[0], red[1]), fmaxf(red[2], red[3]));
    __syncthreads();
    float sum = 0.f;
    #pragma unroll
    for (int i = 0; i < 16; ++i) {
        v[i] = expf(v[i] - mx);
        sum += v[i];
    }
    sum = wave_reduce_sum(sum);
    if (lane == 0) red[wid] = sum;
    __syncthreads();
    float inv = 1.f / (red[0] + red[1] + red[2] + red[3]);
    #pragma unroll
    for (int i = 0; i < 16; ++i)
        p[tid + i * 256] = v[i] * inv;
}

// ---------------- kv[b,h,ck,cv] = sum_n k_sm * v ---------------------------
// grid 64 (b*8+h), block 256 = (ck,cv)
__global__ __launch_bounds__(256) void kv_kernel(
    const float* __restrict__ k_img, const float* __restrict__ v_img,
    float* __restrict__ kv) {
    __shared__ float ks[16 * 132], vs[16 * 132];
    int bh = blockIdx.x;
    int b = bh >> 3, h = bh & 7;
    int tid = threadIdx.x;
    int ck = tid >> 4, cv = tid & 15;
    float acc = 0.f;
    const float* kp = k_img + (size_t)(b * 128 + h * 16) * 4096;
    const float* vp = v_img + (size_t)(b * 128 + h * 16) * 4096;
    for (int nb = 0; nb < 4096; nb += 128) {
        for (int idx = tid; idx < 2048; idx += 256) {
            int r = idx >> 7, col = idx & 127;
            ks[r * 132 + col] = kp[(size_t)r * 4096 + nb + col];
            vs[r * 132 + col] = vp[(size_t)r * 4096 + nb + col];
        }
        __syncthreads();
        for (int kk = 0; kk < 128; ++kk)
            acc += ks[ck * 132 + kk] * vs[cv * 132 + kk];
        __syncthreads();
    }
    kv[(size_t)bh * 256 + ck * 16 + cv] = acc;
}

// ---------------- domain gate -> da (B,128) --------------------------------
__global__ __launch_bounds__(256) void gate_kernel(
    const float* __restrict__ dl, const float* __restrict__ w1,
    const float* __restrict__ b1, const float* __restrict__ w2,
    const float* __restrict__ b2, float* __restrict__ da) {
    __shared__ float hid[512];
    __shared__ float raw[1024];
    int tid = threadIdx.x;
    for (int idx = tid; idx < 512; idx += 256) {
        int b = idx >> 6, jj = idx & 63;
        float a = b1[jj];
        #pragma unroll
        for (int dd = 0; dd < 4; ++dd)
            a += dl[b * 4 + dd] * w1[dd * 64 + jj];
        hid[idx] = fmaxf(a, 0.f);
    }
    __syncthreads();
    for (int idx = tid; idx < 1024; idx += 256) {
        int b = idx >> 7, c = idx & 127;
        float a = b2[c];
        for (int jj = 0; jj < 64; ++jj)
            a += hid[b * 64 + jj] * w2[jj * 128 + c];
        raw[idx] = a;
    }
    __syncthreads();
    if (tid < 128) {
        int b = tid >> 4, ch = tid & 15;
        float mx = -1e30f;
        #pragma unroll
        for (int hh = 0; hh < 8; ++hh)
            mx = fmaxf(mx, raw[b * 128 + hh * 16 + ch]);
        float e[8];
        float s = 0.f;
        #pragma unroll
        for (int hh = 0; hh < 8; ++hh) {
            e[hh] = expf(raw[b * 128 + hh * 16 + ch] - mx);
            s += e[hh];
        }
        float inv = 1.f / s;
        #pragma unroll
        for (int hh = 0; hh < 8; ++hh)
            da[b * 128 + hh * 16 + ch] = e[hh] * inv;
    }
}

// ---------------- crpe conv + factor-att combine -> att image layout -------
// grid 1024 = (b*128+c), block 256
__global__ __launch_bounds__(256) void att_kernel(
    const float* __restrict__ q, const float* __restrict__ v_img,
    const float* __restrict__ kv, const float* __restrict__ da,
    const float* __restrict__ w3, const float* __restrict__ b3,
    const float* __restrict__ w5, const float* __restrict__ b5,
    const float* __restrict__ w7, const float* __restrict__ b7,
    float* __restrict__ att) {
    __shared__ float s[64 * 65];
    __shared__ float wsm[49];
    int bx = blockIdx.x;
    int b = bx >> 7, c = bx & 127;
    int h = c >> 4, cvi = c & 15;
    int tid = threadIdx.x;
    const float* vp = v_img + (size_t)(b * 128 + c) * 4096;
    for (int idx = tid; idx < 4096; idx += 256)
        s[(idx >> 6) * 65 + (idx & 63)] = vp[idx];
    int kc; const float* wp; float bias;
    if (c < 32)      { kc = 3; wp = w3 + c * 9;        bias = b3[c]; }
    else if (c < 80) { kc = 5; wp = w5 + (c - 32) * 25; bias = b5[c - 32]; }
    else             { kc = 7; wp = w7 + (c - 80) * 49; bias = b7[c - 80]; }
    if (tid < kc * kc) wsm[tid] = wp[tid];
    float kvr[16];
    #pragma unroll
    for (int ck = 0; ck < 16; ++ck)
        kvr[ck] = kv[((size_t)(b * 8 + h) * 16 + ck) * 16 + cvi];
    float dac = da[b * 128 + c];
    int off = kc >> 1;
    __syncthreads();
    for (int i = 0; i < 16; ++i) {
        int n = tid + i * 256;
        int y = n >> 6, xx = n & 63;
        float acc = bias;
        for (int dy = 0; dy < kc; ++dy) {
            int sy = y + dy - off;
            if (sy < 0 || sy >= 64) continue;
            for (int dx = 0; dx < kc; ++dx) {
                int sx = xx + dx - off;
                if (sx < 0 || sx >= 64) continue;
                acc += s[sy * 65 + sx] * wsm[dy * kc + dx];
            }
        }
        const float* qp = q + (size_t)(b * 4096 + n) * 128 + h * 16;
        float fa = 0.f;
        #pragma unroll
        for (int ck = 0; ck < 16; ++ck)
            fa += qp[ck] * kvr[ck];
        att[(size_t)(b * 128 + c) * 4096 + n] = dac * (0.25f * fa + qp[cvi] * acc);
    }
}

// ---------------- proj GEMM + bias + residual(x) -> out (token layout) -----
// grid 1024, block 256. A = att image layout (staged transposed)
__global__ __launch_bounds__(256) void proj_kernel(
    const float* __restrict__ att, const float* __restrict__ W,
    const float* __restrict__ bias, const float* __restrict__ xres,
    float* __restrict__ out) {
    __shared__ float sm[32 * 130];
    int tb = blockIdx.x * 32;
    int tid = threadIdx.x;
    int b = tb >> 12, nb = tb & 4095;
    for (int idx = tid; idx < 4096; idx += 256) {
        int t = idx & 31, k = idx >> 5;
        sm[t * 130 + k] = att[(size_t)(b * 128 + k) * 4096 + nb + t];
    }
    __syncthreads();
    int j = tid & 127, half = tid >> 7;
    float acc[16];
    #pragma unroll
    for (int i = 0; i < 16; ++i) acc[i] = 0.f;
    for (int k = 0; k < 128; ++k) {
        float w = W[k * 128 + j];
        #pragma unroll
        for (int i = 0; i < 16; ++i)
            acc[i] += sm[(half * 16 + i) * 130 + k] * w;
    }
    float bj = bias[j];
    #pragma unroll
    for (int i = 0; i < 16; ++i) {
        size_t o = (size_t)(tb + half * 16 + i) * 128 + j;
        out[o] = xres[o] + acc[i] + bj;
    }
}

// ---------------- fused MLP: cur(16tok x128) -> hid(LDS 16x1024) -> out ----
// grid 2048, block 256, LDS ~76KB (2 blocks/CU)
__global__ __launch_bounds__(256, 2) void mlp_kernel(
    const float* __restrict__ cur, const float* __restrict__ w1,
    const float* __restrict__ b1, const float* __restrict__ w2,
    const float* __restrict__ b2, float* __restrict__ out) {
    __shared__ float curs_t[128 * 20];     // [k][tok] padded (20 = 16+4, 16B-aligned rows)
    __shared__ float hid[16 * 1024];       // [tok][hcol]
    int tb = blockIdx.x * 16;
    int tid = threadIdx.x;

    // stage cur tile transposed: curs_t[k][t] = cur[tb+t][k]
    for (int idx = tid; idx < 2048; idx += 256) {
        int t = idx >> 7, k = idx & 127;
        curs_t[k * 20 + t] = cur[(size_t)(tb + t) * 128 + k];
    }
    __syncthreads();

    // ---- fc1 + gelu: thread tile 8 tok x 8 cols (tokg = tid>>7, colg = tid&127)
    {
        int tokg = tid >> 7, colg = tid & 127;
        float acc[8][8];
        #pragma unroll
        for (int i = 0; i < 8; ++i)
            #pragma unroll
            for (int j = 0; j < 8; ++j) acc[i][j] = 0.f;
        const float* wbase = w1 + colg * 8;
        for (int k = 0; k < 128; ++k) {
            float4 a0 = *(const float4*)&curs_t[k * 20 + tokg * 8];
            float4 a1 = *(const float4*)&curs_t[k * 20 + tokg * 8 + 4];
            float4 wv0 = *(const float4*)&wbase[(size_t)k * 1024];
            float4 wv1 = *(const float4*)&wbase[(size_t)k * 1024 + 4];
            float av[8] = {a0.x, a0.y, a0.z, a0.w, a1.x, a1.y, a1.z, a1.w};
            float wv[8] = {wv0.x, wv0.y, wv0.z, wv0.w, wv1.x, wv1.y, wv1.z, wv1.w};
            #pragma unroll
            for (int i = 0; i < 8; ++i)
                #pragma unroll
                for (int j = 0; j < 8; ++j)
                    acc[i][j] += av[i] * wv[j];
        }
        float bv[8];
        #pragma unroll
        for (int j = 0; j < 8; ++j) bv[j] = b1[colg * 8 + j];
        #pragma unroll
        for (int i = 0; i < 8; ++i) {
            float g[8];
            #pragma unroll
            for (int j = 0; j < 8; ++j) {
                float a = acc[i][j] + bv[j];
                g[j] = 0.5f * a * (1.f + erff(a * 0.70710678118654752f));
            }
            float* hp = &hid[(tokg * 8 + i) * 1024 + colg * 8];
            *(float4*)hp       = make_float4(g[0], g[1], g[2], g[3]);
            *(float4*)(hp + 4) = make_float4(g[4], g[5], g[6], g[7]);
        }
    }
    __syncthreads();

    // ---- fc2 + residual: thread tile 8 tok x 1 col (j = tid&127, tg = tid>>7)
    {
        int j = tid & 127, tg = tid >> 7;
        float acc2[8];
        #pragma unroll
        for (int i = 0; i < 8; ++i) acc2[i] = 0.f;
        const float* w2p = w2 + j;
        for (int k4 = 0; k4 < 1024; k4 += 4) {
            float wa = w2p[(size_t)(k4 + 0) * 128];
            float wb = w2p[(size_t)(k4 + 1) * 128];
            float wc = w2p[(size_t)(k4 + 2) * 128];
            float wd = w2p[(size_t)(k4 + 3) * 128];
            #pragma unroll
            for (int i = 0; i < 8; ++i) {
                float4 hv = *(const float4*)&hid[(tg * 8 + i) * 1024 + k4];
                acc2[i] += hv.x * wa + hv.y * wb + hv.z * wc + hv.w * wd;
            }
        }
        float bj = b2[j];
        #pragma unroll
        for (int i = 0; i < 8; ++i) {
            size_t o = (size_t)(tb + tg * 8 + i) * 128 + j;
            out[o] = out[o] + acc2[i] + bj;
        }
    }
}

extern "C" void kernel_launch(void* const* d_in, const int* in_sizes, int n_in,
                              void* d_out, int out_size, void* d_ws, size_t ws_size,
                              hipStream_t stream) {
    const float* img   = (const float*)d_in[0];
    const float* dl    = (const float*)d_in[1];
    const float* pe_dw = (const float*)d_in[2];
    const float* pe_pw = (const float*)d_in[3];
    const float* bn_g  = (const float*)d_in[4];
    const float* bn_b  = (const float*)d_in[5];
    const float* bn_m  = (const float*)d_in[6];
    const float* bn_v  = (const float*)d_in[7];
    const float* cpe_w = (const float*)d_in[8];
    const float* cpe_b = (const float*)d_in[9];
    const float* n1_g  = (const float*)d_in[10];
    const float* n1_b  = (const float*)d_in[11];
    const float* qkv_w = (const float*)d_in[12];
    const float* qkv_b = (const float*)d_in[13];
    const float* w3    = (const float*)d_in[14];
    const float* b3    = (const float*)d_in[15];
    const float* w5    = (const float*)d_in[16];
    const float* b5    = (const float*)d_in[17];
    const float* w7    = (const float*)d_in[18];
    const float* b7    = (const float*)d_in[19];
    const float* dw1   = (const float*)d_in[20];
    const float* db1   = (const float*)d_in[21];
    const float* dw2   = (const float*)d_in[22];
    const float* db2   = (const float*)d_in[23];
    const float* pw    = (const float*)d_in[24];
    const float* pb    = (const float*)d_in[25];
    const float* n2_g  = (const float*)d_in[26];
    const float* n2_b  = (const float*)d_in[27];
    const float* f1w   = (const float*)d_in[28];
    const float* f1b   = (const float*)d_in[29];
    const float* f2w   = (const float*)d_in[30];
    const float* f2b   = (const float*)d_in[31];
    const int*   dptr  = (const int*)d_in[32];
    float* out = (float*)d_out;

    char* ws = (char*)d_ws;
    const size_t SZ = (size_t)8 * 128 * 4096 * 4;   // 16,777,216 bytes
    float* t1    = (float*)(ws);            // also cur (post-LN)
    float* x     = (float*)(ws + SZ);
    float* q     = (float*)(ws + 2 * SZ);
    float* k_img = (float*)(ws + 3 * SZ);   // also att after kv
    float* v_img = (float*)(ws + 4 * SZ);
    float* kv    = (float*)(ws + 5 * SZ);
    float* da    = (float*)(ws + 5 * SZ + 65536);

    pe_kernel<<<512, 256, 0, stream>>>(img, pe_dw, pe_pw, bn_g, bn_b, bn_m, bn_v, dptr, t1);
    cpe_kernel<<<2048, 256, 0, stream>>>(t1, cpe_w, cpe_b, x);
    ln_kernel<<<8192, 256, 0, stream>>>(x, t1, n1_g, n1_b, dptr);
    qkv_kernel<<<dim3(1024, 3), 256, 0, stream>>>(t1, qkv_w, qkv_b, q, k_img, v_img);
    softmax_kernel<<<1024, 256, 0, stream>>>(k_img);
    kv_kernel<<<64, 256, 0, stream>>>(k_img, v_img, kv);
    gate_kernel<<<1, 256, 0, stream>>>(dl, dw1, db1, dw2, db2, da);
    att_kernel<<<1024, 256, 0, stream>>>(q, v_img, kv, da, w3, b3, w5, b5, w7, b7, k_img);
    proj_kernel<<<1024, 256, 0, stream>>>(k_img, pw, pb, x, out);
    ln_kernel<<<8192, 256, 0, stream>>>(out, t1, n2_g, n2_b, dptr);
    mlp_kernel<<<2048, 256, 0, stream>>>(t1, f1w, f1b, f2w, f2b, out);
}

// Round 3
// 714.767 us; speedup vs baseline: 2.3717x; 1.2410x over previous
//
#include <hip/hip_runtime.h>
#include <math.h>

#define EPS_LN 1e-6f
#define EPS_BN 1e-5f

typedef __attribute__((ext_vector_type(8))) short bf16x8;
typedef __attribute__((ext_vector_type(4))) float f32x4;

__device__ __forceinline__ float wave_reduce_sum(float v) {
    #pragma unroll
    for (int m = 32; m >= 1; m >>= 1) v += __shfl_xor(v, m, 64);
    return v;
}
__device__ __forceinline__ float wave_reduce_max(float v) {
    #pragma unroll
    for (int m = 32; m >= 1; m >>= 1) v = fmaxf(v, __shfl_xor(v, m, 64));
    return v;
}
__device__ __forceinline__ short f2bf(float f) {
    union { float f; unsigned u; } v; v.f = f;
    unsigned r = v.u + 0x7fff + ((v.u >> 16) & 1);
    return (short)(r >> 16);
}
__device__ __forceinline__ unsigned pack2bf(float a, float b) {
    return (unsigned)(unsigned short)f2bf(a) | ((unsigned)(unsigned short)f2bf(b) << 16);
}

// ---------------- patch embed: dw3x3 s2 + pw 64->128 + BN(d) + hardswish ----
__global__ __launch_bounds__(256) void pe_kernel(
    const float* __restrict__ img, const float* __restrict__ dww,
    const float* __restrict__ pww, const float* __restrict__ bn_g,
    const float* __restrict__ bn_b, const float* __restrict__ bn_m,
    const float* __restrict__ bn_v, const int* __restrict__ dptr,
    float* __restrict__ t1) {
    __shared__ float dw[64 * 65];
    int bx = blockIdx.x;
    int b = bx >> 6, y = bx & 63;
    int tid = threadIdx.x;
    int d = *dptr;
    for (int idx = tid; idx < 4096; idx += 256) {
        int ci = idx >> 6, xx = idx & 63;
        const float* ip = img + (size_t)(b * 64 + ci) * 128 * 128;
        float acc = 0.f;
        #pragma unroll
        for (int r = 0; r < 3; ++r) {
            int iy = 2 * y + r;
            if (iy >= 128) continue;
            #pragma unroll
            for (int s = 0; s < 3; ++s) {
                int ix = 2 * xx + s;
                if (ix >= 128) continue;
                acc += ip[iy * 128 + ix] * dww[ci * 9 + r * 3 + s];
            }
        }
        dw[ci * 65 + xx] = acc;
    }
    __syncthreads();
    for (int idx = tid; idx < 8192; idx += 256) {
        int co = idx >> 6, xx = idx & 63;
        float acc = 0.f;
        const float* wp = pww + co * 64;
        for (int ci = 0; ci < 64; ++ci)
            acc += dw[ci * 65 + xx] * wp[ci];
        float sc = bn_g[d * 128 + co] * rsqrtf(bn_v[d * 128 + co] + EPS_BN);
        float v = (acc - bn_m[d * 128 + co]) * sc + bn_b[d * 128 + co];
        v = v * fminf(fmaxf(v + 3.f, 0.f), 6.f) * (1.f / 6.f);
        t1[(size_t)(b * 128 + co) * 4096 + y * 64 + xx] = v;
    }
}

// ---------------- ConvPosEnc ----------------
__global__ __launch_bounds__(256) void cpe_kernel(
    const float* __restrict__ t1, const float* __restrict__ cw,
    const float* __restrict__ cb, float* __restrict__ xout) {
    int bx = blockIdx.x;
    int cq = bx & 3, y = (bx >> 2) & 63, b = bx >> 8;
    int c0 = cq * 32;
    __shared__ float s[3 * 32 * 65];
    int tid = threadIdx.x;
    for (int idx = tid; idx < 3 * 32 * 64; idx += 256) {
        int xx = idx & 63;
        int cl = (idx >> 6) & 31;
        int dy = idx >> 11;
        int yy = y + dy - 1;
        float v = 0.f;
        if (yy >= 0 && yy < 64)
            v = t1[(size_t)(b * 128 + c0 + cl) * 4096 + yy * 64 + xx];
        s[(dy * 32 + cl) * 65 + xx] = v;
    }
    __syncthreads();
    for (int idx = tid; idx < 32 * 64; idx += 256) {
        int cl = idx & 31;
        int xx = idx >> 5;
        int c = c0 + cl;
        float center = s[(32 + cl) * 65 + xx];
        float acc = cb[c];
        #pragma unroll
        for (int dy = 0; dy < 3; ++dy) {
            #pragma unroll
            for (int dx = 0; dx < 3; ++dx) {
                int sx = xx + dx - 1;
                if (sx < 0 || sx >= 64) continue;
                acc += s[(dy * 32 + cl) * 65 + sx] * cw[c * 9 + dy * 3 + dx];
            }
        }
        xout[(size_t)(b * 4096 + y * 64 + xx) * 128 + c] = center + acc;
    }
}

// ---------------- LayerNorm over C=128 ------------------
__global__ __launch_bounds__(256) void ln_kernel(
    const float* __restrict__ src, float* __restrict__ dst,
    const float* __restrict__ g, const float* __restrict__ bb,
    const int* __restrict__ dptr) {
    int d = *dptr;
    int wid = threadIdx.x >> 6, lane = threadIdx.x & 63;
    size_t t = (size_t)blockIdx.x * 4 + wid;
    const float* p = src + t * 128;
    float v0 = p[lane], v1 = p[lane + 64];
    float mean = wave_reduce_sum(v0 + v1) * (1.f / 128.f);
    float d0 = v0 - mean, d1 = v1 - mean;
    float var = wave_reduce_sum(d0 * d0 + d1 * d1) * (1.f / 128.f);
    float rs = rsqrtf(var + EPS_LN);
    dst[t * 128 + lane]      = d0 * rs * g[d * 128 + lane]      + bb[d * 128 + lane];
    dst[t * 128 + lane + 64] = d1 * rs * g[d * 128 + lane + 64] + bb[d * 128 + lane + 64];
}

// ---------------- QKV GEMM ----------------
__global__ __launch_bounds__(256) void qkv_kernel(
    const float* __restrict__ A, const float* __restrict__ W,
    const float* __restrict__ bias, float* __restrict__ q,
    float* __restrict__ k_img, float* __restrict__ v_img) {
    __shared__ float sm[32 * 130];
    int tb = blockIdx.x * 32;
    int cblk = blockIdx.y;
    int jb = cblk * 128;
    int tid = threadIdx.x;
    for (int idx = tid; idx < 4096; idx += 256) {
        int t = idx >> 7, k = idx & 127;
        sm[t * 130 + k] = A[(size_t)(tb + t) * 128 + k];
    }
    __syncthreads();
    int j = tid & 127, half = tid >> 7;
    float acc[16];
    #pragma unroll
    for (int i = 0; i < 16; ++i) acc[i] = 0.f;
    for (int k = 0; k < 128; ++k) {
        float w = W[k * 384 + jb + j];
        #pragma unroll
        for (int i = 0; i < 16; ++i)
            acc[i] += sm[(half * 16 + i) * 130 + k] * w;
    }
    float bj = bias[jb + j];
    #pragma unroll
    for (int i = 0; i < 16; ++i) acc[i] += bj;
    if (cblk == 0) {
        #pragma unroll
        for (int i = 0; i < 16; ++i)
            q[(size_t)(tb + half * 16 + i) * 128 + j] = acc[i];
    } else {
        __syncthreads();
        #pragma unroll
        for (int i = 0; i < 16; ++i)
            sm[(half * 16 + i) * 130 + j] = acc[i];
        __syncthreads();
        float* dst = (cblk == 1) ? k_img : v_img;
        int b = tb >> 12;
        int nb = tb & 4095;
        #pragma unroll
        for (int it = 0; it < 16; ++it) {
            int c = it * 8 + (tid >> 5);
            int noff = tid & 31;
            dst[(size_t)(b * 128 + c) * 4096 + nb + noff] = sm[noff * 130 + c];
        }
    }
}

// ---------------- softmax over N ---------------
__global__ __launch_bounds__(256) void softmax_kernel(float* __restrict__ k_img) {
    __shared__ float red[4];
    float* p = k_img + (size_t)blockIdx.x * 4096;
    int tid = threadIdx.x;
    float v[16];
    float mx = -1e30f;
    #pragma unroll
    for (int i = 0; i < 16; ++i) {
        v[i] = p[tid + i * 256];
        mx = fmaxf(mx, v[i]);
    }
    mx = wave_reduce_max(mx);
    int wid = tid >> 6, lane = tid & 63;
    if (lane == 0) red[wid] = mx;
    __syncthreads();
    mx = fmaxf(fmaxf(red[0], red[1]), fmaxf(red[2], red[3]));
    __syncthreads();
    float sum = 0.f;
    #pragma unroll
    for (int i = 0; i < 16; ++i) {
        v[i] = expf(v[i] - mx);
        sum += v[i];
    }
    sum = wave_reduce_sum(sum);
    if (lane == 0) red[wid] = sum;
    __syncthreads();
    float inv = 1.f / (red[0] + red[1] + red[2] + red[3]);
    #pragma unroll
    for (int i = 0; i < 16; ++i)
        p[tid + i * 256] = v[i] * inv;
}

// ---------------- kv einsum ---------------------------
__global__ __launch_bounds__(256) void kv_kernel(
    const float* __restrict__ k_img, const float* __restrict__ v_img,
    float* __restrict__ kv) {
    __shared__ float ks[16 * 132], vs[16 * 132];
    int bh = blockIdx.x;
    int b = bh >> 3, h = bh & 7;
    int tid = threadIdx.x;
    int ck = tid >> 4, cv = tid & 15;
    float acc = 0.f;
    const float* kp = k_img + (size_t)(b * 128 + h * 16) * 4096;
    const float* vp = v_img + (size_t)(b * 128 + h * 16) * 4096;
    for (int nb = 0; nb < 4096; nb += 128) {
        for (int idx = tid; idx < 2048; idx += 256) {
            int r = idx >> 7, col = idx & 127;
            ks[r * 132 + col] = kp[(size_t)r * 4096 + nb + col];
            vs[r * 132 + col] = vp[(size_t)r * 4096 + nb + col];
        }
        __syncthreads();
        for (int kk = 0; kk < 128; ++kk)
            acc += ks[ck * 132 + kk] * vs[cv * 132 + kk];
        __syncthreads();
    }
    kv[(size_t)bh * 256 + ck * 16 + cv] = acc;
}

// ---------------- domain gate --------------------------------
__global__ __launch_bounds__(256) void gate_kernel(
    const float* __restrict__ dl, const float* __restrict__ w1,
    const float* __restrict__ b1, const float* __restrict__ w2,
    const float* __restrict__ b2, float* __restrict__ da) {
    __shared__ float hid[512];
    __shared__ float raw[1024];
    int tid = threadIdx.x;
    for (int idx = tid; idx < 512; idx += 256) {
        int b = idx >> 6, jj = idx & 63;
        float a = b1[jj];
        #pragma unroll
        for (int dd = 0; dd < 4; ++dd)
            a += dl[b * 4 + dd] * w1[dd * 64 + jj];
        hid[idx] = fmaxf(a, 0.f);
    }
    __syncthreads();
    for (int idx = tid; idx < 1024; idx += 256) {
        int b = idx >> 7, c = idx & 127;
        float a = b2[c];
        for (int jj = 0; jj < 64; ++jj)
            a += hid[b * 64 + jj] * w2[jj * 128 + c];
        raw[idx] = a;
    }
    __syncthreads();
    if (tid < 128) {
        int b = tid >> 4, ch = tid & 15;
        float mx = -1e30f;
        #pragma unroll
        for (int hh = 0; hh < 8; ++hh)
            mx = fmaxf(mx, raw[b * 128 + hh * 16 + ch]);
        float e[8];
        float s = 0.f;
        #pragma unroll
        for (int hh = 0; hh < 8; ++hh) {
            e[hh] = expf(raw[b * 128 + hh * 16 + ch] - mx);
            s += e[hh];
        }
        float inv = 1.f / s;
        #pragma unroll
        for (int hh = 0; hh < 8; ++hh)
            da[b * 128 + hh * 16 + ch] = e[hh] * inv;
    }
}

// ---------------- crpe conv + factor-att combine -------
__global__ __launch_bounds__(256) void att_kernel(
    const float* __restrict__ q, const float* __restrict__ v_img,
    const float* __restrict__ kv, const float* __restrict__ da,
    const float* __restrict__ w3, const float* __restrict__ b3,
    const float* __restrict__ w5, const float* __restrict__ b5,
    const float* __restrict__ w7, const float* __restrict__ b7,
    float* __restrict__ att) {
    __shared__ float s[64 * 65];
    __shared__ float wsm[49];
    int bx = blockIdx.x;
    int b = bx >> 7, c = bx & 127;
    int h = c >> 4, cvi = c & 15;
    int tid = threadIdx.x;
    const float* vp = v_img + (size_t)(b * 128 + c) * 4096;
    for (int idx = tid; idx < 4096; idx += 256)
        s[(idx >> 6) * 65 + (idx & 63)] = vp[idx];
    int kc; const float* wp; float bias;
    if (c < 32)      { kc = 3; wp = w3 + c * 9;        bias = b3[c]; }
    else if (c < 80) { kc = 5; wp = w5 + (c - 32) * 25; bias = b5[c - 32]; }
    else             { kc = 7; wp = w7 + (c - 80) * 49; bias = b7[c - 80]; }
    if (tid < kc * kc) wsm[tid] = wp[tid];
    float kvr[16];
    #pragma unroll
    for (int ck = 0; ck < 16; ++ck)
        kvr[ck] = kv[((size_t)(b * 8 + h) * 16 + ck) * 16 + cvi];
    float dac = da[b * 128 + c];
    int off = kc >> 1;
    __syncthreads();
    for (int i = 0; i < 16; ++i) {
        int n = tid + i * 256;
        int y = n >> 6, xx = n & 63;
        float acc = bias;
        for (int dy = 0; dy < kc; ++dy) {
            int sy = y + dy - off;
            if (sy < 0 || sy >= 64) continue;
            for (int dx = 0; dx < kc; ++dx) {
                int sx = xx + dx - off;
                if (sx < 0 || sx >= 64) continue;
                acc += s[sy * 65 + sx] * wsm[dy * kc + dx];
            }
        }
        const float* qp = q + (size_t)(b * 4096 + n) * 128 + h * 16;
        float fa = 0.f;
        #pragma unroll
        for (int ck = 0; ck < 16; ++ck)
            fa += qp[ck] * kvr[ck];
        att[(size_t)(b * 128 + c) * 4096 + n] = dac * (0.25f * fa + qp[cvi] * acc);
    }
}

// ---------------- proj GEMM + bias + residual -----
__global__ __launch_bounds__(256) void proj_kernel(
    const float* __restrict__ att, const float* __restrict__ W,
    const float* __restrict__ bias, const float* __restrict__ xres,
    float* __restrict__ out) {
    __shared__ float sm[32 * 130];
    int tb = blockIdx.x * 32;
    int tid = threadIdx.x;
    int b = tb >> 12, nb = tb & 4095;
    for (int idx = tid; idx < 4096; idx += 256) {
        int t = idx & 31, k = idx >> 5;
        sm[t * 130 + k] = att[(size_t)(b * 128 + k) * 4096 + nb + t];
    }
    __syncthreads();
    int j = tid & 127, half = tid >> 7;
    float acc[16];
    #pragma unroll
    for (int i = 0; i < 16; ++i) acc[i] = 0.f;
    for (int k = 0; k < 128; ++k) {
        float w = W[k * 128 + j];
        #pragma unroll
        for (int i = 0; i < 16; ++i)
            acc[i] += sm[(half * 16 + i) * 130 + k] * w;
    }
    float bj = bias[j];
    #pragma unroll
    for (int i = 0; i < 16; ++i) {
        size_t o = (size_t)(tb + half * 16 + i) * 128 + j;
        out[o] = xres[o] + acc[i] + bj;
    }
}

// ---------------- weight pack: w1 (128x1024) -> MFMA frag order bf16 -------
// entry (n,kk,l): holds w1[kk*32+(l>>4)*8+j][n*16+(l&15)], j=0..7
__global__ __launch_bounds__(256) void pack_w1_kernel(
    const float* __restrict__ w1, short* __restrict__ w1p) {
    int idx = blockIdx.x * 256 + threadIdx.x;   // 16384
    int l = idx & 63, kk = (idx >> 6) & 3, n = idx >> 8;
    int k0 = kk * 32 + (l >> 4) * 8;
    int c = n * 16 + (l & 15);
    bf16x8 v;
    #pragma unroll
    for (int j = 0; j < 8; ++j) v[j] = f2bf(w1[(size_t)(k0 + j) * 1024 + c]);
    *(bf16x8*)&w1p[(size_t)idx * 8] = v;
}

// ---------------- weight pack: w2 (1024x128) -> MFMA frag order bf16 -------
__global__ __launch_bounds__(256) void pack_w2_kernel(
    const float* __restrict__ w2, short* __restrict__ w2p) {
    int idx = blockIdx.x * 256 + threadIdx.x;   // 16384
    int l = idx & 63, kk = (idx >> 6) & 31, n = idx >> 11;
    int k0 = kk * 32 + (l >> 4) * 8;
    int c = n * 16 + (l & 15);
    bf16x8 v;
    #pragma unroll
    for (int j = 0; j < 8; ++j) v[j] = f2bf(w2[(size_t)(k0 + j) * 128 + c]);
    *(bf16x8*)&w2p[(size_t)idx * 8] = v;
}

// ---------------- fused MFMA MLP: 32 tok/block, hid in LDS (frag order) ----
// grid 1024, block 256 (4 waves). GEMM1: D1[hcol][tok] = w1^T x cur^T (swapped)
// GEMM2: D2[cout][tok] = w2^T x hid^T. hid LDS layout = GEMM2 A-frag order.
__global__ __launch_bounds__(256, 2) void mlp_mfma_kernel(
    const float* __restrict__ cur, const short* __restrict__ w1p,
    const float* __restrict__ b1, const short* __restrict__ w2p,
    const float* __restrict__ b2, float* __restrict__ out) {
    __shared__ short hs[32768];   // 64KB: entry (tt*32+kk2)*64+l, 8 bf16 each
    int tb = blockIdx.x * 32;
    int tid = threadIdx.x;
    int lane = tid & 63, wv = tid >> 6;
    int lhi = lane >> 4, llo = lane & 15;

    // a-frags direct from global (f32 -> bf16)
    bf16x8 afr[2][4];
    #pragma unroll
    for (int tt = 0; tt < 2; ++tt) {
        #pragma unroll
        for (int kk = 0; kk < 4; ++kk) {
            const float* p = cur + (size_t)(tb + tt * 16 + llo) * 128 + kk * 32 + lhi * 8;
            bf16x8 v;
            #pragma unroll
            for (int j = 0; j < 8; ++j) v[j] = f2bf(p[j]);
            afr[tt][kk] = v;
        }
    }

    // ---- GEMM1: wave wv owns hn = wv*16 .. wv*16+15 (hidden cols wv*256..)
    f32x4 acc[2][16];
    f32x4 zr = {0.f, 0.f, 0.f, 0.f};
    #pragma unroll
    for (int tt = 0; tt < 2; ++tt)
        #pragma unroll
        for (int nl = 0; nl < 16; ++nl) acc[tt][nl] = zr;

    const short* wbase = w1p + (size_t)(wv * 16) * 4 * 64 * 8;
    #pragma unroll 4
    for (int nl = 0; nl < 16; ++nl) {
        #pragma unroll
        for (int kk = 0; kk < 4; ++kk) {
            bf16x8 bf = *(const bf16x8*)(wbase + ((size_t)(nl * 4 + kk) * 64 + lane) * 8);
            acc[0][nl] = __builtin_amdgcn_mfma_f32_16x16x32_bf16(bf, afr[0][kk], acc[0][nl], 0, 0, 0);
            acc[1][nl] = __builtin_amdgcn_mfma_f32_16x16x32_bf16(bf, afr[1][kk], acc[1][nl], 0, 0, 0);
        }
    }

    // epilogue: bias + gelu + pack to hs (GEMM2 frag order)
    #pragma unroll
    for (int nl = 0; nl < 16; ++nl) {
        int hn = wv * 16 + nl;
        int hc0 = hn * 16 + lhi * 4;
        f32x4 bv = *(const f32x4*)(b1 + hc0);
        int kk2 = hn >> 1;
        int lp = llo + 16 * ((hn & 1) * 2 + (lhi >> 1));
        #pragma unroll
        for (int tt = 0; tt < 2; ++tt) {
            f32x4 a = acc[tt][nl] + bv;
            float g0 = 0.5f * a.x * (1.f + erff(a.x * 0.70710678118654752f));
            float g1 = 0.5f * a.y * (1.f + erff(a.y * 0.70710678118654752f));
            float g2 = 0.5f * a.z * (1.f + erff(a.z * 0.70710678118654752f));
            float g3 = 0.5f * a.w * (1.f + erff(a.w * 0.70710678118654752f));
            uint2 wv2;
            wv2.x = pack2bf(g0, g1);
            wv2.y = pack2bf(g2, g3);
            *(uint2*)((char*)hs + ((size_t)(tt * 32 + kk2) * 64 + lp) * 16 + (lhi & 1) * 8) = wv2;
        }
    }
    __syncthreads();

    // ---- GEMM2: wave wv owns cout blocks {wv*2, wv*2+1}
    f32x4 acc2[2][2];
    #pragma unroll
    for (int cn = 0; cn < 2; ++cn)
        #pragma unroll
        for (int tt = 0; tt < 2; ++tt) acc2[cn][tt] = zr;

    const short* w2base = w2p + (size_t)(wv * 2) * 32 * 64 * 8;
    #pragma unroll 4
    for (int kk2 = 0; kk2 < 32; ++kk2) {
        bf16x8 h0 = *(const bf16x8*)&hs[((size_t)(0 * 32 + kk2) * 64 + lane) * 8];
        bf16x8 h1 = *(const bf16x8*)&hs[((size_t)(1 * 32 + kk2) * 64 + lane) * 8];
        bf16x8 w0 = *(const bf16x8*)(w2base + ((size_t)(0 * 32 + kk2) * 64 + lane) * 8);
        bf16x8 w1f = *(const bf16x8*)(w2base + ((size_t)(1 * 32 + kk2) * 64 + lane) * 8);
        acc2[0][0] = __builtin_amdgcn_mfma_f32_16x16x32_bf16(w0, h0, acc2[0][0], 0, 0, 0);
        acc2[0][1] = __builtin_amdgcn_mfma_f32_16x16x32_bf16(w0, h1, acc2[0][1], 0, 0, 0);
        acc2[1][0] = __builtin_amdgcn_mfma_f32_16x16x32_bf16(w1f, h0, acc2[1][0], 0, 0, 0);
        acc2[1][1] = __builtin_amdgcn_mfma_f32_16x16x32_bf16(w1f, h1, acc2[1][1], 0, 0, 0);
    }

    // epilogue: += bias + residual (out already holds x + attn)
    #pragma unroll
    for (int cn = 0; cn < 2; ++cn) {
        int c0 = (wv * 2 + cn) * 16 + lhi * 4;
        f32x4 bv = *(const f32x4*)(b2 + c0);
        #pragma unroll
        for (int tt = 0; tt < 2; ++tt) {
            float* op = out + (size_t)(tb + tt * 16 + llo) * 128 + c0;
            f32x4 r = *(f32x4*)op;
            r = r + acc2[cn][tt] + bv;
            *(f32x4*)op = r;
        }
    }
}

extern "C" void kernel_launch(void* const* d_in, const int* in_sizes, int n_in,
                              void* d_out, int out_size, void* d_ws, size_t ws_size,
                              hipStream_t stream) {
    const float* img   = (const float*)d_in[0];
    const float* dl    = (const float*)d_in[1];
    const float* pe_dw = (const float*)d_in[2];
    const float* pe_pw = (const float*)d_in[3];
    const float* bn_g  = (const float*)d_in[4];
    const float* bn_b  = (const float*)d_in[5];
    const float* bn_m  = (const float*)d_in[6];
    const float* bn_v  = (const float*)d_in[7];
    const float* cpe_w = (const float*)d_in[8];
    const float* cpe_b = (const float*)d_in[9];
    const float* n1_g  = (const float*)d_in[10];
    const float* n1_b  = (const float*)d_in[11];
    const float* qkv_w = (const float*)d_in[12];
    const float* qkv_b = (const float*)d_in[13];
    const float* w3    = (const float*)d_in[14];
    const float* b3    = (const float*)d_in[15];
    const float* w5    = (const float*)d_in[16];
    const float* b5    = (const float*)d_in[17];
    const float* w7    = (const float*)d_in[18];
    const float* b7    = (const float*)d_in[19];
    const float* dw1   = (const float*)d_in[20];
    const float* db1   = (const float*)d_in[21];
    const float* dw2   = (const float*)d_in[22];
    const float* db2   = (const float*)d_in[23];
    const float* pw    = (const float*)d_in[24];
    const float* pb    = (const float*)d_in[25];
    const float* n2_g  = (const float*)d_in[26];
    const float* n2_b  = (const float*)d_in[27];
    const float* f1w   = (const float*)d_in[28];
    const float* f1b   = (const float*)d_in[29];
    const float* f2w   = (const float*)d_in[30];
    const float* f2b   = (const float*)d_in[31];
    const int*   dptr  = (const int*)d_in[32];
    float* out = (float*)d_out;

    char* ws = (char*)d_ws;
    const size_t SZ = (size_t)8 * 128 * 4096 * 4;   // 16,777,216 bytes
    float* t1    = (float*)(ws);            // also cur (post-LN)
    float* x     = (float*)(ws + SZ);
    float* q     = (float*)(ws + 2 * SZ);   // reused for w1p/w2p after att
    float* k_img = (float*)(ws + 3 * SZ);   // also att after kv
    float* v_img = (float*)(ws + 4 * SZ);
    float* kv    = (float*)(ws + 5 * SZ);
    float* da    = (float*)(ws + 5 * SZ + 65536);
    short* w1p   = (short*)(ws + 2 * SZ);            // 256KB (in dead q)
    short* w2p   = (short*)(ws + 2 * SZ + 262144);   // 256KB

    pe_kernel<<<512, 256, 0, stream>>>(img, pe_dw, pe_pw, bn_g, bn_b, bn_m, bn_v, dptr, t1);
    cpe_kernel<<<2048, 256, 0, stream>>>(t1, cpe_w, cpe_b, x);
    ln_kernel<<<8192, 256, 0, stream>>>(x, t1, n1_g, n1_b, dptr);
    qkv_kernel<<<dim3(1024, 3), 256, 0, stream>>>(t1, qkv_w, qkv_b, q, k_img, v_img);
    softmax_kernel<<<1024, 256, 0, stream>>>(k_img);
    kv_kernel<<<64, 256, 0, stream>>>(k_img, v_img, kv);
    gate_kernel<<<1, 256, 0, stream>>>(dl, dw1, db1, dw2, db2, da);
    att_kernel<<<1024, 256, 0, stream>>>(q, v_img, kv, da, w3, b3, w5, b5, w7, b7, k_img);
    proj_kernel<<<1024, 256, 0, stream>>>(k_img, pw, pb, x, out);
    pack_w1_kernel<<<64, 256, 0, stream>>>(f1w, w1p);
    pack_w2_kernel<<<64, 256, 0, stream>>>(f2w, w2p);
    ln_kernel<<<8192, 256, 0, stream>>>(out, t1, n2_g, n2_b, dptr);
    mlp_mfma_kernel<<<1024, 256, 0, stream>>>(t1, w1p, f1b, w2p, f2b, out);
}

// Round 4
// 552.004 us; speedup vs baseline: 3.0711x; 1.2949x over previous
//
#include <hip/hip_runtime.h>
#include <math.h>

#define EPS_LN 1e-6f
#define EPS_BN 1e-5f

typedef __attribute__((ext_vector_type(8))) short bf16x8;
typedef __attribute__((ext_vector_type(4))) float f32x4;

__device__ __forceinline__ float wave_reduce_sum(float v) {
    #pragma unroll
    for (int m = 32; m >= 1; m >>= 1) v += __shfl_xor(v, m, 64);
    return v;
}
__device__ __forceinline__ float wave_reduce_max(float v) {
    #pragma unroll
    for (int m = 32; m >= 1; m >>= 1) v = fmaxf(v, __shfl_xor(v, m, 64));
    return v;
}
__device__ __forceinline__ short f2bf(float f) {
    union { float f; unsigned u; } v; v.f = f;
    unsigned r = v.u + 0x7fff + ((v.u >> 16) & 1);
    return (short)(r >> 16);
}
__device__ __forceinline__ unsigned pack2bf(float a, float b) {
    return (unsigned)(unsigned short)f2bf(a) | ((unsigned)(unsigned short)f2bf(b) << 16);
}

// ---------------- patch embed: dw3x3 s2 + pw 64->128 + BN(d) + hardswish ----
__global__ __launch_bounds__(256) void pe_kernel(
    const float* __restrict__ img, const float* __restrict__ dww,
    const float* __restrict__ pww, const float* __restrict__ bn_g,
    const float* __restrict__ bn_b, const float* __restrict__ bn_m,
    const float* __restrict__ bn_v, const int* __restrict__ dptr,
    float* __restrict__ t1) {
    __shared__ float dw[64 * 65];
    int bx = blockIdx.x;
    int b = bx >> 6, y = bx & 63;
    int tid = threadIdx.x;
    int d = *dptr;
    for (int idx = tid; idx < 4096; idx += 256) {
        int ci = idx >> 6, xx = idx & 63;
        const float* ip = img + (size_t)(b * 64 + ci) * 128 * 128;
        float acc = 0.f;
        #pragma unroll
        for (int r = 0; r < 3; ++r) {
            int iy = 2 * y + r;
            if (iy >= 128) continue;
            #pragma unroll
            for (int s = 0; s < 3; ++s) {
                int ix = 2 * xx + s;
                if (ix >= 128) continue;
                acc += ip[iy * 128 + ix] * dww[ci * 9 + r * 3 + s];
            }
        }
        dw[ci * 65 + xx] = acc;
    }
    __syncthreads();
    for (int idx = tid; idx < 8192; idx += 256) {
        int co = idx >> 6, xx = idx & 63;
        float acc = 0.f;
        const float* wp = pww + co * 64;
        for (int ci = 0; ci < 64; ++ci)
            acc += dw[ci * 65 + xx] * wp[ci];
        float sc = bn_g[d * 128 + co] * rsqrtf(bn_v[d * 128 + co] + EPS_BN);
        float v = (acc - bn_m[d * 128 + co]) * sc + bn_b[d * 128 + co];
        v = v * fminf(fmaxf(v + 3.f, 0.f), 6.f) * (1.f / 6.f);
        t1[(size_t)(b * 128 + co) * 4096 + y * 64 + xx] = v;
    }
}

// ---------------- ConvPosEnc ----------------
__global__ __launch_bounds__(256) void cpe_kernel(
    const float* __restrict__ t1, const float* __restrict__ cw,
    const float* __restrict__ cb, float* __restrict__ xout) {
    int bx = blockIdx.x;
    int cq = bx & 3, y = (bx >> 2) & 63, b = bx >> 8;
    int c0 = cq * 32;
    __shared__ float s[3 * 32 * 65];
    int tid = threadIdx.x;
    for (int idx = tid; idx < 3 * 32 * 64; idx += 256) {
        int xx = idx & 63;
        int cl = (idx >> 6) & 31;
        int dy = idx >> 11;
        int yy = y + dy - 1;
        float v = 0.f;
        if (yy >= 0 && yy < 64)
            v = t1[(size_t)(b * 128 + c0 + cl) * 4096 + yy * 64 + xx];
        s[(dy * 32 + cl) * 65 + xx] = v;
    }
    __syncthreads();
    for (int idx = tid; idx < 32 * 64; idx += 256) {
        int cl = idx & 31;
        int xx = idx >> 5;
        int c = c0 + cl;
        float center = s[(32 + cl) * 65 + xx];
        float acc = cb[c];
        #pragma unroll
        for (int dy = 0; dy < 3; ++dy) {
            #pragma unroll
            for (int dx = 0; dx < 3; ++dx) {
                int sx = xx + dx - 1;
                if (sx < 0 || sx >= 64) continue;
                acc += s[(dy * 32 + cl) * 65 + sx] * cw[c * 9 + dy * 3 + dx];
            }
        }
        xout[(size_t)(b * 4096 + y * 64 + xx) * 128 + c] = center + acc;
    }
}

// ---------------- LayerNorm over C=128 ------------------
__global__ __launch_bounds__(256) void ln_kernel(
    const float* __restrict__ src, float* __restrict__ dst,
    const float* __restrict__ g, const float* __restrict__ bb,
    const int* __restrict__ dptr) {
    int d = *dptr;
    int wid = threadIdx.x >> 6, lane = threadIdx.x & 63;
    size_t t = (size_t)blockIdx.x * 4 + wid;
    const float* p = src + t * 128;
    float v0 = p[lane], v1 = p[lane + 64];
    float mean = wave_reduce_sum(v0 + v1) * (1.f / 128.f);
    float d0 = v0 - mean, d1 = v1 - mean;
    float var = wave_reduce_sum(d0 * d0 + d1 * d1) * (1.f / 128.f);
    float rs = rsqrtf(var + EPS_LN);
    dst[t * 128 + lane]      = d0 * rs * g[d * 128 + lane]      + bb[d * 128 + lane];
    dst[t * 128 + lane + 64] = d1 * rs * g[d * 128 + lane + 64] + bb[d * 128 + lane + 64];
}

// ---------------- weight packers into MFMA frag order ----------------------
// entry (n,kk,l): holds W[kk*32+(l>>4)*8+j][n*16+(l&15)], j=0..7, for W (K x Ncols)
__global__ __launch_bounds__(256) void pack_qkv_kernel(
    const float* __restrict__ w, short* __restrict__ wp) {
    int idx = blockIdx.x * 256 + threadIdx.x;   // 6144 = 24 n * 4 kk * 64 l
    int l = idx & 63, kk = (idx >> 6) & 3, n = idx >> 8;
    int k0 = kk * 32 + (l >> 4) * 8;
    int c = n * 16 + (l & 15);
    bf16x8 v;
    #pragma unroll
    for (int j = 0; j < 8; ++j) v[j] = f2bf(w[(size_t)(k0 + j) * 384 + c]);
    *(bf16x8*)&wp[(size_t)idx * 8] = v;
}
__global__ __launch_bounds__(256) void pack_pw_kernel(
    const float* __restrict__ w, short* __restrict__ wp) {
    int idx = blockIdx.x * 256 + threadIdx.x;   // 2048 = 8 n * 4 kk * 64 l
    int l = idx & 63, kk = (idx >> 6) & 3, n = idx >> 8;
    int k0 = kk * 32 + (l >> 4) * 8;
    int c = n * 16 + (l & 15);
    bf16x8 v;
    #pragma unroll
    for (int j = 0; j < 8; ++j) v[j] = f2bf(w[(size_t)(k0 + j) * 128 + c]);
    *(bf16x8*)&wp[(size_t)idx * 8] = v;
}
__global__ __launch_bounds__(256) void pack_w1_kernel(
    const float* __restrict__ w1, short* __restrict__ w1p) {
    int idx = blockIdx.x * 256 + threadIdx.x;   // 16384
    int l = idx & 63, kk = (idx >> 6) & 3, n = idx >> 8;
    int k0 = kk * 32 + (l >> 4) * 8;
    int c = n * 16 + (l & 15);
    bf16x8 v;
    #pragma unroll
    for (int j = 0; j < 8; ++j) v[j] = f2bf(w1[(size_t)(k0 + j) * 1024 + c]);
    *(bf16x8*)&w1p[(size_t)idx * 8] = v;
}
__global__ __launch_bounds__(256) void pack_w2_kernel(
    const float* __restrict__ w2, short* __restrict__ w2p) {
    int idx = blockIdx.x * 256 + threadIdx.x;   // 16384
    int l = idx & 63, kk = (idx >> 6) & 31, n = idx >> 11;
    int k0 = kk * 32 + (l >> 4) * 8;
    int c = n * 16 + (l & 15);
    bf16x8 v;
    #pragma unroll
    for (int j = 0; j < 8; ++j) v[j] = f2bf(w2[(size_t)(k0 + j) * 128 + c]);
    *(bf16x8*)&w2p[(size_t)idx * 8] = v;
}

// ---------------- MFMA QKV: 32 tok/block, D[channel][token] ----------------
// grid 1024, block 256 (4 waves). wave wv owns channel blocks wv*6..wv*6+5.
// channels 0-127 -> q (token layout); 128-255 -> k_img; 256-383 -> v_img.
__global__ __launch_bounds__(256, 2) void qkv_mfma_kernel(
    const float* __restrict__ cur, const short* __restrict__ wp,
    const float* __restrict__ bias, float* __restrict__ q,
    float* __restrict__ k_img, float* __restrict__ v_img) {
    int tb = blockIdx.x * 32;
    int tid = threadIdx.x;
    int lane = tid & 63, wv = tid >> 6;
    int lhi = lane >> 4, llo = lane & 15;
    int b = tb >> 12, n0 = tb & 4095;

    bf16x8 afr[2][4];
    #pragma unroll
    for (int tt = 0; tt < 2; ++tt) {
        #pragma unroll
        for (int kk = 0; kk < 4; ++kk) {
            const float* p = cur + (size_t)(tb + tt * 16 + llo) * 128 + kk * 32 + lhi * 8;
            bf16x8 v;
            #pragma unroll
            for (int j = 0; j < 8; ++j) v[j] = f2bf(p[j]);
            afr[tt][kk] = v;
        }
    }

    f32x4 acc[6][2];
    f32x4 zr = {0.f, 0.f, 0.f, 0.f};
    #pragma unroll
    for (int i = 0; i < 6; ++i) { acc[i][0] = zr; acc[i][1] = zr; }

    #pragma unroll
    for (int i = 0; i < 6; ++i) {
        int nb = wv * 6 + i;
        #pragma unroll
        for (int kk = 0; kk < 4; ++kk) {
            bf16x8 wf = *(const bf16x8*)&wp[((size_t)(nb * 4 + kk) * 64 + lane) * 8];
            acc[i][0] = __builtin_amdgcn_mfma_f32_16x16x32_bf16(wf, afr[0][kk], acc[i][0], 0, 0, 0);
            acc[i][1] = __builtin_amdgcn_mfma_f32_16x16x32_bf16(wf, afr[1][kk], acc[i][1], 0, 0, 0);
        }
    }

    #pragma unroll
    for (int i = 0; i < 6; ++i) {
        int j0 = (wv * 6 + i) * 16;
        f32x4 bv = *(const f32x4*)(bias + j0 + lhi * 4);
        #pragma unroll
        for (int tt = 0; tt < 2; ++tt) {
            f32x4 r = acc[i][tt] + bv;
            int t = tb + tt * 16 + llo;
            if (j0 < 128) {
                *(f32x4*)(q + (size_t)t * 128 + j0 + lhi * 4) = r;
            } else {
                float* dst = (j0 < 256) ? k_img : v_img;
                int c0 = (j0 & 127) + lhi * 4;
                float* p = dst + (size_t)(b * 128 + c0) * 4096 + n0 + tt * 16 + llo;
                p[0]        = r.x;
                p[4096]     = r.y;
                p[2 * 4096] = r.z;
                p[3 * 4096] = r.w;
            }
        }
    }
}

// ---------------- softmax over N ---------------
__global__ __launch_bounds__(256) void softmax_kernel(float* __restrict__ k_img) {
    __shared__ float red[4];
    float* p = k_img + (size_t)blockIdx.x * 4096;
    int tid = threadIdx.x;
    float v[16];
    float mx = -1e30f;
    #pragma unroll
    for (int i = 0; i < 16; ++i) {
        v[i] = p[tid + i * 256];
        mx = fmaxf(mx, v[i]);
    }
    mx = wave_reduce_max(mx);
    int wid = tid >> 6, lane = tid & 63;
    if (lane == 0) red[wid] = mx;
    __syncthreads();
    mx = fmaxf(fmaxf(red[0], red[1]), fmaxf(red[2], red[3]));
    __syncthreads();
    float sum = 0.f;
    #pragma unroll
    for (int i = 0; i < 16; ++i) {
        v[i] = expf(v[i] - mx);
        sum += v[i];
    }
    sum = wave_reduce_sum(sum);
    if (lane == 0) red[wid] = sum;
    __syncthreads();
    float inv = 1.f / (red[0] + red[1] + red[2] + red[3]);
    #pragma unroll
    for (int i = 0; i < 16; ++i)
        p[tid + i * 256] = v[i] * inv;
}

// ---------------- kv partial: grid 512 = bh*8+chunk, n-chunk of 512 --------
__global__ __launch_bounds__(256) void kv_part_kernel(
    const float* __restrict__ k_img, const float* __restrict__ v_img,
    float* __restrict__ kvp) {
    __shared__ float ks[16 * 132], vs[16 * 132];
    int bc = blockIdx.x;
    int bh = bc >> 3, chunk = bc & 7;
    int b = bh >> 3, h = bh & 7;
    int tid = threadIdx.x;
    int ck = tid >> 4, cv = tid & 15;
    float acc = 0.f;
    const float* kp = k_img + (size_t)(b * 128 + h * 16) * 4096;
    const float* vp = v_img + (size_t)(b * 128 + h * 16) * 4096;
    int nb0 = chunk * 512;
    for (int nb = nb0; nb < nb0 + 512; nb += 128) {
        for (int idx = tid; idx < 2048; idx += 256) {
            int r = idx >> 7, col = idx & 127;
            ks[r * 132 + col] = kp[(size_t)r * 4096 + nb + col];
            vs[r * 132 + col] = vp[(size_t)r * 4096 + nb + col];
        }
        __syncthreads();
        for (int kk = 0; kk < 128; ++kk)
            acc += ks[ck * 132 + kk] * vs[cv * 132 + kk];
        __syncthreads();
    }
    kvp[(size_t)(chunk * 64 + bh) * 256 + ck * 16 + cv] = acc;
}
__global__ __launch_bounds__(256) void kv_reduce_kernel(
    const float* __restrict__ kvp, float* __restrict__ kv) {
    int i = blockIdx.x * 256 + threadIdx.x;   // 16384
    float s = 0.f;
    #pragma unroll
    for (int c = 0; c < 8; ++c) s += kvp[(size_t)c * 16384 + i];
    kv[i] = s;
}

// ---------------- domain gate --------------------------------
__global__ __launch_bounds__(256) void gate_kernel(
    const float* __restrict__ dl, const float* __restrict__ w1,
    const float* __restrict__ b1, const float* __restrict__ w2,
    const float* __restrict__ b2, float* __restrict__ da) {
    __shared__ float hid[512];
    __shared__ float raw[1024];
    int tid = threadIdx.x;
    for (int idx = tid; idx < 512; idx += 256) {
        int b = idx >> 6, jj = idx & 63;
        float a = b1[jj];
        #pragma unroll
        for (int dd = 0; dd < 4; ++dd)
            a += dl[b * 4 + dd] * w1[dd * 64 + jj];
        hid[idx] = fmaxf(a, 0.f);
    }
    __syncthreads();
    for (int idx = tid; idx < 1024; idx += 256) {
        int b = idx >> 7, c = idx & 127;
        float a = b2[c];
        for (int jj = 0; jj < 64; ++jj)
            a += hid[b * 64 + jj] * w2[jj * 128 + c];
        raw[idx] = a;
    }
    __syncthreads();
    if (tid < 128) {
        int b = tid >> 4, ch = tid & 15;
        float mx = -1e30f;
        #pragma unroll
        for (int hh = 0; hh < 8; ++hh)
            mx = fmaxf(mx, raw[b * 128 + hh * 16 + ch]);
        float e[8];
        float s = 0.f;
        #pragma unroll
        for (int hh = 0; hh < 8; ++hh) {
            e[hh] = expf(raw[b * 128 + hh * 16 + ch] - mx);
            s += e[hh];
        }
        float inv = 1.f / s;
        #pragma unroll
        for (int hh = 0; hh < 8; ++hh)
            da[b * 128 + hh * 16 + ch] = e[hh] * inv;
    }
}

// ---------------- crpe conv + factor-att combine -------
__global__ __launch_bounds__(256) void att_kernel(
    const float* __restrict__ q, const float* __restrict__ v_img,
    const float* __restrict__ kv, const float* __restrict__ da,
    const float* __restrict__ w3, const float* __restrict__ b3,
    const float* __restrict__ w5, const float* __restrict__ b5,
    const float* __restrict__ w7, const float* __restrict__ b7,
    float* __restrict__ att) {
    __shared__ float s[64 * 65];
    __shared__ float wsm[49];
    int bx = blockIdx.x;
    int b = bx >> 7, c = bx & 127;
    int h = c >> 4, cvi = c & 15;
    int tid = threadIdx.x;
    const float* vp = v_img + (size_t)(b * 128 + c) * 4096;
    for (int idx = tid; idx < 4096; idx += 256)
        s[(idx >> 6) * 65 + (idx & 63)] = vp[idx];
    int kc; const float* wp; float bias;
    if (c < 32)      { kc = 3; wp = w3 + c * 9;        bias = b3[c]; }
    else if (c < 80) { kc = 5; wp = w5 + (c - 32) * 25; bias = b5[c - 32]; }
    else             { kc = 7; wp = w7 + (c - 80) * 49; bias = b7[c - 80]; }
    if (tid < kc * kc) wsm[tid] = wp[tid];
    float kvr[16];
    #pragma unroll
    for (int ck = 0; ck < 16; ++ck)
        kvr[ck] = kv[((size_t)(b * 8 + h) * 16 + ck) * 16 + cvi];
    float dac = da[b * 128 + c];
    int off = kc >> 1;
    __syncthreads();
    for (int i = 0; i < 16; ++i) {
        int n = tid + i * 256;
        int y = n >> 6, xx = n & 63;
        float acc = bias;
        for (int dy = 0; dy < kc; ++dy) {
            int sy = y + dy - off;
            if (sy < 0 || sy >= 64) continue;
            for (int dx = 0; dx < kc; ++dx) {
                int sx = xx + dx - off;
                if (sx < 0 || sx >= 64) continue;
                acc += s[sy * 65 + sx] * wsm[dy * kc + dx];
            }
        }
        const float* qp = q + (size_t)(b * 4096 + n) * 128 + h * 16;
        float fa = 0.f;
        #pragma unroll
        for (int ck = 0; ck < 16; ++ck)
            fa += qp[ck] * kvr[ck];
        att[(size_t)(b * 128 + c) * 4096 + n] = dac * (0.25f * fa + qp[cvi] * acc);
    }
}

// ---------------- MFMA proj + residual: A = att (image layout) -------------
// grid 1024, block 256. Stage 128c x 32t f32 tile in LDS, frags from LDS.
__global__ __launch_bounds__(256, 2) void proj_mfma_kernel(
    const float* __restrict__ att, const short* __restrict__ wp,
    const float* __restrict__ bias, const float* __restrict__ xres,
    float* __restrict__ out) {
    __shared__ float As[128 * 33];
    int tb = blockIdx.x * 32;
    int tid = threadIdx.x;
    int lane = tid & 63, wv = tid >> 6;
    int lhi = lane >> 4, llo = lane & 15;
    int b = tb >> 12, n0 = tb & 4095;

    for (int idx = tid; idx < 4096; idx += 256) {
        int c = idx >> 5, t = idx & 31;
        As[c * 33 + t] = att[(size_t)(b * 128 + c) * 4096 + n0 + t];
    }
    __syncthreads();

    bf16x8 afr[2][4];
    #pragma unroll
    for (int tt = 0; tt < 2; ++tt) {
        #pragma unroll
        for (int kk = 0; kk < 4; ++kk) {
            int c0 = kk * 32 + lhi * 8;
            int t = tt * 16 + llo;
            bf16x8 v;
            #pragma unroll
            for (int j = 0; j < 8; ++j) v[j] = f2bf(As[(c0 + j) * 33 + t]);
            afr[tt][kk] = v;
        }
    }

    f32x4 acc[2][2];
    f32x4 zr = {0.f, 0.f, 0.f, 0.f};
    #pragma unroll
    for (int i = 0; i < 2; ++i) { acc[i][0] = zr; acc[i][1] = zr; }

    #pragma unroll
    for (int i = 0; i < 2; ++i) {
        int nb = wv * 2 + i;
        #pragma unroll
        for (int kk = 0; kk < 4; ++kk) {
            bf16x8 wf = *(const bf16x8*)&wp[((size_t)(nb * 4 + kk) * 64 + lane) * 8];
            acc[i][0] = __builtin_amdgcn_mfma_f32_16x16x32_bf16(wf, afr[0][kk], acc[i][0], 0, 0, 0);
            acc[i][1] = __builtin_amdgcn_mfma_f32_16x16x32_bf16(wf, afr[1][kk], acc[i][1], 0, 0, 0);
        }
    }

    #pragma unroll
    for (int i = 0; i < 2; ++i) {
        int j0 = (wv * 2 + i) * 16;
        f32x4 bv = *(const f32x4*)(bias + j0 + lhi * 4);
        #pragma unroll
        for (int tt = 0; tt < 2; ++tt) {
            size_t o = (size_t)(tb + tt * 16 + llo) * 128 + j0 + lhi * 4;
            f32x4 xr = *(const f32x4*)(xres + o);
            *(f32x4*)(out + o) = xr + acc[i][tt] + bv;
        }
    }
}

// ---------------- fused MFMA MLP (32 tok/block, hid in LDS frag order) -----
__global__ __launch_bounds__(256, 2) void mlp_mfma_kernel(
    const float* __restrict__ cur, const short* __restrict__ w1p,
    const float* __restrict__ b1, const short* __restrict__ w2p,
    const float* __restrict__ b2, float* __restrict__ out) {
    __shared__ short hs[32768];
    int tb = blockIdx.x * 32;
    int tid = threadIdx.x;
    int lane = tid & 63, wv = tid >> 6;
    int lhi = lane >> 4, llo = lane & 15;

    bf16x8 afr[2][4];
    #pragma unroll
    for (int tt = 0; tt < 2; ++tt) {
        #pragma unroll
        for (int kk = 0; kk < 4; ++kk) {
            const float* p = cur + (size_t)(tb + tt * 16 + llo) * 128 + kk * 32 + lhi * 8;
            bf16x8 v;
            #pragma unroll
            for (int j = 0; j < 8; ++j) v[j] = f2bf(p[j]);
            afr[tt][kk] = v;
        }
    }

    f32x4 acc[2][16];
    f32x4 zr = {0.f, 0.f, 0.f, 0.f};
    #pragma unroll
    for (int tt = 0; tt < 2; ++tt)
        #pragma unroll
        for (int nl = 0; nl < 16; ++nl) acc[tt][nl] = zr;

    const short* wbase = w1p + (size_t)(wv * 16) * 4 * 64 * 8;
    #pragma unroll 4
    for (int nl = 0; nl < 16; ++nl) {
        #pragma unroll
        for (int kk = 0; kk < 4; ++kk) {
            bf16x8 bf = *(const bf16x8*)(wbase + ((size_t)(nl * 4 + kk) * 64 + lane) * 8);
            acc[0][nl] = __builtin_amdgcn_mfma_f32_16x16x32_bf16(bf, afr[0][kk], acc[0][nl], 0, 0, 0);
            acc[1][nl] = __builtin_amdgcn_mfma_f32_16x16x32_bf16(bf, afr[1][kk], acc[1][nl], 0, 0, 0);
        }
    }

    #pragma unroll
    for (int nl = 0; nl < 16; ++nl) {
        int hn = wv * 16 + nl;
        int hc0 = hn * 16 + lhi * 4;
        f32x4 bv = *(const f32x4*)(b1 + hc0);
        int kk2 = hn >> 1;
        int lp = llo + 16 * ((hn & 1) * 2 + (lhi >> 1));
        #pragma unroll
        for (int tt = 0; tt < 2; ++tt) {
            f32x4 a = acc[tt][nl] + bv;
            float g0 = 0.5f * a.x * (1.f + erff(a.x * 0.70710678118654752f));
            float g1 = 0.5f * a.y * (1.f + erff(a.y * 0.70710678118654752f));
            float g2 = 0.5f * a.z * (1.f + erff(a.z * 0.70710678118654752f));
            float g3 = 0.5f * a.w * (1.f + erff(a.w * 0.70710678118654752f));
            uint2 wv2;
            wv2.x = pack2bf(g0, g1);
            wv2.y = pack2bf(g2, g3);
            *(uint2*)((char*)hs + ((size_t)(tt * 32 + kk2) * 64 + lp) * 16 + (lhi & 1) * 8) = wv2;
        }
    }
    __syncthreads();

    f32x4 acc2[2][2];
    #pragma unroll
    for (int cn = 0; cn < 2; ++cn)
        #pragma unroll
        for (int tt = 0; tt < 2; ++tt) acc2[cn][tt] = zr;

    const short* w2base = w2p + (size_t)(wv * 2) * 32 * 64 * 8;
    #pragma unroll 4
    for (int kk2 = 0; kk2 < 32; ++kk2) {
        bf16x8 h0 = *(const bf16x8*)&hs[((size_t)(0 * 32 + kk2) * 64 + lane) * 8];
        bf16x8 h1 = *(const bf16x8*)&hs[((size_t)(1 * 32 + kk2) * 64 + lane) * 8];
        bf16x8 w0 = *(const bf16x8*)(w2base + ((size_t)(0 * 32 + kk2) * 64 + lane) * 8);
        bf16x8 w1f = *(const bf16x8*)(w2base + ((size_t)(1 * 32 + kk2) * 64 + lane) * 8);
        acc2[0][0] = __builtin_amdgcn_mfma_f32_16x16x32_bf16(w0, h0, acc2[0][0], 0, 0, 0);
        acc2[0][1] = __builtin_amdgcn_mfma_f32_16x16x32_bf16(w0, h1, acc2[0][1], 0, 0, 0);
        acc2[1][0] = __builtin_amdgcn_mfma_f32_16x16x32_bf16(w1f, h0, acc2[1][0], 0, 0, 0);
        acc2[1][1] = __builtin_amdgcn_mfma_f32_16x16x32_bf16(w1f, h1, acc2[1][1], 0, 0, 0);
    }

    #pragma unroll
    for (int cn = 0; cn < 2; ++cn) {
        int c0 = (wv * 2 + cn) * 16 + lhi * 4;
        f32x4 bv = *(const f32x4*)(b2 + c0);
        #pragma unroll
        for (int tt = 0; tt < 2; ++tt) {
            float* op = out + (size_t)(tb + tt * 16 + llo) * 128 + c0;
            f32x4 r = *(f32x4*)op;
            r = r + acc2[cn][tt] + bv;
            *(f32x4*)op = r;
        }
    }
}

extern "C" void kernel_launch(void* const* d_in, const int* in_sizes, int n_in,
                              void* d_out, int out_size, void* d_ws, size_t ws_size,
                              hipStream_t stream) {
    const float* img   = (const float*)d_in[0];
    const float* dl    = (const float*)d_in[1];
    const float* pe_dw = (const float*)d_in[2];
    const float* pe_pw = (const float*)d_in[3];
    const float* bn_g  = (const float*)d_in[4];
    const float* bn_b  = (const float*)d_in[5];
    const float* bn_m  = (const float*)d_in[6];
    const float* bn_v  = (const float*)d_in[7];
    const float* cpe_w = (const float*)d_in[8];
    const float* cpe_b = (const float*)d_in[9];
    const float* n1_g  = (const float*)d_in[10];
    const float* n1_b  = (const float*)d_in[11];
    const float* qkv_w = (const float*)d_in[12];
    const float* qkv_b = (const float*)d_in[13];
    const float* w3    = (const float*)d_in[14];
    const float* b3    = (const float*)d_in[15];
    const float* w5    = (const float*)d_in[16];
    const float* b5    = (const float*)d_in[17];
    const float* w7    = (const float*)d_in[18];
    const float* b7    = (const float*)d_in[19];
    const float* dw1   = (const float*)d_in[20];
    const float* db1   = (const float*)d_in[21];
    const float* dw2   = (const float*)d_in[22];
    const float* db2   = (const float*)d_in[23];
    const float* pw    = (const float*)d_in[24];
    const float* pb    = (const float*)d_in[25];
    const float* n2_g  = (const float*)d_in[26];
    const float* n2_b  = (const float*)d_in[27];
    const float* f1w   = (const float*)d_in[28];
    const float* f1b   = (const float*)d_in[29];
    const float* f2w   = (const float*)d_in[30];
    const float* f2b   = (const float*)d_in[31];
    const int*   dptr  = (const int*)d_in[32];
    float* out = (float*)d_out;

    char* ws = (char*)d_ws;
    const size_t SZ = (size_t)8 * 128 * 4096 * 4;   // 16,777,216 bytes
    float* t1    = (float*)(ws);            // also cur (post-LN)
    float* x     = (float*)(ws + SZ);
    float* q     = (float*)(ws + 2 * SZ);   // dead after att -> w1p/w2p
    float* k_img = (float*)(ws + 3 * SZ);   // att output after kv
    float* v_img = (float*)(ws + 4 * SZ);
    float* kv    = (float*)(ws + 5 * SZ);                  // 64KB
    float* da    = (float*)(ws + 5 * SZ + 0x10000);        // 4KB
    short* qkvp  = (short*)(ws + 5 * SZ + 0x20000);        // 96KB
    short* pwp   = (short*)(ws + 5 * SZ + 0x40000);        // 32KB
    float* kvp   = (float*)(ws + 5 * SZ + 0x50000);        // 512KB
    short* w1p   = (short*)(ws + 2 * SZ);                  // 256KB (in dead q)
    short* w2p   = (short*)(ws + 2 * SZ + 262144);         // 256KB

    pack_qkv_kernel<<<24, 256, 0, stream>>>(qkv_w, qkvp);
    pack_pw_kernel<<<8, 256, 0, stream>>>(pw, pwp);
    gate_kernel<<<1, 256, 0, stream>>>(dl, dw1, db1, dw2, db2, da);
    pe_kernel<<<512, 256, 0, stream>>>(img, pe_dw, pe_pw, bn_g, bn_b, bn_m, bn_v, dptr, t1);
    cpe_kernel<<<2048, 256, 0, stream>>>(t1, cpe_w, cpe_b, x);
    ln_kernel<<<8192, 256, 0, stream>>>(x, t1, n1_g, n1_b, dptr);
    qkv_mfma_kernel<<<1024, 256, 0, stream>>>(t1, qkvp, qkv_b, q, k_img, v_img);
    softmax_kernel<<<1024, 256, 0, stream>>>(k_img);
    kv_part_kernel<<<512, 256, 0, stream>>>(k_img, v_img, kvp);
    kv_reduce_kernel<<<64, 256, 0, stream>>>(kvp, kv);
    att_kernel<<<1024, 256, 0, stream>>>(q, v_img, kv, da, w3, b3, w5, b5, w7, b7, k_img);
    proj_mfma_kernel<<<1024, 256, 0, stream>>>(k_img, pwp, pb, x, out);
    pack_w1_kernel<<<64, 256, 0, stream>>>(f1w, w1p);
    pack_w2_kernel<<<64, 256, 0, stream>>>(f2w, w2p);
    ln_kernel<<<8192, 256, 0, stream>>>(out, t1, n2_g, n2_b, dptr);
    mlp_mfma_kernel<<<1024, 256, 0, stream>>>(t1, w1p, f1b, w2p, f2b, out);
}

// Round 6
// 481.891 us; speedup vs baseline: 3.5179x; 1.1455x over previous
//
#include <hip/hip_runtime.h>
#include <math.h>

#define EPS_LN 1e-6f
#define EPS_BN 1e-5f

typedef __attribute__((ext_vector_type(8))) short bf16x8;
typedef __attribute__((ext_vector_type(4))) float f32x4;

__device__ __forceinline__ float wave_reduce_sum(float v) {
    #pragma unroll
    for (int m = 32; m >= 1; m >>= 1) v += __shfl_xor(v, m, 64);
    return v;
}
__device__ __forceinline__ float wave_reduce_max(float v) {
    #pragma unroll
    for (int m = 32; m >= 1; m >>= 1) v = fmaxf(v, __shfl_xor(v, m, 64));
    return v;
}
__device__ __forceinline__ short f2bf(float f) {
    union { float f; unsigned u; } v; v.f = f;
    unsigned r = v.u + 0x7fff + ((v.u >> 16) & 1);
    return (short)(r >> 16);
}
__device__ __forceinline__ unsigned pack2bf(float a, float b) {
    return (unsigned)(unsigned short)f2bf(a) | ((unsigned)(unsigned short)f2bf(b) << 16);
}

// ---------------- patch embed: dw3x3 s2 + pw 64->128 + BN(d) + hardswish ----
__global__ __launch_bounds__(256) void pe_kernel(
    const float* __restrict__ img, const float* __restrict__ dww,
    const float* __restrict__ pww, const float* __restrict__ bn_g,
    const float* __restrict__ bn_b, const float* __restrict__ bn_m,
    const float* __restrict__ bn_v, const int* __restrict__ dptr,
    float* __restrict__ t1) {
    __shared__ float dw[64 * 65];
    int bx = blockIdx.x;
    int b = bx >> 6, y = bx & 63;
    int tid = threadIdx.x;
    int d = *dptr;
    for (int idx = tid; idx < 4096; idx += 256) {
        int ci = idx >> 6, xx = idx & 63;
        const float* ip = img + (size_t)(b * 64 + ci) * 128 * 128;
        float acc = 0.f;
        #pragma unroll
        for (int r = 0; r < 3; ++r) {
            int iy = 2 * y + r;
            if (iy >= 128) continue;
            #pragma unroll
            for (int s = 0; s < 3; ++s) {
                int ix = 2 * xx + s;
                if (ix >= 128) continue;
                acc += ip[iy * 128 + ix] * dww[ci * 9 + r * 3 + s];
            }
        }
        dw[ci * 65 + xx] = acc;
    }
    __syncthreads();
    for (int idx = tid; idx < 8192; idx += 256) {
        int co = idx >> 6, xx = idx & 63;
        float acc = 0.f;
        const float* wp = pww + co * 64;
        for (int ci = 0; ci < 64; ++ci)
            acc += dw[ci * 65 + xx] * wp[ci];
        float sc = bn_g[d * 128 + co] * rsqrtf(bn_v[d * 128 + co] + EPS_BN);
        float v = (acc - bn_m[d * 128 + co]) * sc + bn_b[d * 128 + co];
        v = v * fminf(fmaxf(v + 3.f, 0.f), 6.f) * (1.f / 6.f);
        t1[(size_t)(b * 128 + co) * 4096 + y * 64 + xx] = v;
    }
}

// ---------------- ConvPosEnc ----------------
__global__ __launch_bounds__(256) void cpe_kernel(
    const float* __restrict__ t1, const float* __restrict__ cw,
    const float* __restrict__ cb, float* __restrict__ xout) {
    int bx = blockIdx.x;
    int cq = bx & 3, y = (bx >> 2) & 63, b = bx >> 8;
    int c0 = cq * 32;
    __shared__ float s[3 * 32 * 65];
    int tid = threadIdx.x;
    for (int idx = tid; idx < 3 * 32 * 64; idx += 256) {
        int xx = idx & 63;
        int cl = (idx >> 6) & 31;
        int dy = idx >> 11;
        int yy = y + dy - 1;
        float v = 0.f;
        if (yy >= 0 && yy < 64)
            v = t1[(size_t)(b * 128 + c0 + cl) * 4096 + yy * 64 + xx];
        s[(dy * 32 + cl) * 65 + xx] = v;
    }
    __syncthreads();
    for (int idx = tid; idx < 32 * 64; idx += 256) {
        int cl = idx & 31;
        int xx = idx >> 5;
        int c = c0 + cl;
        float center = s[(32 + cl) * 65 + xx];
        float acc = cb[c];
        #pragma unroll
        for (int dy = 0; dy < 3; ++dy) {
            #pragma unroll
            for (int dx = 0; dx < 3; ++dx) {
                int sx = xx + dx - 1;
                if (sx < 0 || sx >= 64) continue;
                acc += s[(dy * 32 + cl) * 65 + sx] * cw[c * 9 + dy * 3 + dx];
            }
        }
        xout[(size_t)(b * 4096 + y * 64 + xx) * 128 + c] = center + acc;
    }
}

// ---------------- LayerNorm over C=128 ------------------
__global__ __launch_bounds__(256) void ln_kernel(
    const float* __restrict__ src, float* __restrict__ dst,
    const float* __restrict__ g, const float* __restrict__ bb,
    const int* __restrict__ dptr) {
    int d = *dptr;
    int wid = threadIdx.x >> 6, lane = threadIdx.x & 63;
    size_t t = (size_t)blockIdx.x * 4 + wid;
    const float* p = src + t * 128;
    float v0 = p[lane], v1 = p[lane + 64];
    float mean = wave_reduce_sum(v0 + v1) * (1.f / 128.f);
    float d0 = v0 - mean, d1 = v1 - mean;
    float var = wave_reduce_sum(d0 * d0 + d1 * d1) * (1.f / 128.f);
    float rs = rsqrtf(var + EPS_LN);
    dst[t * 128 + lane]      = d0 * rs * g[d * 128 + lane]      + bb[d * 128 + lane];
    dst[t * 128 + lane + 64] = d1 * rs * g[d * 128 + lane + 64] + bb[d * 128 + lane + 64];
}

// ---------------- weight packers into MFMA frag order ----------------------
__global__ __launch_bounds__(256) void pack_qkv_kernel(
    const float* __restrict__ w, short* __restrict__ wp) {
    int idx = blockIdx.x * 256 + threadIdx.x;   // 6144
    int l = idx & 63, kk = (idx >> 6) & 3, n = idx >> 8;
    int k0 = kk * 32 + (l >> 4) * 8;
    int c = n * 16 + (l & 15);
    bf16x8 v;
    #pragma unroll
    for (int j = 0; j < 8; ++j) v[j] = f2bf(w[(size_t)(k0 + j) * 384 + c]);
    *(bf16x8*)&wp[(size_t)idx * 8] = v;
}
__global__ __launch_bounds__(256) void pack_pw_kernel(
    const float* __restrict__ w, short* __restrict__ wp) {
    int idx = blockIdx.x * 256 + threadIdx.x;   // 2048
    int l = idx & 63, kk = (idx >> 6) & 3, n = idx >> 8;
    int k0 = kk * 32 + (l >> 4) * 8;
    int c = n * 16 + (l & 15);
    bf16x8 v;
    #pragma unroll
    for (int j = 0; j < 8; ++j) v[j] = f2bf(w[(size_t)(k0 + j) * 128 + c]);
    *(bf16x8*)&wp[(size_t)idx * 8] = v;
}
__global__ __launch_bounds__(256) void pack_w1_kernel(
    const float* __restrict__ w1, short* __restrict__ w1p) {
    int idx = blockIdx.x * 256 + threadIdx.x;   // 16384
    int l = idx & 63, kk = (idx >> 6) & 3, n = idx >> 8;
    int k0 = kk * 32 + (l >> 4) * 8;
    int c = n * 16 + (l & 15);
    bf16x8 v;
    #pragma unroll
    for (int j = 0; j < 8; ++j) v[j] = f2bf(w1[(size_t)(k0 + j) * 1024 + c]);
    *(bf16x8*)&w1p[(size_t)idx * 8] = v;
}
__global__ __launch_bounds__(256) void pack_w2_kernel(
    const float* __restrict__ w2, short* __restrict__ w2p) {
    int idx = blockIdx.x * 256 + threadIdx.x;   // 16384
    int l = idx & 63, kk = (idx >> 6) & 31, n = idx >> 11;
    int k0 = kk * 32 + (l >> 4) * 8;
    int c = n * 16 + (l & 15);
    bf16x8 v;
    #pragma unroll
    for (int j = 0; j < 8; ++j) v[j] = f2bf(w2[(size_t)(k0 + j) * 128 + c]);
    *(bf16x8*)&w2p[(size_t)idx * 8] = v;
}

// ---------------- MFMA QKV: 32 tok/block, D[channel][token] ----------------
__global__ __launch_bounds__(256, 2) void qkv_mfma_kernel(
    const float* __restrict__ cur, const short* __restrict__ wp,
    const float* __restrict__ bias, float* __restrict__ q,
    float* __restrict__ k_img, float* __restrict__ v_img) {
    int tb = blockIdx.x * 32;
    int tid = threadIdx.x;
    int lane = tid & 63, wv = tid >> 6;
    int lhi = lane >> 4, llo = lane & 15;
    int b = tb >> 12, n0 = tb & 4095;

    bf16x8 afr[2][4];
    #pragma unroll
    for (int tt = 0; tt < 2; ++tt) {
        #pragma unroll
        for (int kk = 0; kk < 4; ++kk) {
            const float* p = cur + (size_t)(tb + tt * 16 + llo) * 128 + kk * 32 + lhi * 8;
            bf16x8 v;
            #pragma unroll
            for (int j = 0; j < 8; ++j) v[j] = f2bf(p[j]);
            afr[tt][kk] = v;
        }
    }

    f32x4 acc[6][2];
    f32x4 zr = {0.f, 0.f, 0.f, 0.f};
    #pragma unroll
    for (int i = 0; i < 6; ++i) { acc[i][0] = zr; acc[i][1] = zr; }

    #pragma unroll
    for (int i = 0; i < 6; ++i) {
        int nb = wv * 6 + i;
        #pragma unroll
        for (int kk = 0; kk < 4; ++kk) {
            bf16x8 wf = *(const bf16x8*)&wp[((size_t)(nb * 4 + kk) * 64 + lane) * 8];
            acc[i][0] = __builtin_amdgcn_mfma_f32_16x16x32_bf16(wf, afr[0][kk], acc[i][0], 0, 0, 0);
            acc[i][1] = __builtin_amdgcn_mfma_f32_16x16x32_bf16(wf, afr[1][kk], acc[i][1], 0, 0, 0);
        }
    }

    #pragma unroll
    for (int i = 0; i < 6; ++i) {
        int j0 = (wv * 6 + i) * 16;
        f32x4 bv = *(const f32x4*)(bias + j0 + lhi * 4);
        #pragma unroll
        for (int tt = 0; tt < 2; ++tt) {
            f32x4 r = acc[i][tt] + bv;
            int t = tb + tt * 16 + llo;
            if (j0 < 128) {
                *(f32x4*)(q + (size_t)t * 128 + j0 + lhi * 4) = r;
            } else {
                float* dst = (j0 < 256) ? k_img : v_img;
                int c0 = (j0 & 127) + lhi * 4;
                float* p = dst + (size_t)(b * 128 + c0) * 4096 + n0 + tt * 16 + llo;
                p[0]        = r.x;
                p[4096]     = r.y;
                p[2 * 4096] = r.z;
                p[3 * 4096] = r.w;
            }
        }
    }
}

// ---------------- softmax over N ---------------
__global__ __launch_bounds__(256) void softmax_kernel(float* __restrict__ k_img) {
    __shared__ float red[4];
    float* p = k_img + (size_t)blockIdx.x * 4096;
    int tid = threadIdx.x;
    float v[16];
    float mx = -1e30f;
    #pragma unroll
    for (int i = 0; i < 16; ++i) {
        v[i] = p[tid + i * 256];
        mx = fmaxf(mx, v[i]);
    }
    mx = wave_reduce_max(mx);
    int wid = tid >> 6, lane = tid & 63;
    if (lane == 0) red[wid] = mx;
    __syncthreads();
    mx = fmaxf(fmaxf(red[0], red[1]), fmaxf(red[2], red[3]));
    __syncthreads();
    float sum = 0.f;
    #pragma unroll
    for (int i = 0; i < 16; ++i) {
        v[i] = expf(v[i] - mx);
        sum += v[i];
    }
    sum = wave_reduce_sum(sum);
    if (lane == 0) red[wid] = sum;
    __syncthreads();
    float inv = 1.f / (red[0] + red[1] + red[2] + red[3]);
    #pragma unroll
    for (int i = 0; i < 16; ++i)
        p[tid + i * 256] = v[i] * inv;
}

// ---------------- kv partial: grid 512 = bh*8+chunk, n-chunk of 512 --------
__global__ __launch_bounds__(256) void kv_part_kernel(
    const float* __restrict__ k_img, const float* __restrict__ v_img,
    float* __restrict__ kvp) {
    __shared__ float ks[16 * 132], vs[16 * 132];
    int bc = blockIdx.x;
    int bh = bc >> 3, chunk = bc & 7;
    int b = bh >> 3, h = bh & 7;
    int tid = threadIdx.x;
    int ck = tid >> 4, cv = tid & 15;
    float acc = 0.f;
    const float* kp = k_img + (size_t)(b * 128 + h * 16) * 4096;
    const float* vp = v_img + (size_t)(b * 128 + h * 16) * 4096;
    int nb0 = chunk * 512;
    for (int nb = nb0; nb < nb0 + 512; nb += 128) {
        for (int idx = tid; idx < 2048; idx += 256) {
            int r = idx >> 7, col = idx & 127;
            ks[r * 132 + col] = kp[(size_t)r * 4096 + nb + col];
            vs[r * 132 + col] = vp[(size_t)r * 4096 + nb + col];
        }
        __syncthreads();
        for (int kk = 0; kk < 128; ++kk)
            acc += ks[ck * 132 + kk] * vs[cv * 132 + kk];
        __syncthreads();
    }
    kvp[(size_t)(chunk * 64 + bh) * 256 + ck * 16 + cv] = acc;
}
__global__ __launch_bounds__(256) void kv_reduce_kernel(
    const float* __restrict__ kvp, float* __restrict__ kv) {
    int i = blockIdx.x * 256 + threadIdx.x;   // 16384
    float s = 0.f;
    #pragma unroll
    for (int c = 0; c < 8; ++c) s += kvp[(size_t)c * 16384 + i];
    kv[i] = s;
}

// ---------------- domain gate --------------------------------
__global__ __launch_bounds__(256) void gate_kernel(
    const float* __restrict__ dl, const float* __restrict__ w1,
    const float* __restrict__ b1, const float* __restrict__ w2,
    const float* __restrict__ b2, float* __restrict__ da) {
    __shared__ float hid[512];
    __shared__ float raw[1024];
    int tid = threadIdx.x;
    for (int idx = tid; idx < 512; idx += 256) {
        int b = idx >> 6, jj = idx & 63;
        float a = b1[jj];
        #pragma unroll
        for (int dd = 0; dd < 4; ++dd)
            a += dl[b * 4 + dd] * w1[dd * 64 + jj];
        hid[idx] = fmaxf(a, 0.f);
    }
    __syncthreads();
    for (int idx = tid; idx < 1024; idx += 256) {
        int b = idx >> 7, c = idx & 127;
        float a = b2[c];
        for (int jj = 0; jj < 64; ++jj)
            a += hid[b * 64 + jj] * w2[jj * 128 + c];
        raw[idx] = a;
    }
    __syncthreads();
    if (tid < 128) {
        int b = tid >> 4, ch = tid & 15;
        float mx = -1e30f;
        #pragma unroll
        for (int hh = 0; hh < 8; ++hh)
            mx = fmaxf(mx, raw[b * 128 + hh * 16 + ch]);
        float e[8];
        float s = 0.f;
        #pragma unroll
        for (int hh = 0; hh < 8; ++hh) {
            e[hh] = expf(raw[b * 128 + hh * 16 + ch] - mx);
            s += e[hh];
        }
        float inv = 1.f / s;
        #pragma unroll
        for (int hh = 0; hh < 8; ++hh)
            da[b * 128 + hh * 16 + ch] = e[hh] * inv;
    }
}

// ---------------- crpe conv + factor-att combine -------
__global__ __launch_bounds__(256) void att_kernel(
    const float* __restrict__ q, const float* __restrict__ v_img,
    const float* __restrict__ kv, const float* __restrict__ da,
    const float* __restrict__ w3, const float* __restrict__ b3,
    const float* __restrict__ w5, const float* __restrict__ b5,
    const float* __restrict__ w7, const float* __restrict__ b7,
    float* __restrict__ att) {
    __shared__ float s[64 * 65];
    __shared__ float wsm[49];
    int bx = blockIdx.x;
    int b = bx >> 7, c = bx & 127;
    int h = c >> 4, cvi = c & 15;
    int tid = threadIdx.x;
    const float* vp = v_img + (size_t)(b * 128 + c) * 4096;
    for (int idx = tid; idx < 4096; idx += 256)
        s[(idx >> 6) * 65 + (idx & 63)] = vp[idx];
    int kc; const float* wp; float bias;
    if (c < 32)      { kc = 3; wp = w3 + c * 9;        bias = b3[c]; }
    else if (c < 80) { kc = 5; wp = w5 + (c - 32) * 25; bias = b5[c - 32]; }
    else             { kc = 7; wp = w7 + (c - 80) * 49; bias = b7[c - 80]; }
    if (tid < kc * kc) wsm[tid] = wp[tid];
    float kvr[16];
    #pragma unroll
    for (int ck = 0; ck < 16; ++ck)
        kvr[ck] = kv[((size_t)(b * 8 + h) * 16 + ck) * 16 + cvi];
    float dac = da[b * 128 + c];
    int off = kc >> 1;
    __syncthreads();
    for (int i = 0; i < 16; ++i) {
        int n = tid + i * 256;
        int y = n >> 6, xx = n & 63;
        float acc = bias;
        for (int dy = 0; dy < kc; ++dy) {
            int sy = y + dy - off;
            if (sy < 0 || sy >= 64) continue;
            for (int dx = 0; dx < kc; ++dx) {
                int sx = xx + dx - off;
                if (sx < 0 || sx >= 64) continue;
                acc += s[sy * 65 + sx] * wsm[dy * kc + dx];
            }
        }
        const float* qp = q + (size_t)(b * 4096 + n) * 128 + h * 16;
        float fa = 0.f;
        #pragma unroll
        for (int ck = 0; ck < 16; ++ck)
            fa += qp[ck] * kvr[ck];
        att[(size_t)(b * 128 + c) * 4096 + n] = dac * (0.25f * fa + qp[cvi] * acc);
    }
}

// ---------------- MFMA proj + residual: A = att (image layout) -------------
__global__ __launch_bounds__(256, 2) void proj_mfma_kernel(
    const float* __restrict__ att, const short* __restrict__ wp,
    const float* __restrict__ bias, const float* __restrict__ xres,
    float* __restrict__ out) {
    __shared__ float As[128 * 33];
    int tb = blockIdx.x * 32;
    int tid = threadIdx.x;
    int lane = tid & 63, wv = tid >> 6;
    int lhi = lane >> 4, llo = lane & 15;
    int b = tb >> 12, n0 = tb & 4095;

    for (int idx = tid; idx < 4096; idx += 256) {
        int c = idx >> 5, t = idx & 31;
        As[c * 33 + t] = att[(size_t)(b * 128 + c) * 4096 + n0 + t];
    }
    __syncthreads();

    bf16x8 afr[2][4];
    #pragma unroll
    for (int tt = 0; tt < 2; ++tt) {
        #pragma unroll
        for (int kk = 0; kk < 4; ++kk) {
            int c0 = kk * 32 + lhi * 8;
            int t = tt * 16 + llo;
            bf16x8 v;
            #pragma unroll
            for (int j = 0; j < 8; ++j) v[j] = f2bf(As[(c0 + j) * 33 + t]);
            afr[tt][kk] = v;
        }
    }

    f32x4 acc[2][2];
    f32x4 zr = {0.f, 0.f, 0.f, 0.f};
    #pragma unroll
    for (int i = 0; i < 2; ++i) { acc[i][0] = zr; acc[i][1] = zr; }

    #pragma unroll
    for (int i = 0; i < 2; ++i) {
        int nb = wv * 2 + i;
        #pragma unroll
        for (int kk = 0; kk < 4; ++kk) {
            bf16x8 wf = *(const bf16x8*)&wp[((size_t)(nb * 4 + kk) * 64 + lane) * 8];
            acc[i][0] = __builtin_amdgcn_mfma_f32_16x16x32_bf16(wf, afr[0][kk], acc[i][0], 0, 0, 0);
            acc[i][1] = __builtin_amdgcn_mfma_f32_16x16x32_bf16(wf, afr[1][kk], acc[i][1], 0, 0, 0);
        }
    }

    #pragma unroll
    for (int i = 0; i < 2; ++i) {
        int j0 = (wv * 2 + i) * 16;
        f32x4 bv = *(const f32x4*)(bias + j0 + lhi * 4);
        #pragma unroll
        for (int tt = 0; tt < 2; ++tt) {
            size_t o = (size_t)(tb + tt * 16 + llo) * 128 + j0 + lhi * 4;
            f32x4 xr = *(const f32x4*)(xres + o);
            *(f32x4*)(out + o) = xr + acc[i][tt] + bv;
        }
    }
}

// ---------------- fused MFMA MLP (32 tok/block, hid in LDS frag order) -----
// NOTE: GEMM1 nl loop MUST be fully unrolled — partial unroll leaves acc[tt][nl]
// runtime-indexed -> scratch spill (was 441 MB HBM traffic / 145 us, rule #20).
__global__ __launch_bounds__(256, 2) void mlp_mfma_kernel(
    const float* __restrict__ cur, const short* __restrict__ w1p,
    const float* __restrict__ b1, const short* __restrict__ w2p,
    const float* __restrict__ b2, float* __restrict__ out) {
    __shared__ short hs[32768];
    int tb = blockIdx.x * 32;
    int tid = threadIdx.x;
    int lane = tid & 63, wv = tid >> 6;
    int lhi = lane >> 4, llo = lane & 15;

    bf16x8 afr[2][4];
    #pragma unroll
    for (int tt = 0; tt < 2; ++tt) {
        #pragma unroll
        for (int kk = 0; kk < 4; ++kk) {
            const float* p = cur + (size_t)(tb + tt * 16 + llo) * 128 + kk * 32 + lhi * 8;
            bf16x8 v;
            #pragma unroll
            for (int j = 0; j < 8; ++j) v[j] = f2bf(p[j]);
            afr[tt][kk] = v;
        }
    }

    f32x4 acc[2][16];
    f32x4 zr = {0.f, 0.f, 0.f, 0.f};
    #pragma unroll
    for (int tt = 0; tt < 2; ++tt)
        #pragma unroll
        for (int nl = 0; nl < 16; ++nl) acc[tt][nl] = zr;

    const short* wbase = w1p + (size_t)(wv * 16) * 4 * 64 * 8;
    #pragma unroll
    for (int nl = 0; nl < 16; ++nl) {
        #pragma unroll
        for (int kk = 0; kk < 4; ++kk) {
            bf16x8 bf = *(const bf16x8*)(wbase + ((size_t)(nl * 4 + kk) * 64 + lane) * 8);
            acc[0][nl] = __builtin_amdgcn_mfma_f32_16x16x32_bf16(bf, afr[0][kk], acc[0][nl], 0, 0, 0);
            acc[1][nl] = __builtin_amdgcn_mfma_f32_16x16x32_bf16(bf, afr[1][kk], acc[1][nl], 0, 0, 0);
        }
    }

    #pragma unroll
    for (int nl = 0; nl < 16; ++nl) {
        int hn = wv * 16 + nl;
        int hc0 = hn * 16 + lhi * 4;
        f32x4 bv = *(const f32x4*)(b1 + hc0);
        int kk2 = hn >> 1;
        int lp = llo + 16 * ((hn & 1) * 2 + (lhi >> 1));
        #pragma unroll
        for (int tt = 0; tt < 2; ++tt) {
            f32x4 a = acc[tt][nl] + bv;
            float g0 = 0.5f * a.x * (1.f + erff(a.x * 0.70710678118654752f));
            float g1 = 0.5f * a.y * (1.f + erff(a.y * 0.70710678118654752f));
            float g2 = 0.5f * a.z * (1.f + erff(a.z * 0.70710678118654752f));
            float g3 = 0.5f * a.w * (1.f + erff(a.w * 0.70710678118654752f));
            uint2 wv2;
            wv2.x = pack2bf(g0, g1);
            wv2.y = pack2bf(g2, g3);
            *(uint2*)((char*)hs + ((size_t)(tt * 32 + kk2) * 64 + lp) * 16 + (lhi & 1) * 8) = wv2;
        }
    }
    __syncthreads();

    f32x4 acc2[2][2];
    #pragma unroll
    for (int cn = 0; cn < 2; ++cn)
        #pragma unroll
        for (int tt = 0; tt < 2; ++tt) acc2[cn][tt] = zr;

    const short* w2base = w2p + (size_t)(wv * 2) * 32 * 64 * 8;
    #pragma unroll 4
    for (int kk2 = 0; kk2 < 32; ++kk2) {
        bf16x8 h0 = *(const bf16x8*)&hs[((size_t)(0 * 32 + kk2) * 64 + lane) * 8];
        bf16x8 h1 = *(const bf16x8*)&hs[((size_t)(1 * 32 + kk2) * 64 + lane) * 8];
        bf16x8 w0 = *(const bf16x8*)(w2base + ((size_t)(0 * 32 + kk2) * 64 + lane) * 8);
        bf16x8 w1f = *(const bf16x8*)(w2base + ((size_t)(1 * 32 + kk2) * 64 + lane) * 8);
        acc2[0][0] = __builtin_amdgcn_mfma_f32_16x16x32_bf16(w0, h0, acc2[0][0], 0, 0, 0);
        acc2[0][1] = __builtin_amdgcn_mfma_f32_16x16x32_bf16(w0, h1, acc2[0][1], 0, 0, 0);
        acc2[1][0] = __builtin_amdgcn_mfma_f32_16x16x32_bf16(w1f, h0, acc2[1][0], 0, 0, 0);
        acc2[1][1] = __builtin_amdgcn_mfma_f32_16x16x32_bf16(w1f, h1, acc2[1][1], 0, 0, 0);
    }

    #pragma unroll
    for (int cn = 0; cn < 2; ++cn) {
        int c0 = (wv * 2 + cn) * 16 + lhi * 4;
        f32x4 bv = *(const f32x4*)(b2 + c0);
        #pragma unroll
        for (int tt = 0; tt < 2; ++tt) {
            float* op = out + (size_t)(tb + tt * 16 + llo) * 128 + c0;
            f32x4 r = *(f32x4*)op;
            r = r + acc2[cn][tt] + bv;
            *(f32x4*)op = r;
        }
    }
}

extern "C" void kernel_launch(void* const* d_in, const int* in_sizes, int n_in,
                              void* d_out, int out_size, void* d_ws, size_t ws_size,
                              hipStream_t stream) {
    const float* img   = (const float*)d_in[0];
    const float* dl    = (const float*)d_in[1];
    const float* pe_dw = (const float*)d_in[2];
    const float* pe_pw = (const float*)d_in[3];
    const float* bn_g  = (const float*)d_in[4];
    const float* bn_b  = (const float*)d_in[5];
    const float* bn_m  = (const float*)d_in[6];
    const float* bn_v  = (const float*)d_in[7];
    const float* cpe_w = (const float*)d_in[8];
    const float* cpe_b = (const float*)d_in[9];
    const float* n1_g  = (const float*)d_in[10];
    const float* n1_b  = (const float*)d_in[11];
    const float* qkv_w = (const float*)d_in[12];
    const float* qkv_b = (const float*)d_in[13];
    const float* w3    = (const float*)d_in[14];
    const float* b3    = (const float*)d_in[15];
    const float* w5    = (const float*)d_in[16];
    const float* b5    = (const float*)d_in[17];
    const float* w7    = (const float*)d_in[18];
    const float* b7    = (const float*)d_in[19];
    const float* dw1   = (const float*)d_in[20];
    const float* db1   = (const float*)d_in[21];
    const float* dw2   = (const float*)d_in[22];
    const float* db2   = (const float*)d_in[23];
    const float* pw    = (const float*)d_in[24];
    const float* pb    = (const float*)d_in[25];
    const float* n2_g  = (const float*)d_in[26];
    const float* n2_b  = (const float*)d_in[27];
    const float* f1w   = (const float*)d_in[28];
    const float* f1b   = (const float*)d_in[29];
    const float* f2w   = (const float*)d_in[30];
    const float* f2b   = (const float*)d_in[31];
    const int*   dptr  = (const int*)d_in[32];
    float* out = (float*)d_out;

    char* ws = (char*)d_ws;
    const size_t SZ = (size_t)8 * 128 * 4096 * 4;   // 16,777,216 bytes
    float* t1    = (float*)(ws);            // also cur (post-LN)
    float* x     = (float*)(ws + SZ);
    float* q     = (float*)(ws + 2 * SZ);   // dead after att -> w1p/w2p
    float* k_img = (float*)(ws + 3 * SZ);   // att output after kv
    float* v_img = (float*)(ws + 4 * SZ);
    float* kv    = (float*)(ws + 5 * SZ);                  // 64KB
    float* da    = (float*)(ws + 5 * SZ + 0x10000);        // 4KB
    short* qkvp  = (short*)(ws + 5 * SZ + 0x20000);        // 96KB
    short* pwp   = (short*)(ws + 5 * SZ + 0x40000);        // 32KB
    float* kvp   = (float*)(ws + 5 * SZ + 0x50000);        // 512KB
    short* w1p   = (short*)(ws + 2 * SZ);                  // 256KB (in dead q)
    short* w2p   = (short*)(ws + 2 * SZ + 262144);         // 256KB

    pack_qkv_kernel<<<24, 256, 0, stream>>>(qkv_w, qkvp);
    pack_pw_kernel<<<8, 256, 0, stream>>>(pw, pwp);
    gate_kernel<<<1, 256, 0, stream>>>(dl, dw1, db1, dw2, db2, da);
    pe_kernel<<<512, 256, 0, stream>>>(img, pe_dw, pe_pw, bn_g, bn_b, bn_m, bn_v, dptr, t1);
    cpe_kernel<<<2048, 256, 0, stream>>>(t1, cpe_w, cpe_b, x);
    ln_kernel<<<8192, 256, 0, stream>>>(x, t1, n1_g, n1_b, dptr);
    qkv_mfma_kernel<<<1024, 256, 0, stream>>>(t1, qkvp, qkv_b, q, k_img, v_img);
    softmax_kernel<<<1024, 256, 0, stream>>>(k_img);
    kv_part_kernel<<<512, 256, 0, stream>>>(k_img, v_img, kvp);
    kv_reduce_kernel<<<64, 256, 0, stream>>>(kvp, kv);
    att_kernel<<<1024, 256, 0, stream>>>(q, v_img, kv, da, w3, b3, w5, b5, w7, b7, k_img);
    proj_mfma_kernel<<<1024, 256, 0, stream>>>(k_img, pwp, pb, x, out);
    pack_w1_kernel<<<64, 256, 0, stream>>>(f1w, w1p);
    pack_w2_kernel<<<64, 256, 0, stream>>>(f2w, w2p);
    ln_kernel<<<8192, 256, 0, stream>>>(out, t1, n2_g, n2_b, dptr);
    mlp_mfma_kernel<<<1024, 256, 0, stream>>>(t1, w1p, f1b, w2p, f2b, out);
}

// Round 7
// 477.994 us; speedup vs baseline: 3.5466x; 1.0082x over previous
//
#include <hip/hip_runtime.h>
#include <math.h>

#define EPS_LN 1e-6f
#define EPS_BN 1e-5f

typedef __attribute__((ext_vector_type(8))) short bf16x8;
typedef __attribute__((ext_vector_type(4))) float f32x4;

__device__ __forceinline__ float wave_reduce_sum(float v) {
    #pragma unroll
    for (int m = 32; m >= 1; m >>= 1) v += __shfl_xor(v, m, 64);
    return v;
}
__device__ __forceinline__ float wave_reduce_max(float v) {
    #pragma unroll
    for (int m = 32; m >= 1; m >>= 1) v = fmaxf(v, __shfl_xor(v, m, 64));
    return v;
}
__device__ __forceinline__ short f2bf(float f) {
    union { float f; unsigned u; } v; v.f = f;
    unsigned r = v.u + 0x7fff + ((v.u >> 16) & 1);
    return (short)(r >> 16);
}
__device__ __forceinline__ unsigned pack2bf(float a, float b) {
    return (unsigned)(unsigned short)f2bf(a) | ((unsigned)(unsigned short)f2bf(b) << 16);
}

// ---------------- patch embed: dw3x3 s2 + pw 64->128 + BN(d) + hardswish ----
__global__ __launch_bounds__(256) void pe_kernel(
    const float* __restrict__ img, const float* __restrict__ dww,
    const float* __restrict__ pww, const float* __restrict__ bn_g,
    const float* __restrict__ bn_b, const float* __restrict__ bn_m,
    const float* __restrict__ bn_v, const int* __restrict__ dptr,
    float* __restrict__ t1) {
    __shared__ float dw[64 * 65];
    int bx = blockIdx.x;
    int b = bx >> 6, y = bx & 63;
    int tid = threadIdx.x;
    int d = *dptr;
    for (int idx = tid; idx < 4096; idx += 256) {
        int ci = idx >> 6, xx = idx & 63;
        const float* ip = img + (size_t)(b * 64 + ci) * 128 * 128;
        float acc = 0.f;
        #pragma unroll
        for (int r = 0; r < 3; ++r) {
            int iy = 2 * y + r;
            if (iy >= 128) continue;
            #pragma unroll
            for (int s = 0; s < 3; ++s) {
                int ix = 2 * xx + s;
                if (ix >= 128) continue;
                acc += ip[iy * 128 + ix] * dww[ci * 9 + r * 3 + s];
            }
        }
        dw[ci * 65 + xx] = acc;
    }
    __syncthreads();
    for (int idx = tid; idx < 8192; idx += 256) {
        int co = idx >> 6, xx = idx & 63;
        float acc = 0.f;
        const float* wp = pww + co * 64;
        for (int ci = 0; ci < 64; ++ci)
            acc += dw[ci * 65 + xx] * wp[ci];
        float sc = bn_g[d * 128 + co] * rsqrtf(bn_v[d * 128 + co] + EPS_BN);
        float v = (acc - bn_m[d * 128 + co]) * sc + bn_b[d * 128 + co];
        v = v * fminf(fmaxf(v + 3.f, 0.f), 6.f) * (1.f / 6.f);
        t1[(size_t)(b * 128 + co) * 4096 + y * 64 + xx] = v;
    }
}

// ---------------- ConvPosEnc ----------------
__global__ __launch_bounds__(256) void cpe_kernel(
    const float* __restrict__ t1, const float* __restrict__ cw,
    const float* __restrict__ cb, float* __restrict__ xout) {
    int bx = blockIdx.x;
    int cq = bx & 3, y = (bx >> 2) & 63, b = bx >> 8;
    int c0 = cq * 32;
    __shared__ float s[3 * 32 * 65];
    int tid = threadIdx.x;
    for (int idx = tid; idx < 3 * 32 * 64; idx += 256) {
        int xx = idx & 63;
        int cl = (idx >> 6) & 31;
        int dy = idx >> 11;
        int yy = y + dy - 1;
        float v = 0.f;
        if (yy >= 0 && yy < 64)
            v = t1[(size_t)(b * 128 + c0 + cl) * 4096 + yy * 64 + xx];
        s[(dy * 32 + cl) * 65 + xx] = v;
    }
    __syncthreads();
    for (int idx = tid; idx < 32 * 64; idx += 256) {
        int cl = idx & 31;
        int xx = idx >> 5;
        int c = c0 + cl;
        float center = s[(32 + cl) * 65 + xx];
        float acc = cb[c];
        #pragma unroll
        for (int dy = 0; dy < 3; ++dy) {
            #pragma unroll
            for (int dx = 0; dx < 3; ++dx) {
                int sx = xx + dx - 1;
                if (sx < 0 || sx >= 64) continue;
                acc += s[(dy * 32 + cl) * 65 + sx] * cw[c * 9 + dy * 3 + dx];
            }
        }
        xout[(size_t)(b * 4096 + y * 64 + xx) * 128 + c] = center + acc;
    }
}

// ---------------- weight packers (LN gamma folded in) ----------------------
// entry (n,kk,l): holds g[k]*W[k][n*16+(l&15)], k = kk*32+(l>>4)*8+j
__global__ __launch_bounds__(256) void pack_qkv_kernel(
    const float* __restrict__ w, const float* __restrict__ g,
    const int* __restrict__ dptr, short* __restrict__ wp) {
    int idx = blockIdx.x * 256 + threadIdx.x;   // 6144
    int d = *dptr;
    int l = idx & 63, kk = (idx >> 6) & 3, n = idx >> 8;
    int k0 = kk * 32 + (l >> 4) * 8;
    int c = n * 16 + (l & 15);
    bf16x8 v;
    #pragma unroll
    for (int j = 0; j < 8; ++j)
        v[j] = f2bf(g[d * 128 + k0 + j] * w[(size_t)(k0 + j) * 384 + c]);
    *(bf16x8*)&wp[(size_t)idx * 8] = v;
}
__global__ __launch_bounds__(256) void pack_pw_kernel(
    const float* __restrict__ w, short* __restrict__ wp) {
    int idx = blockIdx.x * 256 + threadIdx.x;   // 2048
    int l = idx & 63, kk = (idx >> 6) & 3, n = idx >> 8;
    int k0 = kk * 32 + (l >> 4) * 8;
    int c = n * 16 + (l & 15);
    bf16x8 v;
    #pragma unroll
    for (int j = 0; j < 8; ++j) v[j] = f2bf(w[(size_t)(k0 + j) * 128 + c]);
    *(bf16x8*)&wp[(size_t)idx * 8] = v;
}
__global__ __launch_bounds__(256) void pack_w1_kernel(
    const float* __restrict__ w1, const float* __restrict__ g,
    const int* __restrict__ dptr, short* __restrict__ w1p) {
    int idx = blockIdx.x * 256 + threadIdx.x;   // 16384
    int d = *dptr;
    int l = idx & 63, kk = (idx >> 6) & 3, n = idx >> 8;
    int k0 = kk * 32 + (l >> 4) * 8;
    int c = n * 16 + (l & 15);
    bf16x8 v;
    #pragma unroll
    for (int j = 0; j < 8; ++j)
        v[j] = f2bf(g[d * 128 + k0 + j] * w1[(size_t)(k0 + j) * 1024 + c]);
    *(bf16x8*)&w1p[(size_t)idx * 8] = v;
}
__global__ __launch_bounds__(256) void pack_w2_kernel(
    const float* __restrict__ w2, short* __restrict__ w2p) {
    int idx = blockIdx.x * 256 + threadIdx.x;   // 16384
    int l = idx & 63, kk = (idx >> 6) & 31, n = idx >> 11;
    int k0 = kk * 32 + (l >> 4) * 8;
    int c = n * 16 + (l & 15);
    bf16x8 v;
    #pragma unroll
    for (int j = 0; j < 8; ++j) v[j] = f2bf(w2[(size_t)(k0 + j) * 128 + c]);
    *(bf16x8*)&w2p[(size_t)idx * 8] = v;
}

// ---------------- bias folds: b' = b + beta @ W ----------------------------
__global__ __launch_bounds__(256) void fold_qkv_bias_kernel(
    const float* __restrict__ w, const float* __restrict__ bqkv,
    const float* __restrict__ beta, const int* __restrict__ dptr,
    float* __restrict__ bp) {
    int j = blockIdx.x * 256 + threadIdx.x;
    if (j >= 384) return;
    int d = *dptr;
    float s = bqkv[j];
    for (int k = 0; k < 128; ++k) s += beta[d * 128 + k] * w[(size_t)k * 384 + j];
    bp[j] = s;
}
__global__ __launch_bounds__(256) void fold_fc1_bias_kernel(
    const float* __restrict__ w, const float* __restrict__ b1,
    const float* __restrict__ beta, const int* __restrict__ dptr,
    float* __restrict__ bp) {
    int j = blockIdx.x * 256 + threadIdx.x;
    if (j >= 1024) return;
    int d = *dptr;
    float s = b1[j];
    for (int k = 0; k < 128; ++k) s += beta[d * 128 + k] * w[(size_t)k * 1024 + j];
    bp[j] = s;
}

// ---------------- MFMA QKV (LN1 fused): 32 tok/block, out image layout -----
// prologue: 4-lane shfl LN (gamma/beta folded into wp/biasp).
__global__ __launch_bounds__(256, 2) void qkv_mfma_kernel(
    const float* __restrict__ x, const short* __restrict__ wp,
    const float* __restrict__ biasp, float* __restrict__ q_img,
    float* __restrict__ k_img, float* __restrict__ v_img) {
    int tb = blockIdx.x * 32;
    int tid = threadIdx.x;
    int lane = tid & 63, wv = tid >> 6;
    int lhi = lane >> 4, llo = lane & 15;
    int b = tb >> 12, n0 = tb & 4095;

    bf16x8 afr[2][4];
    #pragma unroll
    for (int tt = 0; tt < 2; ++tt) {
        f32x4 v0[4], v1[4];
        float sum = 0.f;
        #pragma unroll
        for (int kk = 0; kk < 4; ++kk) {
            const float* p = x + (size_t)(tb + tt * 16 + llo) * 128 + kk * 32 + lhi * 8;
            v0[kk] = *(const f32x4*)p;
            v1[kk] = *(const f32x4*)(p + 4);
            sum += v0[kk].x + v0[kk].y + v0[kk].z + v0[kk].w
                 + v1[kk].x + v1[kk].y + v1[kk].z + v1[kk].w;
        }
        sum += __shfl_xor(sum, 16, 64);
        sum += __shfl_xor(sum, 32, 64);
        float mean = sum * (1.f / 128.f);
        float vs = 0.f;
        #pragma unroll
        for (int kk = 0; kk < 4; ++kk) {
            f32x4 a = v0[kk], c = v1[kk];
            float d0 = a.x - mean, d1 = a.y - mean, d2 = a.z - mean, d3 = a.w - mean;
            float d4 = c.x - mean, d5 = c.y - mean, d6 = c.z - mean, d7 = c.w - mean;
            vs += d0*d0 + d1*d1 + d2*d2 + d3*d3 + d4*d4 + d5*d5 + d6*d6 + d7*d7;
        }
        vs += __shfl_xor(vs, 16, 64);
        vs += __shfl_xor(vs, 32, 64);
        float rs = rsqrtf(vs * (1.f / 128.f) + EPS_LN);
        #pragma unroll
        for (int kk = 0; kk < 4; ++kk) {
            bf16x8 o;
            o[0] = f2bf((v0[kk].x - mean) * rs);
            o[1] = f2bf((v0[kk].y - mean) * rs);
            o[2] = f2bf((v0[kk].z - mean) * rs);
            o[3] = f2bf((v0[kk].w - mean) * rs);
            o[4] = f2bf((v1[kk].x - mean) * rs);
            o[5] = f2bf((v1[kk].y - mean) * rs);
            o[6] = f2bf((v1[kk].z - mean) * rs);
            o[7] = f2bf((v1[kk].w - mean) * rs);
            afr[tt][kk] = o;
        }
    }

    f32x4 acc[6][2];
    f32x4 zr = {0.f, 0.f, 0.f, 0.f};
    #pragma unroll
    for (int i = 0; i < 6; ++i) { acc[i][0] = zr; acc[i][1] = zr; }

    #pragma unroll
    for (int i = 0; i < 6; ++i) {
        int nb = wv * 6 + i;
        #pragma unroll
        for (int kk = 0; kk < 4; ++kk) {
            bf16x8 wf = *(const bf16x8*)&wp[((size_t)(nb * 4 + kk) * 64 + lane) * 8];
            acc[i][0] = __builtin_amdgcn_mfma_f32_16x16x32_bf16(wf, afr[0][kk], acc[i][0], 0, 0, 0);
            acc[i][1] = __builtin_amdgcn_mfma_f32_16x16x32_bf16(wf, afr[1][kk], acc[i][1], 0, 0, 0);
        }
    }

    #pragma unroll
    for (int i = 0; i < 6; ++i) {
        int j0 = (wv * 6 + i) * 16;
        f32x4 bv = *(const f32x4*)(biasp + j0 + lhi * 4);
        float* dst = (j0 < 128) ? q_img : ((j0 < 256) ? k_img : v_img);
        int c0 = (j0 & 127) + lhi * 4;
        #pragma unroll
        for (int tt = 0; tt < 2; ++tt) {
            f32x4 r = acc[i][tt] + bv;
            float* p = dst + (size_t)(b * 128 + c0) * 4096 + n0 + tt * 16 + llo;
            p[0]        = r.x;
            p[4096]     = r.y;
            p[2 * 4096] = r.z;
            p[3 * 4096] = r.w;
        }
    }
}

// ---------------- softmax over N ---------------
__global__ __launch_bounds__(256) void softmax_kernel(float* __restrict__ k_img) {
    __shared__ float red[4];
    float* p = k_img + (size_t)blockIdx.x * 4096;
    int tid = threadIdx.x;
    float v[16];
    float mx = -1e30f;
    #pragma unroll
    for (int i = 0; i < 16; ++i) {
        v[i] = p[tid + i * 256];
        mx = fmaxf(mx, v[i]);
    }
    mx = wave_reduce_max(mx);
    int wid = tid >> 6, lane = tid & 63;
    if (lane == 0) red[wid] = mx;
    __syncthreads();
    mx = fmaxf(fmaxf(red[0], red[1]), fmaxf(red[2], red[3]));
    __syncthreads();
    float sum = 0.f;
    #pragma unroll
    for (int i = 0; i < 16; ++i) {
        v[i] = expf(v[i] - mx);
        sum += v[i];
    }
    sum = wave_reduce_sum(sum);
    if (lane == 0) red[wid] = sum;
    __syncthreads();
    float inv = 1.f / (red[0] + red[1] + red[2] + red[3]);
    #pragma unroll
    for (int i = 0; i < 16; ++i)
        p[tid + i * 256] = v[i] * inv;
}

// ---------------- kv partial: grid 512 = bh*8+chunk, n-chunk of 512 --------
__global__ __launch_bounds__(256) void kv_part_kernel(
    const float* __restrict__ k_img, const float* __restrict__ v_img,
    float* __restrict__ kvp) {
    __shared__ float ks[16 * 132], vs[16 * 132];
    int bc = blockIdx.x;
    int bh = bc >> 3, chunk = bc & 7;
    int b = bh >> 3, h = bh & 7;
    int tid = threadIdx.x;
    int ck = tid >> 4, cv = tid & 15;
    float acc = 0.f;
    const float* kp = k_img + (size_t)(b * 128 + h * 16) * 4096;
    const float* vp = v_img + (size_t)(b * 128 + h * 16) * 4096;
    int nb0 = chunk * 512;
    for (int nb = nb0; nb < nb0 + 512; nb += 128) {
        for (int idx = tid; idx < 2048; idx += 256) {
            int r = idx >> 7, col = idx & 127;
            ks[r * 132 + col] = kp[(size_t)r * 4096 + nb + col];
            vs[r * 132 + col] = vp[(size_t)r * 4096 + nb + col];
        }
        __syncthreads();
        for (int kk = 0; kk < 128; ++kk)
            acc += ks[ck * 132 + kk] * vs[cv * 132 + kk];
        __syncthreads();
    }
    kvp[(size_t)(chunk * 64 + bh) * 256 + ck * 16 + cv] = acc;
}
__global__ __launch_bounds__(256) void kv_reduce_kernel(
    const float* __restrict__ kvp, float* __restrict__ kv) {
    int i = blockIdx.x * 256 + threadIdx.x;   // 16384
    float s = 0.f;
    #pragma unroll
    for (int c = 0; c < 8; ++c) s += kvp[(size_t)c * 16384 + i];
    kv[i] = s;
}

// ---------------- domain gate --------------------------------
__global__ __launch_bounds__(256) void gate_kernel(
    const float* __restrict__ dl, const float* __restrict__ w1,
    const float* __restrict__ b1, const float* __restrict__ w2,
    const float* __restrict__ b2, float* __restrict__ da) {
    __shared__ float hid[512];
    __shared__ float raw[1024];
    int tid = threadIdx.x;
    for (int idx = tid; idx < 512; idx += 256) {
        int b = idx >> 6, jj = idx & 63;
        float a = b1[jj];
        #pragma unroll
        for (int dd = 0; dd < 4; ++dd)
            a += dl[b * 4 + dd] * w1[dd * 64 + jj];
        hid[idx] = fmaxf(a, 0.f);
    }
    __syncthreads();
    for (int idx = tid; idx < 1024; idx += 256) {
        int b = idx >> 7, c = idx & 127;
        float a = b2[c];
        for (int jj = 0; jj < 64; ++jj)
            a += hid[b * 64 + jj] * w2[jj * 128 + c];
        raw[idx] = a;
    }
    __syncthreads();
    if (tid < 128) {
        int b = tid >> 4, ch = tid & 15;
        float mx = -1e30f;
        #pragma unroll
        for (int hh = 0; hh < 8; ++hh)
            mx = fmaxf(mx, raw[b * 128 + hh * 16 + ch]);
        float e[8];
        float s = 0.f;
        #pragma unroll
        for (int hh = 0; hh < 8; ++hh) {
            e[hh] = expf(raw[b * 128 + hh * 16 + ch] - mx);
            s += e[hh];
        }
        float inv = 1.f / s;
        #pragma unroll
        for (int hh = 0; hh < 8; ++hh)
            da[b * 128 + hh * 16 + ch] = e[hh] * inv;
    }
}

// ---------------- crpe conv + factor-att combine (q image layout) ----------
// XCD swizzle: batch-major chunks of 128 -> each XCD's L2 holds q[b]+v[b] (4MB).
__global__ __launch_bounds__(256) void att_kernel(
    const float* __restrict__ q_img, const float* __restrict__ v_img,
    const float* __restrict__ kv, const float* __restrict__ da,
    const float* __restrict__ w3, const float* __restrict__ b3,
    const float* __restrict__ w5, const float* __restrict__ b5,
    const float* __restrict__ w7, const float* __restrict__ b7,
    float* __restrict__ att) {
    __shared__ float s[64 * 65];
    __shared__ float wsm[49];
    int o = ((blockIdx.x & 7) << 7) | (blockIdx.x >> 3);   // bijective, 1024%8==0
    int b = o >> 7, c = o & 127;
    int h = c >> 4, cvi = c & 15;
    int tid = threadIdx.x;
    const float* vp = v_img + (size_t)(b * 128 + c) * 4096;
    for (int idx = tid; idx < 4096; idx += 256)
        s[(idx >> 6) * 65 + (idx & 63)] = vp[idx];
    int kc; const float* wp; float bias;
    if (c < 32)      { kc = 3; wp = w3 + c * 9;        bias = b3[c]; }
    else if (c < 80) { kc = 5; wp = w5 + (c - 32) * 25; bias = b5[c - 32]; }
    else             { kc = 7; wp = w7 + (c - 80) * 49; bias = b7[c - 80]; }
    if (tid < kc * kc) wsm[tid] = wp[tid];
    float kvr[16];
    #pragma unroll
    for (int ck = 0; ck < 16; ++ck)
        kvr[ck] = kv[((size_t)(b * 8 + h) * 16 + ck) * 16 + cvi];
    float dac = da[b * 128 + c];
    int off = kc >> 1;
    const float* qrow = q_img + (size_t)(b * 128 + h * 16) * 4096;
    __syncthreads();
    for (int i = 0; i < 16; ++i) {
        int n = tid + i * 256;
        int y = n >> 6, xx = n & 63;
        float acc = bias;
        for (int dy = 0; dy < kc; ++dy) {
            int sy = y + dy - off;
            if (sy < 0 || sy >= 64) continue;
            for (int dx = 0; dx < kc; ++dx) {
                int sx = xx + dx - off;
                if (sx < 0 || sx >= 64) continue;
                acc += s[sy * 65 + sx] * wsm[dy * kc + dx];
            }
        }
        float fa = 0.f;
        #pragma unroll
        for (int ck = 0; ck < 16; ++ck)
            fa += qrow[(size_t)ck * 4096 + n] * kvr[ck];
        float qcv = qrow[(size_t)cvi * 4096 + n];
        att[(size_t)(b * 128 + c) * 4096 + n] = dac * (0.25f * fa + qcv * acc);
    }
}

// ---------------- MFMA proj + residual: A = att (image layout) -------------
__global__ __launch_bounds__(256, 2) void proj_mfma_kernel(
    const float* __restrict__ att, const short* __restrict__ wp,
    const float* __restrict__ bias, const float* __restrict__ xres,
    float* __restrict__ out) {
    __shared__ float As[128 * 33];
    int tb = blockIdx.x * 32;
    int tid = threadIdx.x;
    int lane = tid & 63, wv = tid >> 6;
    int lhi = lane >> 4, llo = lane & 15;
    int b = tb >> 12, n0 = tb & 4095;

    for (int idx = tid; idx < 4096; idx += 256) {
        int c = idx >> 5, t = idx & 31;
        As[c * 33 + t] = att[(size_t)(b * 128 + c) * 4096 + n0 + t];
    }
    __syncthreads();

    bf16x8 afr[2][4];
    #pragma unroll
    for (int tt = 0; tt < 2; ++tt) {
        #pragma unroll
        for (int kk = 0; kk < 4; ++kk) {
            int c0 = kk * 32 + lhi * 8;
            int t = tt * 16 + llo;
            bf16x8 v;
            #pragma unroll
            for (int j = 0; j < 8; ++j) v[j] = f2bf(As[(c0 + j) * 33 + t]);
            afr[tt][kk] = v;
        }
    }

    f32x4 acc[2][2];
    f32x4 zr = {0.f, 0.f, 0.f, 0.f};
    #pragma unroll
    for (int i = 0; i < 2; ++i) { acc[i][0] = zr; acc[i][1] = zr; }

    #pragma unroll
    for (int i = 0; i < 2; ++i) {
        int nb = wv * 2 + i;
        #pragma unroll
        for (int kk = 0; kk < 4; ++kk) {
            bf16x8 wf = *(const bf16x8*)&wp[((size_t)(nb * 4 + kk) * 64 + lane) * 8];
            acc[i][0] = __builtin_amdgcn_mfma_f32_16x16x32_bf16(wf, afr[0][kk], acc[i][0], 0, 0, 0);
            acc[i][1] = __builtin_amdgcn_mfma_f32_16x16x32_bf16(wf, afr[1][kk], acc[i][1], 0, 0, 0);
        }
    }

    #pragma unroll
    for (int i = 0; i < 2; ++i) {
        int j0 = (wv * 2 + i) * 16;
        f32x4 bv = *(const f32x4*)(bias + j0 + lhi * 4);
        #pragma unroll
        for (int tt = 0; tt < 2; ++tt) {
            size_t o = (size_t)(tb + tt * 16 + llo) * 128 + j0 + lhi * 4;
            f32x4 xr = *(const f32x4*)(xres + o);
            *(f32x4*)(out + o) = xr + acc[i][tt] + bv;
        }
    }
}

// ---------------- fused MFMA MLP (LN2 fused; reads io pre-barrier, RMW after)
// NOTE: GEMM1 nl loop MUST stay fully unrolled (rule #20 — scratch spill).
__global__ __launch_bounds__(256, 2) void mlp_mfma_kernel(
    const short* __restrict__ w1p, const float* __restrict__ b1p,
    const short* __restrict__ w2p, const float* __restrict__ b2,
    float* io) {
    __shared__ short hs[32768];
    int tb = blockIdx.x * 32;
    int tid = threadIdx.x;
    int lane = tid & 63, wv = tid >> 6;
    int lhi = lane >> 4, llo = lane & 15;

    bf16x8 afr[2][4];
    #pragma unroll
    for (int tt = 0; tt < 2; ++tt) {
        f32x4 v0[4], v1[4];
        float sum = 0.f;
        #pragma unroll
        for (int kk = 0; kk < 4; ++kk) {
            const float* p = io + (size_t)(tb + tt * 16 + llo) * 128 + kk * 32 + lhi * 8;
            v0[kk] = *(const f32x4*)p;
            v1[kk] = *(const f32x4*)(p + 4);
            sum += v0[kk].x + v0[kk].y + v0[kk].z + v0[kk].w
                 + v1[kk].x + v1[kk].y + v1[kk].z + v1[kk].w;
        }
        sum += __shfl_xor(sum, 16, 64);
        sum += __shfl_xor(sum, 32, 64);
        float mean = sum * (1.f / 128.f);
        float vs = 0.f;
        #pragma unroll
        for (int kk = 0; kk < 4; ++kk) {
            f32x4 a = v0[kk], c = v1[kk];
            float d0 = a.x - mean, d1 = a.y - mean, d2 = a.z - mean, d3 = a.w - mean;
            float d4 = c.x - mean, d5 = c.y - mean, d6 = c.z - mean, d7 = c.w - mean;
            vs += d0*d0 + d1*d1 + d2*d2 + d3*d3 + d4*d4 + d5*d5 + d6*d6 + d7*d7;
        }
        vs += __shfl_xor(vs, 16, 64);
        vs += __shfl_xor(vs, 32, 64);
        float rs = rsqrtf(vs * (1.f / 128.f) + EPS_LN);
        #pragma unroll
        for (int kk = 0; kk < 4; ++kk) {
            bf16x8 o;
            o[0] = f2bf((v0[kk].x - mean) * rs);
            o[1] = f2bf((v0[kk].y - mean) * rs);
            o[2] = f2bf((v0[kk].z - mean) * rs);
            o[3] = f2bf((v0[kk].w - mean) * rs);
            o[4] = f2bf((v1[kk].x - mean) * rs);
            o[5] = f2bf((v1[kk].y - mean) * rs);
            o[6] = f2bf((v1[kk].z - mean) * rs);
            o[7] = f2bf((v1[kk].w - mean) * rs);
            afr[tt][kk] = o;
        }
    }

    f32x4 acc[2][16];
    f32x4 zr = {0.f, 0.f, 0.f, 0.f};
    #pragma unroll
    for (int tt = 0; tt < 2; ++tt)
        #pragma unroll
        for (int nl = 0; nl < 16; ++nl) acc[tt][nl] = zr;

    const short* wbase = w1p + (size_t)(wv * 16) * 4 * 64 * 8;
    #pragma unroll
    for (int nl = 0; nl < 16; ++nl) {
        #pragma unroll
        for (int kk = 0; kk < 4; ++kk) {
            bf16x8 bf = *(const bf16x8*)(wbase + ((size_t)(nl * 4 + kk) * 64 + lane) * 8);
            acc[0][nl] = __builtin_amdgcn_mfma_f32_16x16x32_bf16(bf, afr[0][kk], acc[0][nl], 0, 0, 0);
            acc[1][nl] = __builtin_amdgcn_mfma_f32_16x16x32_bf16(bf, afr[1][kk], acc[1][nl], 0, 0, 0);
        }
    }

    #pragma unroll
    for (int nl = 0; nl < 16; ++nl) {
        int hn = wv * 16 + nl;
        int hc0 = hn * 16 + lhi * 4;
        f32x4 bv = *(const f32x4*)(b1p + hc0);
        int kk2 = hn >> 1;
        int lp = llo + 16 * ((hn & 1) * 2 + (lhi >> 1));
        #pragma unroll
        for (int tt = 0; tt < 2; ++tt) {
            f32x4 a = acc[tt][nl] + bv;
            float g0 = 0.5f * a.x * (1.f + erff(a.x * 0.70710678118654752f));
            float g1 = 0.5f * a.y * (1.f + erff(a.y * 0.70710678118654752f));
            float g2 = 0.5f * a.z * (1.f + erff(a.z * 0.70710678118654752f));
            float g3 = 0.5f * a.w * (1.f + erff(a.w * 0.70710678118654752f));
            uint2 wv2;
            wv2.x = pack2bf(g0, g1);
            wv2.y = pack2bf(g2, g3);
            *(uint2*)((char*)hs + ((size_t)(tt * 32 + kk2) * 64 + lp) * 16 + (lhi & 1) * 8) = wv2;
        }
    }
    __syncthreads();

    f32x4 acc2[2][2];
    #pragma unroll
    for (int cn = 0; cn < 2; ++cn)
        #pragma unroll
        for (int tt = 0; tt < 2; ++tt) acc2[cn][tt] = zr;

    const short* w2base = w2p + (size_t)(wv * 2) * 32 * 64 * 8;
    #pragma unroll 4
    for (int kk2 = 0; kk2 < 32; ++kk2) {
        bf16x8 h0 = *(const bf16x8*)&hs[((size_t)(0 * 32 + kk2) * 64 + lane) * 8];
        bf16x8 h1 = *(const bf16x8*)&hs[((size_t)(1 * 32 + kk2) * 64 + lane) * 8];
        bf16x8 w0 = *(const bf16x8*)(w2base + ((size_t)(0 * 32 + kk2) * 64 + lane) * 8);
        bf16x8 w1f = *(const bf16x8*)(w2base + ((size_t)(1 * 32 + kk2) * 64 + lane) * 8);
        acc2[0][0] = __builtin_amdgcn_mfma_f32_16x16x32_bf16(w0, h0, acc2[0][0], 0, 0, 0);
        acc2[0][1] = __builtin_amdgcn_mfma_f32_16x16x32_bf16(w0, h1, acc2[0][1], 0, 0, 0);
        acc2[1][0] = __builtin_amdgcn_mfma_f32_16x16x32_bf16(w1f, h0, acc2[1][0], 0, 0, 0);
        acc2[1][1] = __builtin_amdgcn_mfma_f32_16x16x32_bf16(w1f, h1, acc2[1][1], 0, 0, 0);
    }

    #pragma unroll
    for (int cn = 0; cn < 2; ++cn) {
        int c0 = (wv * 2 + cn) * 16 + lhi * 4;
        f32x4 bv = *(const f32x4*)(b2 + c0);
        #pragma unroll
        for (int tt = 0; tt < 2; ++tt) {
            float* op = io + (size_t)(tb + tt * 16 + llo) * 128 + c0;
            f32x4 r = *(f32x4*)op;
            r = r + acc2[cn][tt] + bv;
            *(f32x4*)op = r;
        }
    }
}

extern "C" void kernel_launch(void* const* d_in, const int* in_sizes, int n_in,
                              void* d_out, int out_size, void* d_ws, size_t ws_size,
                              hipStream_t stream) {
    const float* img   = (const float*)d_in[0];
    const float* dl    = (const float*)d_in[1];
    const float* pe_dw = (const float*)d_in[2];
    const float* pe_pw = (const float*)d_in[3];
    const float* bn_g  = (const float*)d_in[4];
    const float* bn_b  = (const float*)d_in[5];
    const float* bn_m  = (const float*)d_in[6];
    const float* bn_v  = (const float*)d_in[7];
    const float* cpe_w = (const float*)d_in[8];
    const float* cpe_b = (const float*)d_in[9];
    const float* n1_g  = (const float*)d_in[10];
    const float* n1_b  = (const float*)d_in[11];
    const float* qkv_w = (const float*)d_in[12];
    const float* qkv_b = (const float*)d_in[13];
    const float* w3    = (const float*)d_in[14];
    const float* b3    = (const float*)d_in[15];
    const float* w5    = (const float*)d_in[16];
    const float* b5    = (const float*)d_in[17];
    const float* w7    = (const float*)d_in[18];
    const float* b7    = (const float*)d_in[19];
    const float* dw1   = (const float*)d_in[20];
    const float* db1   = (const float*)d_in[21];
    const float* dw2   = (const float*)d_in[22];
    const float* db2   = (const float*)d_in[23];
    const float* pw    = (const float*)d_in[24];
    const float* pb    = (const float*)d_in[25];
    const float* n2_g  = (const float*)d_in[26];
    const float* n2_b  = (const float*)d_in[27];
    const float* f1w   = (const float*)d_in[28];
    const float* f1b   = (const float*)d_in[29];
    const float* f2w   = (const float*)d_in[30];
    const float* f2b   = (const float*)d_in[31];
    const int*   dptr  = (const int*)d_in[32];
    float* out = (float*)d_out;

    char* ws = (char*)d_ws;
    const size_t SZ = (size_t)8 * 128 * 4096 * 4;   // 16,777,216 bytes
    float* t1    = (float*)(ws);            // pe out (image layout)
    float* x     = (float*)(ws + SZ);       // residual stream after cpe
    float* q_img = (float*)(ws + 2 * SZ);   // dead after att -> w1p/w2p
    float* k_img = (float*)(ws + 3 * SZ);   // att output after kv
    float* v_img = (float*)(ws + 4 * SZ);
    float* kv    = (float*)(ws + 5 * SZ);                  // 64KB
    float* da    = (float*)(ws + 5 * SZ + 0x10000);        // 4KB
    short* qkvp  = (short*)(ws + 5 * SZ + 0x20000);        // 96KB
    short* pwp   = (short*)(ws + 5 * SZ + 0x40000);        // 32KB
    float* qbp   = (float*)(ws + 5 * SZ + 0x48000);        // 1.5KB folded qkv bias
    float* f1bp  = (float*)(ws + 5 * SZ + 0x4A000);        // 4KB folded fc1 bias
    float* kvp   = (float*)(ws + 5 * SZ + 0x50000);        // 512KB
    short* w1p   = (short*)(ws + 2 * SZ);                  // 256KB (in dead q)
    short* w2p   = (short*)(ws + 2 * SZ + 262144);         // 256KB

    pack_qkv_kernel<<<24, 256, 0, stream>>>(qkv_w, n1_g, dptr, qkvp);
    fold_qkv_bias_kernel<<<2, 256, 0, stream>>>(qkv_w, qkv_b, n1_b, dptr, qbp);
    pack_pw_kernel<<<8, 256, 0, stream>>>(pw, pwp);
    gate_kernel<<<1, 256, 0, stream>>>(dl, dw1, db1, dw2, db2, da);
    pe_kernel<<<512, 256, 0, stream>>>(img, pe_dw, pe_pw, bn_g, bn_b, bn_m, bn_v, dptr, t1);
    cpe_kernel<<<2048, 256, 0, stream>>>(t1, cpe_w, cpe_b, x);
    qkv_mfma_kernel<<<1024, 256, 0, stream>>>(x, qkvp, qbp, q_img, k_img, v_img);
    softmax_kernel<<<1024, 256, 0, stream>>>(k_img);
    kv_part_kernel<<<512, 256, 0, stream>>>(k_img, v_img, kvp);
    kv_reduce_kernel<<<64, 256, 0, stream>>>(kvp, kv);
    att_kernel<<<1024, 256, 0, stream>>>(q_img, v_img, kv, da, w3, b3, w5, b5, w7, b7, k_img);
    proj_mfma_kernel<<<1024, 256, 0, stream>>>(k_img, pwp, pb, x, out);
    pack_w1_kernel<<<64, 256, 0, stream>>>(f1w, n2_g, dptr, w1p);
    fold_fc1_bias_kernel<<<4, 256, 0, stream>>>(f1w, f1b, n2_b, dptr, f1bp);
    pack_w2_kernel<<<64, 256, 0, stream>>>(f2w, w2p);
    mlp_mfma_kernel<<<1024, 256, 0, stream>>>(w1p, f1bp, w2p, f2b, out);
}

// Round 8
// 379.643 us; speedup vs baseline: 4.4654x; 1.2591x over previous
//
#include <hip/hip_runtime.h>
#include <math.h>

#define EPS_LN 1e-6f
#define EPS_BN 1e-5f

typedef __attribute__((ext_vector_type(8))) short bf16x8;
typedef __attribute__((ext_vector_type(4))) float f32x4;

__device__ __forceinline__ float wave_reduce_sum(float v) {
    #pragma unroll
    for (int m = 32; m >= 1; m >>= 1) v += __shfl_xor(v, m, 64);
    return v;
}
__device__ __forceinline__ float wave_reduce_max(float v) {
    #pragma unroll
    for (int m = 32; m >= 1; m >>= 1) v = fmaxf(v, __shfl_xor(v, m, 64));
    return v;
}
__device__ __forceinline__ short f2bf(float f) {
    union { float f; unsigned u; } v; v.f = f;
    unsigned r = v.u + 0x7fff + ((v.u >> 16) & 1);
    return (short)(r >> 16);
}
__device__ __forceinline__ unsigned pack2bf(float a, float b) {
    return (unsigned)(unsigned short)f2bf(a) | ((unsigned)(unsigned short)f2bf(b) << 16);
}

// ---------------- patch embed: dw3x3 s2 + pw 64->128 + BN(d) + hardswish ----
// grid 512 = b*64+y. Register-tiled pw (8co x 4xx/thread), LDS-staged weights.
__global__ __launch_bounds__(256) void pe_kernel(
    const float* __restrict__ img, const float* __restrict__ dww,
    const float* __restrict__ pww, const float* __restrict__ bn_g,
    const float* __restrict__ bn_b, const float* __restrict__ bn_m,
    const float* __restrict__ bn_v, const int* __restrict__ dptr,
    float* __restrict__ t1) {
    __shared__ float dw[64 * 68];     // [ci][xx], stride 68 (16B-aligned rows)
    __shared__ float wsm[64 * 132];   // [ci][co], stride 132 (16B-aligned rows)
    int bx = blockIdx.x;
    int b = bx >> 6, y = bx & 63;
    int tid = threadIdx.x;
    int d = *dptr;

    // stage pw weights transposed: wsm[ci][co] = pww[co][ci] (coalesced read)
    for (int idx = tid; idx < 8192; idx += 256) {
        int co = idx >> 6, ci = idx & 63;
        wsm[ci * 132 + co] = pww[idx];
    }

    // depthwise 3x3 s2, vectorized 4 outputs/task
    for (int it = 0; it < 4; ++it) {
        int task = tid + it * 256;
        int ci = task >> 4, xx0 = (task & 15) * 4;
        const float* ip = img + (size_t)(b * 64 + ci) * 16384;
        const float* wd = dww + ci * 9;
        float a0 = 0.f, a1 = 0.f, a2 = 0.f, a3 = 0.f;
        #pragma unroll
        for (int r = 0; r < 3; ++r) {
            int iy = 2 * y + r;
            if (iy >= 128) continue;      // only y=63, r=2 (SAME pad_hi=1)
            const float* rp = ip + iy * 128 + 2 * xx0;
            float u[9];
            *(f32x4*)&u[0] = *(const f32x4*)rp;
            *(f32x4*)&u[4] = *(const f32x4*)(rp + 4);
            u[8] = (xx0 < 60) ? rp[8] : 0.f;   // ix=128 is pad
            #pragma unroll
            for (int s = 0; s < 3; ++s) {
                float w = wd[r * 3 + s];
                a0 += u[s] * w;
                a1 += u[2 + s] * w;
                a2 += u[4 + s] * w;
                a3 += u[6 + s] * w;
            }
        }
        f32x4 st = {a0, a1, a2, a3};
        *(f32x4*)&dw[ci * 68 + xx0] = st;
    }
    __syncthreads();

    // pointwise 64->128: thread tile 8 co x 4 xx, 3x b128 + 32 FMA per ci
    int xg = tid & 15, cog = tid >> 4;
    int xx0 = xg * 4, co0 = cog * 8;
    f32x4 acc[8];
    f32x4 zr = {0.f, 0.f, 0.f, 0.f};
    #pragma unroll
    for (int i = 0; i < 8; ++i) acc[i] = zr;
    for (int ci = 0; ci < 64; ++ci) {
        f32x4 dv = *(const f32x4*)&dw[ci * 68 + xx0];
        f32x4 w0 = *(const f32x4*)&wsm[ci * 132 + co0];
        f32x4 w1 = *(const f32x4*)&wsm[ci * 132 + co0 + 4];
        acc[0] += dv * w0.x; acc[1] += dv * w0.y;
        acc[2] += dv * w0.z; acc[3] += dv * w0.w;
        acc[4] += dv * w1.x; acc[5] += dv * w1.y;
        acc[6] += dv * w1.z; acc[7] += dv * w1.w;
    }
    #pragma unroll
    for (int i = 0; i < 8; ++i) {
        int co = co0 + i;
        float sc = bn_g[d * 128 + co] * rsqrtf(bn_v[d * 128 + co] + EPS_BN);
        float mu = bn_m[d * 128 + co], be = bn_b[d * 128 + co];
        f32x4 v = (acc[i] - mu) * sc + be;
        f32x4 r;
        r.x = v.x * fminf(fmaxf(v.x + 3.f, 0.f), 6.f) * (1.f / 6.f);
        r.y = v.y * fminf(fmaxf(v.y + 3.f, 0.f), 6.f) * (1.f / 6.f);
        r.z = v.z * fminf(fmaxf(v.z + 3.f, 0.f), 6.f) * (1.f / 6.f);
        r.w = v.w * fminf(fmaxf(v.w + 3.f, 0.f), 6.f) * (1.f / 6.f);
        *(f32x4*)&t1[(size_t)(b * 128 + co) * 4096 + y * 64 + xx0] = r;
    }
}

// ---------------- ConvPosEnc ----------------
__global__ __launch_bounds__(256) void cpe_kernel(
    const float* __restrict__ t1, const float* __restrict__ cw,
    const float* __restrict__ cb, float* __restrict__ xout) {
    int bx = blockIdx.x;
    int cq = bx & 3, y = (bx >> 2) & 63, b = bx >> 8;
    int c0 = cq * 32;
    __shared__ float s[3 * 32 * 65];
    int tid = threadIdx.x;
    for (int idx = tid; idx < 3 * 32 * 64; idx += 256) {
        int xx = idx & 63;
        int cl = (idx >> 6) & 31;
        int dy = idx >> 11;
        int yy = y + dy - 1;
        float v = 0.f;
        if (yy >= 0 && yy < 64)
            v = t1[(size_t)(b * 128 + c0 + cl) * 4096 + yy * 64 + xx];
        s[(dy * 32 + cl) * 65 + xx] = v;
    }
    __syncthreads();
    for (int idx = tid; idx < 32 * 64; idx += 256) {
        int cl = idx & 31;
        int xx = idx >> 5;
        int c = c0 + cl;
        float center = s[(32 + cl) * 65 + xx];
        float acc = cb[c];
        #pragma unroll
        for (int dy = 0; dy < 3; ++dy) {
            #pragma unroll
            for (int dx = 0; dx < 3; ++dx) {
                int sx = xx + dx - 1;
                if (sx < 0 || sx >= 64) continue;
                acc += s[(dy * 32 + cl) * 65 + sx] * cw[c * 9 + dy * 3 + dx];
            }
        }
        xout[(size_t)(b * 4096 + y * 64 + xx) * 128 + c] = center + acc;
    }
}

// ---------------- weight packers (LN gamma folded in) ----------------------
__global__ __launch_bounds__(256) void pack_qkv_kernel(
    const float* __restrict__ w, const float* __restrict__ g,
    const int* __restrict__ dptr, short* __restrict__ wp) {
    int idx = blockIdx.x * 256 + threadIdx.x;   // 6144
    int d = *dptr;
    int l = idx & 63, kk = (idx >> 6) & 3, n = idx >> 8;
    int k0 = kk * 32 + (l >> 4) * 8;
    int c = n * 16 + (l & 15);
    bf16x8 v;
    #pragma unroll
    for (int j = 0; j < 8; ++j)
        v[j] = f2bf(g[d * 128 + k0 + j] * w[(size_t)(k0 + j) * 384 + c]);
    *(bf16x8*)&wp[(size_t)idx * 8] = v;
}
__global__ __launch_bounds__(256) void pack_pw_kernel(
    const float* __restrict__ w, short* __restrict__ wp) {
    int idx = blockIdx.x * 256 + threadIdx.x;   // 2048
    int l = idx & 63, kk = (idx >> 6) & 3, n = idx >> 8;
    int k0 = kk * 32 + (l >> 4) * 8;
    int c = n * 16 + (l & 15);
    bf16x8 v;
    #pragma unroll
    for (int j = 0; j < 8; ++j) v[j] = f2bf(w[(size_t)(k0 + j) * 128 + c]);
    *(bf16x8*)&wp[(size_t)idx * 8] = v;
}
__global__ __launch_bounds__(256) void pack_w1_kernel(
    const float* __restrict__ w1, const float* __restrict__ g,
    const int* __restrict__ dptr, short* __restrict__ w1p) {
    int idx = blockIdx.x * 256 + threadIdx.x;   // 16384
    int d = *dptr;
    int l = idx & 63, kk = (idx >> 6) & 3, n = idx >> 8;
    int k0 = kk * 32 + (l >> 4) * 8;
    int c = n * 16 + (l & 15);
    bf16x8 v;
    #pragma unroll
    for (int j = 0; j < 8; ++j)
        v[j] = f2bf(g[d * 128 + k0 + j] * w1[(size_t)(k0 + j) * 1024 + c]);
    *(bf16x8*)&w1p[(size_t)idx * 8] = v;
}
__global__ __launch_bounds__(256) void pack_w2_kernel(
    const float* __restrict__ w2, short* __restrict__ w2p) {
    int idx = blockIdx.x * 256 + threadIdx.x;   // 16384
    int l = idx & 63, kk = (idx >> 6) & 31, n = idx >> 11;
    int k0 = kk * 32 + (l >> 4) * 8;
    int c = n * 16 + (l & 15);
    bf16x8 v;
    #pragma unroll
    for (int j = 0; j < 8; ++j) v[j] = f2bf(w2[(size_t)(k0 + j) * 128 + c]);
    *(bf16x8*)&w2p[(size_t)idx * 8] = v;
}

// ---------------- bias folds: b' = b + beta @ W ----------------------------
__global__ __launch_bounds__(256) void fold_qkv_bias_kernel(
    const float* __restrict__ w, const float* __restrict__ bqkv,
    const float* __restrict__ beta, const int* __restrict__ dptr,
    float* __restrict__ bp) {
    int j = blockIdx.x * 256 + threadIdx.x;
    if (j >= 384) return;
    int d = *dptr;
    float s = bqkv[j];
    for (int k = 0; k < 128; ++k) s += beta[d * 128 + k] * w[(size_t)k * 384 + j];
    bp[j] = s;
}
__global__ __launch_bounds__(256) void fold_fc1_bias_kernel(
    const float* __restrict__ w, const float* __restrict__ b1,
    const float* __restrict__ beta, const int* __restrict__ dptr,
    float* __restrict__ bp) {
    int j = blockIdx.x * 256 + threadIdx.x;
    if (j >= 1024) return;
    int d = *dptr;
    float s = b1[j];
    for (int k = 0; k < 128; ++k) s += beta[d * 128 + k] * w[(size_t)k * 1024 + j];
    bp[j] = s;
}

// ---------------- MFMA QKV (LN1 fused): 32 tok/block, out image layout -----
__global__ __launch_bounds__(256, 2) void qkv_mfma_kernel(
    const float* __restrict__ x, const short* __restrict__ wp,
    const float* __restrict__ biasp, float* __restrict__ q_img,
    float* __restrict__ k_img, float* __restrict__ v_img) {
    int tb = blockIdx.x * 32;
    int tid = threadIdx.x;
    int lane = tid & 63, wv = tid >> 6;
    int lhi = lane >> 4, llo = lane & 15;
    int b = tb >> 12, n0 = tb & 4095;

    bf16x8 afr[2][4];
    #pragma unroll
    for (int tt = 0; tt < 2; ++tt) {
        f32x4 v0[4], v1[4];
        float sum = 0.f;
        #pragma unroll
        for (int kk = 0; kk < 4; ++kk) {
            const float* p = x + (size_t)(tb + tt * 16 + llo) * 128 + kk * 32 + lhi * 8;
            v0[kk] = *(const f32x4*)p;
            v1[kk] = *(const f32x4*)(p + 4);
            sum += v0[kk].x + v0[kk].y + v0[kk].z + v0[kk].w
                 + v1[kk].x + v1[kk].y + v1[kk].z + v1[kk].w;
        }
        sum += __shfl_xor(sum, 16, 64);
        sum += __shfl_xor(sum, 32, 64);
        float mean = sum * (1.f / 128.f);
        float vs = 0.f;
        #pragma unroll
        for (int kk = 0; kk < 4; ++kk) {
            f32x4 a = v0[kk], c = v1[kk];
            float d0 = a.x - mean, d1 = a.y - mean, d2 = a.z - mean, d3 = a.w - mean;
            float d4 = c.x - mean, d5 = c.y - mean, d6 = c.z - mean, d7 = c.w - mean;
            vs += d0*d0 + d1*d1 + d2*d2 + d3*d3 + d4*d4 + d5*d5 + d6*d6 + d7*d7;
        }
        vs += __shfl_xor(vs, 16, 64);
        vs += __shfl_xor(vs, 32, 64);
        float rs = rsqrtf(vs * (1.f / 128.f) + EPS_LN);
        #pragma unroll
        for (int kk = 0; kk < 4; ++kk) {
            bf16x8 o;
            o[0] = f2bf((v0[kk].x - mean) * rs);
            o[1] = f2bf((v0[kk].y - mean) * rs);
            o[2] = f2bf((v0[kk].z - mean) * rs);
            o[3] = f2bf((v0[kk].w - mean) * rs);
            o[4] = f2bf((v1[kk].x - mean) * rs);
            o[5] = f2bf((v1[kk].y - mean) * rs);
            o[6] = f2bf((v1[kk].z - mean) * rs);
            o[7] = f2bf((v1[kk].w - mean) * rs);
            afr[tt][kk] = o;
        }
    }

    f32x4 acc[6][2];
    f32x4 zr = {0.f, 0.f, 0.f, 0.f};
    #pragma unroll
    for (int i = 0; i < 6; ++i) { acc[i][0] = zr; acc[i][1] = zr; }

    #pragma unroll
    for (int i = 0; i < 6; ++i) {
        int nb = wv * 6 + i;
        #pragma unroll
        for (int kk = 0; kk < 4; ++kk) {
            bf16x8 wf = *(const bf16x8*)&wp[((size_t)(nb * 4 + kk) * 64 + lane) * 8];
            acc[i][0] = __builtin_amdgcn_mfma_f32_16x16x32_bf16(wf, afr[0][kk], acc[i][0], 0, 0, 0);
            acc[i][1] = __builtin_amdgcn_mfma_f32_16x16x32_bf16(wf, afr[1][kk], acc[i][1], 0, 0, 0);
        }
    }

    #pragma unroll
    for (int i = 0; i < 6; ++i) {
        int j0 = (wv * 6 + i) * 16;
        f32x4 bv = *(const f32x4*)(biasp + j0 + lhi * 4);
        float* dst = (j0 < 128) ? q_img : ((j0 < 256) ? k_img : v_img);
        int c0 = (j0 & 127) + lhi * 4;
        #pragma unroll
        for (int tt = 0; tt < 2; ++tt) {
            f32x4 r = acc[i][tt] + bv;
            float* p = dst + (size_t)(b * 128 + c0) * 4096 + n0 + tt * 16 + llo;
            p[0]        = r.x;
            p[4096]     = r.y;
            p[2 * 4096] = r.z;
            p[3 * 4096] = r.w;
        }
    }
}

// ---------------- softmax over N ---------------
__global__ __launch_bounds__(256) void softmax_kernel(float* __restrict__ k_img) {
    __shared__ float red[4];
    float* p = k_img + (size_t)blockIdx.x * 4096;
    int tid = threadIdx.x;
    float v[16];
    float mx = -1e30f;
    #pragma unroll
    for (int i = 0; i < 16; ++i) {
        v[i] = p[tid + i * 256];
        mx = fmaxf(mx, v[i]);
    }
    mx = wave_reduce_max(mx);
    int wid = tid >> 6, lane = tid & 63;
    if (lane == 0) red[wid] = mx;
    __syncthreads();
    mx = fmaxf(fmaxf(red[0], red[1]), fmaxf(red[2], red[3]));
    __syncthreads();
    float sum = 0.f;
    #pragma unroll
    for (int i = 0; i < 16; ++i) {
        v[i] = expf(v[i] - mx);
        sum += v[i];
    }
    sum = wave_reduce_sum(sum);
    if (lane == 0) red[wid] = sum;
    __syncthreads();
    float inv = 1.f / (red[0] + red[1] + red[2] + red[3]);
    #pragma unroll
    for (int i = 0; i < 16; ++i)
        p[tid + i * 256] = v[i] * inv;
}

// ---------------- kv partial: grid 512 = bh*8+chunk, n-chunk of 512 --------
__global__ __launch_bounds__(256) void kv_part_kernel(
    const float* __restrict__ k_img, const float* __restrict__ v_img,
    float* __restrict__ kvp) {
    __shared__ float ks[16 * 132], vs[16 * 132];
    int bc = blockIdx.x;
    int bh = bc >> 3, chunk = bc & 7;
    int b = bh >> 3, h = bh & 7;
    int tid = threadIdx.x;
    int ck = tid >> 4, cv = tid & 15;
    float acc = 0.f;
    const float* kp = k_img + (size_t)(b * 128 + h * 16) * 4096;
    const float* vp = v_img + (size_t)(b * 128 + h * 16) * 4096;
    int nb0 = chunk * 512;
    for (int nb = nb0; nb < nb0 + 512; nb += 128) {
        for (int idx = tid; idx < 2048; idx += 256) {
            int r = idx >> 7, col = idx & 127;
            ks[r * 132 + col] = kp[(size_t)r * 4096 + nb + col];
            vs[r * 132 + col] = vp[(size_t)r * 4096 + nb + col];
        }
        __syncthreads();
        for (int kk = 0; kk < 128; ++kk)
            acc += ks[ck * 132 + kk] * vs[cv * 132 + kk];
        __syncthreads();
    }
    kvp[(size_t)(chunk * 64 + bh) * 256 + ck * 16 + cv] = acc;
}
__global__ __launch_bounds__(256) void kv_reduce_kernel(
    const float* __restrict__ kvp, float* __restrict__ kv) {
    int i = blockIdx.x * 256 + threadIdx.x;   // 16384
    float s = 0.f;
    #pragma unroll
    for (int c = 0; c < 8; ++c) s += kvp[(size_t)c * 16384 + i];
    kv[i] = s;
}

// ---------------- fa[b,c,n] = sum_ck kv[b,h,ck,cv] * q[b,h*16+ck,n] --------
// grid 1024 = bh*16+chunk, block 256. 16 q loads -> 16 outputs per thread.
__global__ __launch_bounds__(256) void fa_kernel(
    const float* __restrict__ q_img, const float* __restrict__ kv,
    float* __restrict__ fa_img) {
    __shared__ float kvs[256];
    int bid = blockIdx.x;
    int bh = bid >> 4, chunk = bid & 15;
    int b = bh >> 3, h = bh & 7;
    int tid = threadIdx.x;
    kvs[tid] = kv[bh * 256 + tid];
    __syncthreads();
    int n = chunk * 256 + tid;
    const float* qp = q_img + (size_t)(b * 128 + h * 16) * 4096 + n;
    float qv[16];
    #pragma unroll
    for (int ck = 0; ck < 16; ++ck) qv[ck] = qp[(size_t)ck * 4096];
    float* fp = fa_img + (size_t)(b * 128 + h * 16) * 4096 + n;
    #pragma unroll
    for (int cv = 0; cv < 16; ++cv) {
        float s = 0.f;
        #pragma unroll
        for (int ck = 0; ck < 16; ++ck) s += qv[ck] * kvs[ck * 16 + cv];
        fp[(size_t)cv * 4096] = s;
    }
}

// ---------------- domain gate --------------------------------
__global__ __launch_bounds__(256) void gate_kernel(
    const float* __restrict__ dl, const float* __restrict__ w1,
    const float* __restrict__ b1, const float* __restrict__ w2,
    const float* __restrict__ b2, float* __restrict__ da) {
    __shared__ float hid[512];
    __shared__ float raw[1024];
    int tid = threadIdx.x;
    for (int idx = tid; idx < 512; idx += 256) {
        int b = idx >> 6, jj = idx & 63;
        float a = b1[jj];
        #pragma unroll
        for (int dd = 0; dd < 4; ++dd)
            a += dl[b * 4 + dd] * w1[dd * 64 + jj];
        hid[idx] = fmaxf(a, 0.f);
    }
    __syncthreads();
    for (int idx = tid; idx < 1024; idx += 256) {
        int b = idx >> 7, c = idx & 127;
        float a = b2[c];
        for (int jj = 0; jj < 64; ++jj)
            a += hid[b * 64 + jj] * w2[jj * 128 + c];
        raw[idx] = a;
    }
    __syncthreads();
    if (tid < 128) {
        int b = tid >> 4, ch = tid & 15;
        float mx = -1e30f;
        #pragma unroll
        for (int hh = 0; hh < 8; ++hh)
            mx = fmaxf(mx, raw[b * 128 + hh * 16 + ch]);
        float e[8];
        float s = 0.f;
        #pragma unroll
        for (int hh = 0; hh < 8; ++hh) {
            e[hh] = expf(raw[b * 128 + hh * 16 + ch] - mx);
            s += e[hh];
        }
        float inv = 1.f / s;
        #pragma unroll
        for (int hh = 0; hh < 8; ++hh)
            da[b * 128 + hh * 16 + ch] = e[hh] * inv;
    }
}

// ---------------- conv helper: 4 outputs, compile-time KC (rule #20) -------
template<int KC>
__device__ __forceinline__ void conv4(const float* __restrict__ s,
                                      const float* __restrict__ wsm,
                                      int y, int xx0, float* a4) {
    const int OFF = KC / 2;
    #pragma unroll
    for (int dy = 0; dy < KC; ++dy) {
        int sy = y + dy - OFF;
        if (sy < 0 || sy >= 64) continue;
        const float* r = s + sy * 72;
        float u[12];
        *(f32x4*)&u[0] = *(const f32x4*)&r[xx0];
        *(f32x4*)&u[4] = *(const f32x4*)&r[xx0 + 4];
        *(f32x4*)&u[8] = *(const f32x4*)&r[xx0 + 8];
        #pragma unroll
        for (int dx = 0; dx < KC; ++dx) {
            float w = wsm[dy * KC + dx];
            const int base = dx - OFF + 4;     // u idx for output j=0
            a4[0] += u[base + 0] * w;
            a4[1] += u[base + 1] * w;
            a4[2] += u[base + 2] * w;
            a4[3] += u[base + 3] * w;
        }
    }
}

// ---------------- crpe conv + combine (fa precomputed) ---------------------
// grid 1024 XCD-swizzled, block 256. Per output: conv + 2 f4 loads.
__global__ __launch_bounds__(256) void att_kernel(
    const float* __restrict__ q_img, const float* __restrict__ v_img,
    const float* __restrict__ fa_img, const float* __restrict__ da,
    const float* __restrict__ w3, const float* __restrict__ b3,
    const float* __restrict__ w5, const float* __restrict__ b5,
    const float* __restrict__ w7, const float* __restrict__ b7,
    float* __restrict__ att) {
    __shared__ float s[64 * 72];   // cols -4..67 at +4, zero-padded
    __shared__ float wsm[49];
    int o = ((blockIdx.x & 7) << 7) | (blockIdx.x >> 3);   // bijective, 1024%8==0
    int b = o >> 7, c = o & 127;
    int tid = threadIdx.x;
    const float* vp = v_img + (size_t)(b * 128 + c) * 4096;
    for (int idx = tid; idx < 4096; idx += 256) {
        int row = idx >> 6, xx = idx & 63;
        s[row * 72 + xx + 4] = vp[idx];
    }
    for (int idx = tid; idx < 512; idx += 256) {
        int row = idx >> 3, j = idx & 7;
        s[row * 72 + (j < 4 ? j : 64 + j)] = 0.f;
    }
    int kc; const float* wp; float bias;
    if (c < 32)      { kc = 3; wp = w3 + c * 9;         bias = b3[c]; }
    else if (c < 80) { kc = 5; wp = w5 + (c - 32) * 25; bias = b5[c - 32]; }
    else             { kc = 7; wp = w7 + (c - 80) * 49; bias = b7[c - 80]; }
    if (tid < kc * kc) wsm[tid] = wp[tid];
    float dac = da[b * 128 + c];
    size_t rowbase = (size_t)(b * 128 + c) * 4096;
    __syncthreads();
    for (int it = 0; it < 4; ++it) {
        int task = tid + it * 256;
        int y = task >> 4, xx0 = (task & 15) * 4;
        float a4[4] = {bias, bias, bias, bias};
        if (kc == 3)      conv4<3>(s, wsm, y, xx0, a4);
        else if (kc == 5) conv4<5>(s, wsm, y, xx0, a4);
        else              conv4<7>(s, wsm, y, xx0, a4);
        size_t base = rowbase + y * 64 + xx0;
        f32x4 fav = *(const f32x4*)&fa_img[base];
        f32x4 qv  = *(const f32x4*)&q_img[base];
        f32x4 cv4 = {a4[0], a4[1], a4[2], a4[3]};
        f32x4 r = (fav * 0.25f + qv * cv4) * dac;
        *(f32x4*)&att[base] = r;
    }
}

// ---------------- MFMA proj + residual: A = att (image layout) -------------
__global__ __launch_bounds__(256, 2) void proj_mfma_kernel(
    const float* __restrict__ att, const short* __restrict__ wp,
    const float* __restrict__ bias, const float* __restrict__ xres,
    float* __restrict__ out) {
    __shared__ float As[128 * 33];
    int tb = blockIdx.x * 32;
    int tid = threadIdx.x;
    int lane = tid & 63, wv = tid >> 6;
    int lhi = lane >> 4, llo = lane & 15;
    int b = tb >> 12, n0 = tb & 4095;

    for (int idx = tid; idx < 4096; idx += 256) {
        int c = idx >> 5, t = idx & 31;
        As[c * 33 + t] = att[(size_t)(b * 128 + c) * 4096 + n0 + t];
    }
    __syncthreads();

    bf16x8 afr[2][4];
    #pragma unroll
    for (int tt = 0; tt < 2; ++tt) {
        #pragma unroll
        for (int kk = 0; kk < 4; ++kk) {
            int c0 = kk * 32 + lhi * 8;
            int t = tt * 16 + llo;
            bf16x8 v;
            #pragma unroll
            for (int j = 0; j < 8; ++j) v[j] = f2bf(As[(c0 + j) * 33 + t]);
            afr[tt][kk] = v;
        }
    }

    f32x4 acc[2][2];
    f32x4 zr = {0.f, 0.f, 0.f, 0.f};
    #pragma unroll
    for (int i = 0; i < 2; ++i) { acc[i][0] = zr; acc[i][1] = zr; }

    #pragma unroll
    for (int i = 0; i < 2; ++i) {
        int nb = wv * 2 + i;
        #pragma unroll
        for (int kk = 0; kk < 4; ++kk) {
            bf16x8 wf = *(const bf16x8*)&wp[((size_t)(nb * 4 + kk) * 64 + lane) * 8];
            acc[i][0] = __builtin_amdgcn_mfma_f32_16x16x32_bf16(wf, afr[0][kk], acc[i][0], 0, 0, 0);
            acc[i][1] = __builtin_amdgcn_mfma_f32_16x16x32_bf16(wf, afr[1][kk], acc[i][1], 0, 0, 0);
        }
    }

    #pragma unroll
    for (int i = 0; i < 2; ++i) {
        int j0 = (wv * 2 + i) * 16;
        f32x4 bv = *(const f32x4*)(bias + j0 + lhi * 4);
        #pragma unroll
        for (int tt = 0; tt < 2; ++tt) {
            size_t o = (size_t)(tb + tt * 16 + llo) * 128 + j0 + lhi * 4;
            f32x4 xr = *(const f32x4*)(xres + o);
            *(f32x4*)(out + o) = xr + acc[i][tt] + bv;
        }
    }
}

// ---------------- fused MFMA MLP (LN2 fused) -------------------------------
// NOTE: GEMM1 nl loop MUST stay fully unrolled (rule #20 — scratch spill).
__global__ __launch_bounds__(256, 2) void mlp_mfma_kernel(
    const short* __restrict__ w1p, const float* __restrict__ b1p,
    const short* __restrict__ w2p, const float* __restrict__ b2,
    float* io) {
    __shared__ short hs[32768];
    int tb = blockIdx.x * 32;
    int tid = threadIdx.x;
    int lane = tid & 63, wv = tid >> 6;
    int lhi = lane >> 4, llo = lane & 15;

    bf16x8 afr[2][4];
    #pragma unroll
    for (int tt = 0; tt < 2; ++tt) {
        f32x4 v0[4], v1[4];
        float sum = 0.f;
        #pragma unroll
        for (int kk = 0; kk < 4; ++kk) {
            const float* p = io + (size_t)(tb + tt * 16 + llo) * 128 + kk * 32 + lhi * 8;
            v0[kk] = *(const f32x4*)p;
            v1[kk] = *(const f32x4*)(p + 4);
            sum += v0[kk].x + v0[kk].y + v0[kk].z + v0[kk].w
                 + v1[kk].x + v1[kk].y + v1[kk].z + v1[kk].w;
        }
        sum += __shfl_xor(sum, 16, 64);
        sum += __shfl_xor(sum, 32, 64);
        float mean = sum * (1.f / 128.f);
        float vs = 0.f;
        #pragma unroll
        for (int kk = 0; kk < 4; ++kk) {
            f32x4 a = v0[kk], c = v1[kk];
            float d0 = a.x - mean, d1 = a.y - mean, d2 = a.z - mean, d3 = a.w - mean;
            float d4 = c.x - mean, d5 = c.y - mean, d6 = c.z - mean, d7 = c.w - mean;
            vs += d0*d0 + d1*d1 + d2*d2 + d3*d3 + d4*d4 + d5*d5 + d6*d6 + d7*d7;
        }
        vs += __shfl_xor(vs, 16, 64);
        vs += __shfl_xor(vs, 32, 64);
        float rs = rsqrtf(vs * (1.f / 128.f) + EPS_LN);
        #pragma unroll
        for (int kk = 0; kk < 4; ++kk) {
            bf16x8 o;
            o[0] = f2bf((v0[kk].x - mean) * rs);
            o[1] = f2bf((v0[kk].y - mean) * rs);
            o[2] = f2bf((v0[kk].z - mean) * rs);
            o[3] = f2bf((v0[kk].w - mean) * rs);
            o[4] = f2bf((v1[kk].x - mean) * rs);
            o[5] = f2bf((v1[kk].y - mean) * rs);
            o[6] = f2bf((v1[kk].z - mean) * rs);
            o[7] = f2bf((v1[kk].w - mean) * rs);
            afr[tt][kk] = o;
        }
    }

    f32x4 acc[2][16];
    f32x4 zr = {0.f, 0.f, 0.f, 0.f};
    #pragma unroll
    for (int tt = 0; tt < 2; ++tt)
        #pragma unroll
        for (int nl = 0; nl < 16; ++nl) acc[tt][nl] = zr;

    const short* wbase = w1p + (size_t)(wv * 16) * 4 * 64 * 8;
    #pragma unroll
    for (int nl = 0; nl < 16; ++nl) {
        #pragma unroll
        for (int kk = 0; kk < 4; ++kk) {
            bf16x8 bf = *(const bf16x8*)(wbase + ((size_t)(nl * 4 + kk) * 64 + lane) * 8);
            acc[0][nl] = __builtin_amdgcn_mfma_f32_16x16x32_bf16(bf, afr[0][kk], acc[0][nl], 0, 0, 0);
            acc[1][nl] = __builtin_amdgcn_mfma_f32_16x16x32_bf16(bf, afr[1][kk], acc[1][nl], 0, 0, 0);
        }
    }

    #pragma unroll
    for (int nl = 0; nl < 16; ++nl) {
        int hn = wv * 16 + nl;
        int hc0 = hn * 16 + lhi * 4;
        f32x4 bv = *(const f32x4*)(b1p + hc0);
        int kk2 = hn >> 1;
        int lp = llo + 16 * ((hn & 1) * 2 + (lhi >> 1));
        #pragma unroll
        for (int tt = 0; tt < 2; ++tt) {
            f32x4 a = acc[tt][nl] + bv;
            float g0 = 0.5f * a.x * (1.f + erff(a.x * 0.70710678118654752f));
            float g1 = 0.5f * a.y * (1.f + erff(a.y * 0.70710678118654752f));
            float g2 = 0.5f * a.z * (1.f + erff(a.z * 0.70710678118654752f));
            float g3 = 0.5f * a.w * (1.f + erff(a.w * 0.70710678118654752f));
            uint2 wv2;
            wv2.x = pack2bf(g0, g1);
            wv2.y = pack2bf(g2, g3);
            *(uint2*)((char*)hs + ((size_t)(tt * 32 + kk2) * 64 + lp) * 16 + (lhi & 1) * 8) = wv2;
        }
    }
    __syncthreads();

    f32x4 acc2[2][2];
    #pragma unroll
    for (int cn = 0; cn < 2; ++cn)
        #pragma unroll
        for (int tt = 0; tt < 2; ++tt) acc2[cn][tt] = zr;

    const short* w2base = w2p + (size_t)(wv * 2) * 32 * 64 * 8;
    #pragma unroll 4
    for (int kk2 = 0; kk2 < 32; ++kk2) {
        bf16x8 h0 = *(const bf16x8*)&hs[((size_t)(0 * 32 + kk2) * 64 + lane) * 8];
        bf16x8 h1 = *(const bf16x8*)&hs[((size_t)(1 * 32 + kk2) * 64 + lane) * 8];
        bf16x8 w0 = *(const bf16x8*)(w2base + ((size_t)(0 * 32 + kk2) * 64 + lane) * 8);
        bf16x8 w1f = *(const bf16x8*)(w2base + ((size_t)(1 * 32 + kk2) * 64 + lane) * 8);
        acc2[0][0] = __builtin_amdgcn_mfma_f32_16x16x32_bf16(w0, h0, acc2[0][0], 0, 0, 0);
        acc2[0][1] = __builtin_amdgcn_mfma_f32_16x16x32_bf16(w0, h1, acc2[0][1], 0, 0, 0);
        acc2[1][0] = __builtin_amdgcn_mfma_f32_16x16x32_bf16(w1f, h0, acc2[1][0], 0, 0, 0);
        acc2[1][1] = __builtin_amdgcn_mfma_f32_16x16x32_bf16(w1f, h1, acc2[1][1], 0, 0, 0);
    }

    #pragma unroll
    for (int cn = 0; cn < 2; ++cn) {
        int c0 = (wv * 2 + cn) * 16 + lhi * 4;
        f32x4 bv = *(const f32x4*)(b2 + c0);
        #pragma unroll
        for (int tt = 0; tt < 2; ++tt) {
            float* op = io + (size_t)(tb + tt * 16 + llo) * 128 + c0;
            f32x4 r = *(f32x4*)op;
            r = r + acc2[cn][tt] + bv;
            *(f32x4*)op = r;
        }
    }
}

extern "C" void kernel_launch(void* const* d_in, const int* in_sizes, int n_in,
                              void* d_out, int out_size, void* d_ws, size_t ws_size,
                              hipStream_t stream) {
    const float* img   = (const float*)d_in[0];
    const float* dl    = (const float*)d_in[1];
    const float* pe_dw = (const float*)d_in[2];
    const float* pe_pw = (const float*)d_in[3];
    const float* bn_g  = (const float*)d_in[4];
    const float* bn_b  = (const float*)d_in[5];
    const float* bn_m  = (const float*)d_in[6];
    const float* bn_v  = (const float*)d_in[7];
    const float* cpe_w = (const float*)d_in[8];
    const float* cpe_b = (const float*)d_in[9];
    const float* n1_g  = (const float*)d_in[10];
    const float* n1_b  = (const float*)d_in[11];
    const float* qkv_w = (const float*)d_in[12];
    const float* qkv_b = (const float*)d_in[13];
    const float* w3    = (const float*)d_in[14];
    const float* b3    = (const float*)d_in[15];
    const float* w5    = (const float*)d_in[16];
    const float* b5    = (const float*)d_in[17];
    const float* w7    = (const float*)d_in[18];
    const float* b7    = (const float*)d_in[19];
    const float* dw1   = (const float*)d_in[20];
    const float* db1   = (const float*)d_in[21];
    const float* dw2   = (const float*)d_in[22];
    const float* db2   = (const float*)d_in[23];
    const float* pw    = (const float*)d_in[24];
    const float* pb    = (const float*)d_in[25];
    const float* n2_g  = (const float*)d_in[26];
    const float* n2_b  = (const float*)d_in[27];
    const float* f1w   = (const float*)d_in[28];
    const float* f1b   = (const float*)d_in[29];
    const float* f2w   = (const float*)d_in[30];
    const float* f2b   = (const float*)d_in[31];
    const int*   dptr  = (const int*)d_in[32];
    float* out = (float*)d_out;

    char* ws = (char*)d_ws;
    const size_t SZ = (size_t)8 * 128 * 4096 * 4;   // 16,777,216 bytes
    float* t1    = (float*)(ws);            // pe out; dead after cpe -> fa_img
    float* x     = (float*)(ws + SZ);       // residual stream after cpe
    float* q_img = (float*)(ws + 2 * SZ);   // dead after att -> w1p/w2p
    float* k_img = (float*)(ws + 3 * SZ);   // att output after kv
    float* v_img = (float*)(ws + 4 * SZ);
    float* kv    = (float*)(ws + 5 * SZ);                  // 64KB
    float* da    = (float*)(ws + 5 * SZ + 0x10000);        // 4KB
    short* qkvp  = (short*)(ws + 5 * SZ + 0x20000);        // 96KB
    short* pwp   = (short*)(ws + 5 * SZ + 0x40000);        // 32KB
    float* qbp   = (float*)(ws + 5 * SZ + 0x48000);        // folded qkv bias
    float* f1bp  = (float*)(ws + 5 * SZ + 0x4A000);        // folded fc1 bias
    float* kvp   = (float*)(ws + 5 * SZ + 0x50000);        // 512KB
    float* fa_img = t1;                                    // reuse dead t1
    short* w1p   = (short*)(ws + 2 * SZ);                  // 256KB (in dead q)
    short* w2p   = (short*)(ws + 2 * SZ + 262144);         // 256KB

    pack_qkv_kernel<<<24, 256, 0, stream>>>(qkv_w, n1_g, dptr, qkvp);
    fold_qkv_bias_kernel<<<2, 256, 0, stream>>>(qkv_w, qkv_b, n1_b, dptr, qbp);
    pack_pw_kernel<<<8, 256, 0, stream>>>(pw, pwp);
    gate_kernel<<<1, 256, 0, stream>>>(dl, dw1, db1, dw2, db2, da);
    pe_kernel<<<512, 256, 0, stream>>>(img, pe_dw, pe_pw, bn_g, bn_b, bn_m, bn_v, dptr, t1);
    cpe_kernel<<<2048, 256, 0, stream>>>(t1, cpe_w, cpe_b, x);
    qkv_mfma_kernel<<<1024, 256, 0, stream>>>(x, qkvp, qbp, q_img, k_img, v_img);
    softmax_kernel<<<1024, 256, 0, stream>>>(k_img);
    kv_part_kernel<<<512, 256, 0, stream>>>(k_img, v_img, kvp);
    kv_reduce_kernel<<<64, 256, 0, stream>>>(kvp, kv);
    fa_kernel<<<1024, 256, 0, stream>>>(q_img, kv, fa_img);
    att_kernel<<<1024, 256, 0, stream>>>(q_img, v_img, fa_img, da, w3, b3, w5, b5, w7, b7, k_img);
    proj_mfma_kernel<<<1024, 256, 0, stream>>>(k_img, pwp, pb, x, out);
    pack_w1_kernel<<<64, 256, 0, stream>>>(f1w, n2_g, dptr, w1p);
    fold_fc1_bias_kernel<<<4, 256, 0, stream>>>(f1w, f1b, n2_b, dptr, f1bp);
    pack_w2_kernel<<<64, 256, 0, stream>>>(f2w, w2p);
    mlp_mfma_kernel<<<1024, 256, 0, stream>>>(w1p, f1bp, w2p, f2b, out);
}

// Round 10
// 367.641 us; speedup vs baseline: 4.6111x; 1.0326x over previous
//
#include <hip/hip_runtime.h>
#include <math.h>

#define EPS_LN 1e-6f
#define EPS_BN 1e-5f

typedef __attribute__((ext_vector_type(8))) short bf16x8;
typedef __attribute__((ext_vector_type(4))) float f32x4;

__device__ __forceinline__ float wave_reduce_sum(float v) {
    #pragma unroll
    for (int m = 32; m >= 1; m >>= 1) v += __shfl_xor(v, m, 64);
    return v;
}
__device__ __forceinline__ float wave_reduce_max(float v) {
    #pragma unroll
    for (int m = 32; m >= 1; m >>= 1) v = fmaxf(v, __shfl_xor(v, m, 64));
    return v;
}
__device__ __forceinline__ short f2bf(float f) {
    union { float f; unsigned u; } v; v.f = f;
    unsigned r = v.u + 0x7fff + ((v.u >> 16) & 1);
    return (short)(r >> 16);
}
__device__ __forceinline__ unsigned pack2bf(float a, float b) {
    return (unsigned)(unsigned short)f2bf(a) | ((unsigned)(unsigned short)f2bf(b) << 16);
}

// ---------------- patch embed: dw3x3 s2 + pw 64->128 + BN(d) + hardswish ----
__global__ __launch_bounds__(256) void pe_kernel(
    const float* __restrict__ img, const float* __restrict__ dww,
    const float* __restrict__ pww, const float* __restrict__ bn_g,
    const float* __restrict__ bn_b, const float* __restrict__ bn_m,
    const float* __restrict__ bn_v, const int* __restrict__ dptr,
    float* __restrict__ t1) {
    __shared__ float dw[64 * 68];
    __shared__ float wsm[64 * 132];
    int bx = blockIdx.x;
    int b = bx >> 6, y = bx & 63;
    int tid = threadIdx.x;
    int d = *dptr;

    for (int idx = tid; idx < 8192; idx += 256) {
        int co = idx >> 6, ci = idx & 63;
        wsm[ci * 132 + co] = pww[idx];
    }

    for (int it = 0; it < 4; ++it) {
        int task = tid + it * 256;
        int ci = task >> 4, xx0 = (task & 15) * 4;
        const float* ip = img + (size_t)(b * 64 + ci) * 16384;
        const float* wd = dww + ci * 9;
        float a0 = 0.f, a1 = 0.f, a2 = 0.f, a3 = 0.f;
        #pragma unroll
        for (int r = 0; r < 3; ++r) {
            int iy = 2 * y + r;
            if (iy >= 128) continue;
            const float* rp = ip + iy * 128 + 2 * xx0;
            float u[9];
            *(f32x4*)&u[0] = *(const f32x4*)rp;
            *(f32x4*)&u[4] = *(const f32x4*)(rp + 4);
            u[8] = (xx0 < 60) ? rp[8] : 0.f;
            #pragma unroll
            for (int s = 0; s < 3; ++s) {
                float w = wd[r * 3 + s];
                a0 += u[s] * w;
                a1 += u[2 + s] * w;
                a2 += u[4 + s] * w;
                a3 += u[6 + s] * w;
            }
        }
        f32x4 st = {a0, a1, a2, a3};
        *(f32x4*)&dw[ci * 68 + xx0] = st;
    }
    __syncthreads();

    int xg = tid & 15, cog = tid >> 4;
    int xx0 = xg * 4, co0 = cog * 8;
    f32x4 acc[8];
    f32x4 zr = {0.f, 0.f, 0.f, 0.f};
    #pragma unroll
    for (int i = 0; i < 8; ++i) acc[i] = zr;
    for (int ci = 0; ci < 64; ++ci) {
        f32x4 dv = *(const f32x4*)&dw[ci * 68 + xx0];
        f32x4 w0 = *(const f32x4*)&wsm[ci * 132 + co0];
        f32x4 w1 = *(const f32x4*)&wsm[ci * 132 + co0 + 4];
        acc[0] += dv * w0.x; acc[1] += dv * w0.y;
        acc[2] += dv * w0.z; acc[3] += dv * w0.w;
        acc[4] += dv * w1.x; acc[5] += dv * w1.y;
        acc[6] += dv * w1.z; acc[7] += dv * w1.w;
    }
    #pragma unroll
    for (int i = 0; i < 8; ++i) {
        int co = co0 + i;
        float sc = bn_g[d * 128 + co] * rsqrtf(bn_v[d * 128 + co] + EPS_BN);
        float mu = bn_m[d * 128 + co], be = bn_b[d * 128 + co];
        f32x4 v = (acc[i] - mu) * sc + be;
        f32x4 r;
        r.x = v.x * fminf(fmaxf(v.x + 3.f, 0.f), 6.f) * (1.f / 6.f);
        r.y = v.y * fminf(fmaxf(v.y + 3.f, 0.f), 6.f) * (1.f / 6.f);
        r.z = v.z * fminf(fmaxf(v.z + 3.f, 0.f), 6.f) * (1.f / 6.f);
        r.w = v.w * fminf(fmaxf(v.w + 3.f, 0.f), 6.f) * (1.f / 6.f);
        *(f32x4*)&t1[(size_t)(b * 128 + co) * 4096 + y * 64 + xx0] = r;
    }
}

// ---------------- ConvPosEnc ----------------
__global__ __launch_bounds__(256) void cpe_kernel(
    const float* __restrict__ t1, const float* __restrict__ cw,
    const float* __restrict__ cb, float* __restrict__ xout) {
    int bx = blockIdx.x;
    int cq = bx & 3, y = (bx >> 2) & 63, b = bx >> 8;
    int c0 = cq * 32;
    __shared__ float s[3 * 32 * 65];
    int tid = threadIdx.x;
    for (int idx = tid; idx < 3 * 32 * 64; idx += 256) {
        int xx = idx & 63;
        int cl = (idx >> 6) & 31;
        int dy = idx >> 11;
        int yy = y + dy - 1;
        float v = 0.f;
        if (yy >= 0 && yy < 64)
            v = t1[(size_t)(b * 128 + c0 + cl) * 4096 + yy * 64 + xx];
        s[(dy * 32 + cl) * 65 + xx] = v;
    }
    __syncthreads();
    for (int idx = tid; idx < 32 * 64; idx += 256) {
        int cl = idx & 31;
        int xx = idx >> 5;
        int c = c0 + cl;
        float center = s[(32 + cl) * 65 + xx];
        float acc = cb[c];
        #pragma unroll
        for (int dy = 0; dy < 3; ++dy) {
            #pragma unroll
            for (int dx = 0; dx < 3; ++dx) {
                int sx = xx + dx - 1;
                if (sx < 0 || sx >= 64) continue;
                acc += s[(dy * 32 + cl) * 65 + sx] * cw[c * 9 + dy * 3 + dx];
            }
        }
        xout[(size_t)(b * 4096 + y * 64 + xx) * 128 + c] = center + acc;
    }
}

// ---------------- weight packers (LN gamma folded in) ----------------------
__global__ __launch_bounds__(256) void pack_qkv_kernel(
    const float* __restrict__ w, const float* __restrict__ g,
    const int* __restrict__ dptr, short* __restrict__ wp) {
    int idx = blockIdx.x * 256 + threadIdx.x;   // 6144
    int d = *dptr;
    int l = idx & 63, kk = (idx >> 6) & 3, n = idx >> 8;
    int k0 = kk * 32 + (l >> 4) * 8;
    int c = n * 16 + (l & 15);
    bf16x8 v;
    #pragma unroll
    for (int j = 0; j < 8; ++j)
        v[j] = f2bf(g[d * 128 + k0 + j] * w[(size_t)(k0 + j) * 384 + c]);
    *(bf16x8*)&wp[(size_t)idx * 8] = v;
}
__global__ __launch_bounds__(256) void pack_pw_kernel(
    const float* __restrict__ w, short* __restrict__ wp) {
    int idx = blockIdx.x * 256 + threadIdx.x;   // 2048
    int l = idx & 63, kk = (idx >> 6) & 3, n = idx >> 8;
    int k0 = kk * 32 + (l >> 4) * 8;
    int c = n * 16 + (l & 15);
    bf16x8 v;
    #pragma unroll
    for (int j = 0; j < 8; ++j) v[j] = f2bf(w[(size_t)(k0 + j) * 128 + c]);
    *(bf16x8*)&wp[(size_t)idx * 8] = v;
}
__global__ __launch_bounds__(256) void pack_w1_kernel(
    const float* __restrict__ w1, const float* __restrict__ g,
    const int* __restrict__ dptr, short* __restrict__ w1p) {
    int idx = blockIdx.x * 256 + threadIdx.x;   // 16384
    int d = *dptr;
    int l = idx & 63, kk = (idx >> 6) & 3, n = idx >> 8;
    int k0 = kk * 32 + (l >> 4) * 8;
    int c = n * 16 + (l & 15);
    bf16x8 v;
    #pragma unroll
    for (int j = 0; j < 8; ++j)
        v[j] = f2bf(g[d * 128 + k0 + j] * w1[(size_t)(k0 + j) * 1024 + c]);
    *(bf16x8*)&w1p[(size_t)idx * 8] = v;
}
__global__ __launch_bounds__(256) void pack_w2_kernel(
    const float* __restrict__ w2, short* __restrict__ w2p) {
    int idx = blockIdx.x * 256 + threadIdx.x;   // 16384
    int l = idx & 63, kk = (idx >> 6) & 31, n = idx >> 11;
    int k0 = kk * 32 + (l >> 4) * 8;
    int c = n * 16 + (l & 15);
    bf16x8 v;
    #pragma unroll
    for (int j = 0; j < 8; ++j) v[j] = f2bf(w2[(size_t)(k0 + j) * 128 + c]);
    *(bf16x8*)&w2p[(size_t)idx * 8] = v;
}

// ---------------- bias folds: b' = b + beta @ W ----------------------------
__global__ __launch_bounds__(256) void fold_qkv_bias_kernel(
    const float* __restrict__ w, const float* __restrict__ bqkv,
    const float* __restrict__ beta, const int* __restrict__ dptr,
    float* __restrict__ bp) {
    int j = blockIdx.x * 256 + threadIdx.x;
    if (j >= 384) return;
    int d = *dptr;
    float s = bqkv[j];
    for (int k = 0; k < 128; ++k) s += beta[d * 128 + k] * w[(size_t)k * 384 + j];
    bp[j] = s;
}
__global__ __launch_bounds__(256) void fold_fc1_bias_kernel(
    const float* __restrict__ w, const float* __restrict__ b1,
    const float* __restrict__ beta, const int* __restrict__ dptr,
    float* __restrict__ bp) {
    int j = blockIdx.x * 256 + threadIdx.x;
    if (j >= 1024) return;
    int d = *dptr;
    float s = b1[j];
    for (int k = 0; k < 128; ++k) s += beta[d * 128 + k] * w[(size_t)k * 1024 + j];
    bp[j] = s;
}

// ---------------- MFMA QKV (LN1 fused): 512 thr, 8 waves, wave-split tt ----
// wave wv: tt = wv&1 (token half), g = wv>>1 owns channel blocks g*6..g*6+5.
__global__ __launch_bounds__(512, 4) void qkv_mfma_kernel(
    const float* __restrict__ x, const short* __restrict__ wp,
    const float* __restrict__ biasp, float* __restrict__ q_img,
    float* __restrict__ k_img, float* __restrict__ v_img) {
    int tb = blockIdx.x * 32;
    int tid = threadIdx.x;
    int lane = tid & 63, wv = tid >> 6;
    int tt = wv & 1, g = wv >> 1;
    int lhi = lane >> 4, llo = lane & 15;
    int b = tb >> 12, n0 = tb & 4095;

    // LN for this wave's 16 tokens
    bf16x8 afr[4];
    {
        f32x4 v0[4], v1[4];
        float sum = 0.f;
        #pragma unroll
        for (int kk = 0; kk < 4; ++kk) {
            const float* p = x + (size_t)(tb + tt * 16 + llo) * 128 + kk * 32 + lhi * 8;
            v0[kk] = *(const f32x4*)p;
            v1[kk] = *(const f32x4*)(p + 4);
            sum += v0[kk].x + v0[kk].y + v0[kk].z + v0[kk].w
                 + v1[kk].x + v1[kk].y + v1[kk].z + v1[kk].w;
        }
        sum += __shfl_xor(sum, 16, 64);
        sum += __shfl_xor(sum, 32, 64);
        float mean = sum * (1.f / 128.f);
        float vs = 0.f;
        #pragma unroll
        for (int kk = 0; kk < 4; ++kk) {
            f32x4 a = v0[kk], c = v1[kk];
            float d0 = a.x - mean, d1 = a.y - mean, d2 = a.z - mean, d3 = a.w - mean;
            float d4 = c.x - mean, d5 = c.y - mean, d6 = c.z - mean, d7 = c.w - mean;
            vs += d0*d0 + d1*d1 + d2*d2 + d3*d3 + d4*d4 + d5*d5 + d6*d6 + d7*d7;
        }
        vs += __shfl_xor(vs, 16, 64);
        vs += __shfl_xor(vs, 32, 64);
        float rs = rsqrtf(vs * (1.f / 128.f) + EPS_LN);
        #pragma unroll
        for (int kk = 0; kk < 4; ++kk) {
            bf16x8 o;
            o[0] = f2bf((v0[kk].x - mean) * rs);
            o[1] = f2bf((v0[kk].y - mean) * rs);
            o[2] = f2bf((v0[kk].z - mean) * rs);
            o[3] = f2bf((v0[kk].w - mean) * rs);
            o[4] = f2bf((v1[kk].x - mean) * rs);
            o[5] = f2bf((v1[kk].y - mean) * rs);
            o[6] = f2bf((v1[kk].z - mean) * rs);
            o[7] = f2bf((v1[kk].w - mean) * rs);
            afr[kk] = o;
        }
    }

    f32x4 acc[6];
    f32x4 zr = {0.f, 0.f, 0.f, 0.f};
    #pragma unroll
    for (int i = 0; i < 6; ++i) acc[i] = zr;

    #pragma unroll
    for (int i = 0; i < 6; ++i) {
        int nb = g * 6 + i;
        #pragma unroll
        for (int kk = 0; kk < 4; ++kk) {
            bf16x8 wf = *(const bf16x8*)&wp[((size_t)(nb * 4 + kk) * 64 + lane) * 8];
            acc[i] = __builtin_amdgcn_mfma_f32_16x16x32_bf16(wf, afr[kk], acc[i], 0, 0, 0);
        }
    }

    #pragma unroll
    for (int i = 0; i < 6; ++i) {
        int j0 = (g * 6 + i) * 16;
        f32x4 bv = *(const f32x4*)(biasp + j0 + lhi * 4);
        float* dst = (j0 < 128) ? q_img : ((j0 < 256) ? k_img : v_img);
        int c0 = (j0 & 127) + lhi * 4;
        f32x4 r = acc[i] + bv;
        float* p = dst + (size_t)(b * 128 + c0) * 4096 + n0 + tt * 16 + llo;
        p[0]        = r.x;
        p[4096]     = r.y;
        p[2 * 4096] = r.z;
        p[3 * 4096] = r.w;
    }
}

// ---------------- softmax over N ---------------
__global__ __launch_bounds__(256) void softmax_kernel(float* __restrict__ k_img) {
    __shared__ float red[4];
    float* p = k_img + (size_t)blockIdx.x * 4096;
    int tid = threadIdx.x;
    float v[16];
    float mx = -1e30f;
    #pragma unroll
    for (int i = 0; i < 16; ++i) {
        v[i] = p[tid + i * 256];
        mx = fmaxf(mx, v[i]);
    }
    mx = wave_reduce_max(mx);
    int wid = tid >> 6, lane = tid & 63;
    if (lane == 0) red[wid] = mx;
    __syncthreads();
    mx = fmaxf(fmaxf(red[0], red[1]), fmaxf(red[2], red[3]));
    __syncthreads();
    float sum = 0.f;
    #pragma unroll
    for (int i = 0; i < 16; ++i) {
        v[i] = expf(v[i] - mx);
        sum += v[i];
    }
    sum = wave_reduce_sum(sum);
    if (lane == 0) red[wid] = sum;
    __syncthreads();
    float inv = 1.f / (red[0] + red[1] + red[2] + red[3]);
    #pragma unroll
    for (int i = 0; i < 16; ++i)
        p[tid + i * 256] = v[i] * inv;
}

// ---------------- kv partial: grid 512 = bh*8+chunk, n-chunk of 512 --------
__global__ __launch_bounds__(256) void kv_part_kernel(
    const float* __restrict__ k_img, const float* __restrict__ v_img,
    float* __restrict__ kvp) {
    __shared__ float ks[16 * 132], vs[16 * 132];
    int bc = blockIdx.x;
    int bh = bc >> 3, chunk = bc & 7;
    int b = bh >> 3, h = bh & 7;
    int tid = threadIdx.x;
    int ck = tid >> 4, cv = tid & 15;
    float acc = 0.f;
    const float* kp = k_img + (size_t)(b * 128 + h * 16) * 4096;
    const float* vp = v_img + (size_t)(b * 128 + h * 16) * 4096;
    int nb0 = chunk * 512;
    for (int nb = nb0; nb < nb0 + 512; nb += 128) {
        for (int idx = tid; idx < 2048; idx += 256) {
            int r = idx >> 7, col = idx & 127;
            ks[r * 132 + col] = kp[(size_t)r * 4096 + nb + col];
            vs[r * 132 + col] = vp[(size_t)r * 4096 + nb + col];
        }
        __syncthreads();
        for (int kk = 0; kk < 128; ++kk)
            acc += ks[ck * 132 + kk] * vs[cv * 132 + kk];
        __syncthreads();
    }
    kvp[(size_t)(chunk * 64 + bh) * 256 + ck * 16 + cv] = acc;
}
__global__ __launch_bounds__(256) void kv_reduce_kernel(
    const float* __restrict__ kvp, float* __restrict__ kv) {
    int i = blockIdx.x * 256 + threadIdx.x;   // 16384
    float s = 0.f;
    #pragma unroll
    for (int c = 0; c < 8; ++c) s += kvp[(size_t)c * 16384 + i];
    kv[i] = s;
}

// ---------------- fa[b,c,n] = sum_ck kv[b,h,ck,cv] * q[b,h*16+ck,n] --------
__global__ __launch_bounds__(256) void fa_kernel(
    const float* __restrict__ q_img, const float* __restrict__ kv,
    float* __restrict__ fa_img) {
    __shared__ float kvs[256];
    int bid = blockIdx.x;
    int bh = bid >> 4, chunk = bid & 15;
    int b = bh >> 3, h = bh & 7;
    int tid = threadIdx.x;
    kvs[tid] = kv[bh * 256 + tid];
    __syncthreads();
    int n = chunk * 256 + tid;
    const float* qp = q_img + (size_t)(b * 128 + h * 16) * 4096 + n;
    float qv[16];
    #pragma unroll
    for (int ck = 0; ck < 16; ++ck) qv[ck] = qp[(size_t)ck * 4096];
    float* fp = fa_img + (size_t)(b * 128 + h * 16) * 4096 + n;
    #pragma unroll
    for (int cv = 0; cv < 16; ++cv) {
        float s = 0.f;
        #pragma unroll
        for (int ck = 0; ck < 16; ++ck) s += qv[ck] * kvs[ck * 16 + cv];
        fp[(size_t)cv * 4096] = s;
    }
}

// ---------------- domain gate --------------------------------
__global__ __launch_bounds__(256) void gate_kernel(
    const float* __restrict__ dl, const float* __restrict__ w1,
    const float* __restrict__ b1, const float* __restrict__ w2,
    const float* __restrict__ b2, float* __restrict__ da) {
    __shared__ float hid[512];
    __shared__ float raw[1024];
    int tid = threadIdx.x;
    for (int idx = tid; idx < 512; idx += 256) {
        int b = idx >> 6, jj = idx & 63;
        float a = b1[jj];
        #pragma unroll
        for (int dd = 0; dd < 4; ++dd)
            a += dl[b * 4 + dd] * w1[dd * 64 + jj];
        hid[idx] = fmaxf(a, 0.f);
    }
    __syncthreads();
    for (int idx = tid; idx < 1024; idx += 256) {
        int b = idx >> 7, c = idx & 127;
        float a = b2[c];
        for (int jj = 0; jj < 64; ++jj)
            a += hid[b * 64 + jj] * w2[jj * 128 + c];
        raw[idx] = a;
    }
    __syncthreads();
    if (tid < 128) {
        int b = tid >> 4, ch = tid & 15;
        float mx = -1e30f;
        #pragma unroll
        for (int hh = 0; hh < 8; ++hh)
            mx = fmaxf(mx, raw[b * 128 + hh * 16 + ch]);
        float e[8];
        float s = 0.f;
        #pragma unroll
        for (int hh = 0; hh < 8; ++hh) {
            e[hh] = expf(raw[b * 128 + hh * 16 + ch] - mx);
            s += e[hh];
        }
        float inv = 1.f / s;
        #pragma unroll
        for (int hh = 0; hh < 8; ++hh)
            da[b * 128 + hh * 16 + ch] = e[hh] * inv;
    }
}

// ---------------- conv helper: 4 outputs, compile-time KC (rule #20) -------
template<int KC>
__device__ __forceinline__ void conv4(const float* __restrict__ s,
                                      const float* __restrict__ wsm,
                                      int y, int xx0, float* a4) {
    const int OFF = KC / 2;
    #pragma unroll
    for (int dy = 0; dy < KC; ++dy) {
        int sy = y + dy - OFF;
        if (sy < 0 || sy >= 64) continue;
        const float* r = s + sy * 72;
        float u[12];
        *(f32x4*)&u[0] = *(const f32x4*)&r[xx0];
        *(f32x4*)&u[4] = *(const f32x4*)&r[xx0 + 4];
        *(f32x4*)&u[8] = *(const f32x4*)&r[xx0 + 8];
        #pragma unroll
        for (int dx = 0; dx < KC; ++dx) {
            float w = wsm[dy * KC + dx];
            const int base = dx - OFF + 4;
            a4[0] += u[base + 0] * w;
            a4[1] += u[base + 1] * w;
            a4[2] += u[base + 2] * w;
            a4[3] += u[base + 3] * w;
        }
    }
}

// ---------------- crpe conv + combine (fa precomputed) ---------------------
__global__ __launch_bounds__(256) void att_kernel(
    const float* __restrict__ q_img, const float* __restrict__ v_img,
    const float* __restrict__ fa_img, const float* __restrict__ da,
    const float* __restrict__ w3, const float* __restrict__ b3,
    const float* __restrict__ w5, const float* __restrict__ b5,
    const float* __restrict__ w7, const float* __restrict__ b7,
    float* __restrict__ att) {
    __shared__ float s[64 * 72];
    __shared__ float wsm[49];
    int o = ((blockIdx.x & 7) << 7) | (blockIdx.x >> 3);
    int b = o >> 7, c = o & 127;
    int tid = threadIdx.x;
    const float* vp = v_img + (size_t)(b * 128 + c) * 4096;
    for (int idx = tid; idx < 4096; idx += 256) {
        int row = idx >> 6, xx = idx & 63;
        s[row * 72 + xx + 4] = vp[idx];
    }
    for (int idx = tid; idx < 512; idx += 256) {
        int row = idx >> 3, j = idx & 7;
        s[row * 72 + (j < 4 ? j : 64 + j)] = 0.f;
    }
    int kc; const float* wp; float bias;
    if (c < 32)      { kc = 3; wp = w3 + c * 9;         bias = b3[c]; }
    else if (c < 80) { kc = 5; wp = w5 + (c - 32) * 25; bias = b5[c - 32]; }
    else             { kc = 7; wp = w7 + (c - 80) * 49; bias = b7[c - 80]; }
    if (tid < kc * kc) wsm[tid] = wp[tid];
    float dac = da[b * 128 + c];
    size_t rowbase = (size_t)(b * 128 + c) * 4096;
    __syncthreads();
    for (int it = 0; it < 4; ++it) {
        int task = tid + it * 256;
        int y = task >> 4, xx0 = (task & 15) * 4;
        float a4[4] = {bias, bias, bias, bias};
        if (kc == 3)      conv4<3>(s, wsm, y, xx0, a4);
        else if (kc == 5) conv4<5>(s, wsm, y, xx0, a4);
        else              conv4<7>(s, wsm, y, xx0, a4);
        size_t base = rowbase + y * 64 + xx0;
        f32x4 fav = *(const f32x4*)&fa_img[base];
        f32x4 qv  = *(const f32x4*)&q_img[base];
        f32x4 cv4 = {a4[0], a4[1], a4[2], a4[3]};
        f32x4 r = (fav * 0.25f + qv * cv4) * dac;
        *(f32x4*)&att[base] = r;
    }
}

// ---------------- MFMA proj + residual: A = att (image layout) -------------
__global__ __launch_bounds__(256, 2) void proj_mfma_kernel(
    const float* __restrict__ att, const short* __restrict__ wp,
    const float* __restrict__ bias, const float* __restrict__ xres,
    float* __restrict__ out) {
    __shared__ float As[128 * 33];
    int tb = blockIdx.x * 32;
    int tid = threadIdx.x;
    int lane = tid & 63, wv = tid >> 6;
    int lhi = lane >> 4, llo = lane & 15;
    int b = tb >> 12, n0 = tb & 4095;

    for (int idx = tid; idx < 4096; idx += 256) {
        int c = idx >> 5, t = idx & 31;
        As[c * 33 + t] = att[(size_t)(b * 128 + c) * 4096 + n0 + t];
    }
    __syncthreads();

    bf16x8 afr[2][4];
    #pragma unroll
    for (int tt = 0; tt < 2; ++tt) {
        #pragma unroll
        for (int kk = 0; kk < 4; ++kk) {
            int c0 = kk * 32 + lhi * 8;
            int t = tt * 16 + llo;
            bf16x8 v;
            #pragma unroll
            for (int j = 0; j < 8; ++j) v[j] = f2bf(As[(c0 + j) * 33 + t]);
            afr[tt][kk] = v;
        }
    }

    f32x4 acc[2][2];
    f32x4 zr = {0.f, 0.f, 0.f, 0.f};
    #pragma unroll
    for (int i = 0; i < 2; ++i) { acc[i][0] = zr; acc[i][1] = zr; }

    #pragma unroll
    for (int i = 0; i < 2; ++i) {
        int nb = wv * 2 + i;
        #pragma unroll
        for (int kk = 0; kk < 4; ++kk) {
            bf16x8 wf = *(const bf16x8*)&wp[((size_t)(nb * 4 + kk) * 64 + lane) * 8];
            acc[i][0] = __builtin_amdgcn_mfma_f32_16x16x32_bf16(wf, afr[0][kk], acc[i][0], 0, 0, 0);
            acc[i][1] = __builtin_amdgcn_mfma_f32_16x16x32_bf16(wf, afr[1][kk], acc[i][1], 0, 0, 0);
        }
    }

    #pragma unroll
    for (int i = 0; i < 2; ++i) {
        int j0 = (wv * 2 + i) * 16;
        f32x4 bv = *(const f32x4*)(bias + j0 + lhi * 4);
        #pragma unroll
        for (int tt = 0; tt < 2; ++tt) {
            size_t o = (size_t)(tb + tt * 16 + llo) * 128 + j0 + lhi * 4;
            f32x4 xr = *(const f32x4*)(xres + o);
            *(f32x4*)(out + o) = xr + acc[i][tt] + bv;
        }
    }
}

// ---------------- fused MFMA MLP (LN2 fused): 512 thr, 8 waves -------------
// GEMM1: wave wv -> tt = wv&1, hidden group g = wv>>1 (hn = g*16+nl, nl<16).
// GEMM2: wave wv -> cout block wv, both token halves.
// NOTE: nl loop MUST stay fully unrolled (rule #20 — scratch spill).
__global__ __launch_bounds__(512, 4) void mlp_mfma_kernel(
    const short* __restrict__ w1p, const float* __restrict__ b1p,
    const short* __restrict__ w2p, const float* __restrict__ b2,
    float* io) {
    __shared__ short hs[32768];
    int tb = blockIdx.x * 32;
    int tid = threadIdx.x;
    int lane = tid & 63, wv = tid >> 6;
    int tt = wv & 1, g = wv >> 1;
    int lhi = lane >> 4, llo = lane & 15;

    bf16x8 afr[4];
    {
        f32x4 v0[4], v1[4];
        float sum = 0.f;
        #pragma unroll
        for (int kk = 0; kk < 4; ++kk) {
            const float* p = io + (size_t)(tb + tt * 16 + llo) * 128 + kk * 32 + lhi * 8;
            v0[kk] = *(const f32x4*)p;
            v1[kk] = *(const f32x4*)(p + 4);
            sum += v0[kk].x + v0[kk].y + v0[kk].z + v0[kk].w
                 + v1[kk].x + v1[kk].y + v1[kk].z + v1[kk].w;
        }
        sum += __shfl_xor(sum, 16, 64);
        sum += __shfl_xor(sum, 32, 64);
        float mean = sum * (1.f / 128.f);
        float vs = 0.f;
        #pragma unroll
        for (int kk = 0; kk < 4; ++kk) {
            f32x4 a = v0[kk], c = v1[kk];
            float d0 = a.x - mean, d1 = a.y - mean, d2 = a.z - mean, d3 = a.w - mean;
            float d4 = c.x - mean, d5 = c.y - mean, d6 = c.z - mean, d7 = c.w - mean;
            vs += d0*d0 + d1*d1 + d2*d2 + d3*d3 + d4*d4 + d5*d5 + d6*d6 + d7*d7;
        }
        vs += __shfl_xor(vs, 16, 64);
        vs += __shfl_xor(vs, 32, 64);
        float rs = rsqrtf(vs * (1.f / 128.f) + EPS_LN);
        #pragma unroll
        for (int kk = 0; kk < 4; ++kk) {
            bf16x8 o;
            o[0] = f2bf((v0[kk].x - mean) * rs);
            o[1] = f2bf((v0[kk].y - mean) * rs);
            o[2] = f2bf((v0[kk].z - mean) * rs);
            o[3] = f2bf((v0[kk].w - mean) * rs);
            o[4] = f2bf((v1[kk].x - mean) * rs);
            o[5] = f2bf((v1[kk].y - mean) * rs);
            o[6] = f2bf((v1[kk].z - mean) * rs);
            o[7] = f2bf((v1[kk].w - mean) * rs);
            afr[kk] = o;
        }
    }

    f32x4 acc[16];
    f32x4 zr = {0.f, 0.f, 0.f, 0.f};
    #pragma unroll
    for (int nl = 0; nl < 16; ++nl) acc[nl] = zr;

    const short* wbase = w1p + (size_t)(g * 16) * 4 * 64 * 8;
    #pragma unroll
    for (int nl = 0; nl < 16; ++nl) {
        #pragma unroll
        for (int kk = 0; kk < 4; ++kk) {
            bf16x8 bf = *(const bf16x8*)(wbase + ((size_t)(nl * 4 + kk) * 64 + lane) * 8);
            acc[nl] = __builtin_amdgcn_mfma_f32_16x16x32_bf16(bf, afr[kk], acc[nl], 0, 0, 0);
        }
    }

    #pragma unroll
    for (int nl = 0; nl < 16; ++nl) {
        int hn = g * 16 + nl;
        int hc0 = hn * 16 + lhi * 4;
        f32x4 bv = *(const f32x4*)(b1p + hc0);
        int kk2 = hn >> 1;
        int lp = llo + 16 * ((hn & 1) * 2 + (lhi >> 1));
        f32x4 a = acc[nl] + bv;
        float g0 = 0.5f * a.x * (1.f + erff(a.x * 0.70710678118654752f));
        float g1 = 0.5f * a.y * (1.f + erff(a.y * 0.70710678118654752f));
        float g2 = 0.5f * a.z * (1.f + erff(a.z * 0.70710678118654752f));
        float g3 = 0.5f * a.w * (1.f + erff(a.w * 0.70710678118654752f));
        uint2 wv2;
        wv2.x = pack2bf(g0, g1);
        wv2.y = pack2bf(g2, g3);
        *(uint2*)((char*)hs + ((size_t)(tt * 32 + kk2) * 64 + lp) * 16 + (lhi & 1) * 8) = wv2;
    }
    __syncthreads();

    f32x4 acc2[2];
    acc2[0] = zr; acc2[1] = zr;

    const short* w2base = w2p + (size_t)wv * 32 * 64 * 8;
    #pragma unroll 4
    for (int kk2 = 0; kk2 < 32; ++kk2) {
        bf16x8 h0 = *(const bf16x8*)&hs[((size_t)(0 * 32 + kk2) * 64 + lane) * 8];
        bf16x8 h1 = *(const bf16x8*)&hs[((size_t)(1 * 32 + kk2) * 64 + lane) * 8];
        bf16x8 w0 = *(const bf16x8*)(w2base + ((size_t)kk2 * 64 + lane) * 8);
        acc2[0] = __builtin_amdgcn_mfma_f32_16x16x32_bf16(w0, h0, acc2[0], 0, 0, 0);
        acc2[1] = __builtin_amdgcn_mfma_f32_16x16x32_bf16(w0, h1, acc2[1], 0, 0, 0);
    }

    int c0 = wv * 16 + lhi * 4;
    f32x4 bv = *(const f32x4*)(b2 + c0);
    #pragma unroll
    for (int tt2 = 0; tt2 < 2; ++tt2) {
        float* op = io + (size_t)(tb + tt2 * 16 + llo) * 128 + c0;
        f32x4 r = *(f32x4*)op;
        r = r + acc2[tt2] + bv;
        *(f32x4*)op = r;
    }
}

extern "C" void kernel_launch(void* const* d_in, const int* in_sizes, int n_in,
                              void* d_out, int out_size, void* d_ws, size_t ws_size,
                              hipStream_t stream) {
    const float* img   = (const float*)d_in[0];
    const float* dl    = (const float*)d_in[1];
    const float* pe_dw = (const float*)d_in[2];
    const float* pe_pw = (const float*)d_in[3];
    const float* bn_g  = (const float*)d_in[4];
    const float* bn_b  = (const float*)d_in[5];
    const float* bn_m  = (const float*)d_in[6];
    const float* bn_v  = (const float*)d_in[7];
    const float* cpe_w = (const float*)d_in[8];
    const float* cpe_b = (const float*)d_in[9];
    const float* n1_g  = (const float*)d_in[10];
    const float* n1_b  = (const float*)d_in[11];
    const float* qkv_w = (const float*)d_in[12];
    const float* qkv_b = (const float*)d_in[13];
    const float* w3    = (const float*)d_in[14];
    const float* b3    = (const float*)d_in[15];
    const float* w5    = (const float*)d_in[16];
    const float* b5    = (const float*)d_in[17];
    const float* w7    = (const float*)d_in[18];
    const float* b7    = (const float*)d_in[19];
    const float* dw1   = (const float*)d_in[20];
    const float* db1   = (const float*)d_in[21];
    const float* dw2   = (const float*)d_in[22];
    const float* db2   = (const float*)d_in[23];
    const float* pw    = (const float*)d_in[24];
    const float* pb    = (const float*)d_in[25];
    const float* n2_g  = (const float*)d_in[26];
    const float* n2_b  = (const float*)d_in[27];
    const float* f1w   = (const float*)d_in[28];
    const float* f1b   = (const float*)d_in[29];
    const float* f2w   = (const float*)d_in[30];
    const float* f2b   = (const float*)d_in[31];
    const int*   dptr  = (const int*)d_in[32];
    float* out = (float*)d_out;

    char* ws = (char*)d_ws;
    const size_t SZ = (size_t)8 * 128 * 4096 * 4;   // 16,777,216 bytes
    float* t1    = (float*)(ws);            // pe out; dead after cpe -> fa_img
    float* x     = (float*)(ws + SZ);       // residual stream after cpe
    float* q_img = (float*)(ws + 2 * SZ);   // dead after att -> w1p/w2p
    float* k_img = (float*)(ws + 3 * SZ);   // att output after kv
    float* v_img = (float*)(ws + 4 * SZ);
    float* kv    = (float*)(ws + 5 * SZ);                  // 64KB
    float* da    = (float*)(ws + 5 * SZ + 0x10000);        // 4KB
    short* qkvp  = (short*)(ws + 5 * SZ + 0x20000);        // 96KB
    short* pwp   = (short*)(ws + 5 * SZ + 0x40000);        // 32KB
    float* qbp   = (float*)(ws + 5 * SZ + 0x48000);        // folded qkv bias
    float* f1bp  = (float*)(ws + 5 * SZ + 0x4A000);        // folded fc1 bias
    float* kvp   = (float*)(ws + 5 * SZ + 0x50000);        // 512KB
    float* fa_img = t1;                                    // reuse dead t1
    short* w1p   = (short*)(ws + 2 * SZ);                  // 256KB (in dead q)
    short* w2p   = (short*)(ws + 2 * SZ + 262144);         // 256KB

    pack_qkv_kernel<<<24, 256, 0, stream>>>(qkv_w, n1_g, dptr, qkvp);
    fold_qkv_bias_kernel<<<2, 256, 0, stream>>>(qkv_w, qkv_b, n1_b, dptr, qbp);
    pack_pw_kernel<<<8, 256, 0, stream>>>(pw, pwp);
    gate_kernel<<<1, 256, 0, stream>>>(dl, dw1, db1, dw2, db2, da);
    pe_kernel<<<512, 256, 0, stream>>>(img, pe_dw, pe_pw, bn_g, bn_b, bn_m, bn_v, dptr, t1);
    cpe_kernel<<<2048, 256, 0, stream>>>(t1, cpe_w, cpe_b, x);
    qkv_mfma_kernel<<<1024, 512, 0, stream>>>(x, qkvp, qbp, q_img, k_img, v_img);
    softmax_kernel<<<1024, 256, 0, stream>>>(k_img);
    kv_part_kernel<<<512, 256, 0, stream>>>(k_img, v_img, kvp);
    kv_reduce_kernel<<<64, 256, 0, stream>>>(kvp, kv);
    fa_kernel<<<1024, 256, 0, stream>>>(q_img, kv, fa_img);
    att_kernel<<<1024, 256, 0, stream>>>(q_img, v_img, fa_img, da, w3, b3, w5, b5, w7, b7, k_img);
    proj_mfma_kernel<<<1024, 256, 0, stream>>>(k_img, pwp, pb, x, out);
    pack_w1_kernel<<<64, 256, 0, stream>>>(f1w, n2_g, dptr, w1p);
    fold_fc1_bias_kernel<<<4, 256, 0, stream>>>(f1w, f1b, n2_b, dptr, f1bp);
    pack_w2_kernel<<<64, 256, 0, stream>>>(f2w, w2p);
    mlp_mfma_kernel<<<1024, 512, 0, stream>>>(w1p, f1bp, w2p, f2b, out);
}

// Round 11
// 337.857 us; speedup vs baseline: 5.0176x; 1.0882x over previous
//
#include <hip/hip_runtime.h>
#include <math.h>

#define EPS_LN 1e-6f
#define EPS_BN 1e-5f

typedef __attribute__((ext_vector_type(8))) short bf16x8;
typedef __attribute__((ext_vector_type(4))) float f32x4;

__device__ __forceinline__ float wave_reduce_sum(float v) {
    #pragma unroll
    for (int m = 32; m >= 1; m >>= 1) v += __shfl_xor(v, m, 64);
    return v;
}
__device__ __forceinline__ float wave_reduce_max(float v) {
    #pragma unroll
    for (int m = 32; m >= 1; m >>= 1) v = fmaxf(v, __shfl_xor(v, m, 64));
    return v;
}
__device__ __forceinline__ short f2bf(float f) {
    union { float f; unsigned u; } v; v.f = f;
    unsigned r = v.u + 0x7fff + ((v.u >> 16) & 1);
    return (short)(r >> 16);
}
__device__ __forceinline__ unsigned pack2bf(float a, float b) {
    return (unsigned)(unsigned short)f2bf(a) | ((unsigned)(unsigned short)f2bf(b) << 16);
}
// tanh-approx gelu (sigmoid form): x*sigmoid(1.5958x + 0.14270x^3); ~8 VALU ops
__device__ __forceinline__ float gelu_f(float x) {
    float x2 = x * x;
    float u = x * (-1.595769122f - 0.071354816f * x2) * 1.0f;  // -2*0.79788*(x+0.044715x^3)
    float e = __expf(u);
    return x * __builtin_amdgcn_rcpf(1.f + e);
}

// ---------------- patch embed: dw3x3 s2 + pw 64->128 + BN(d) + hardswish ----
__global__ __launch_bounds__(256) void pe_kernel(
    const float* __restrict__ img, const float* __restrict__ dww,
    const float* __restrict__ pww, const float* __restrict__ bn_g,
    const float* __restrict__ bn_b, const float* __restrict__ bn_m,
    const float* __restrict__ bn_v, const int* __restrict__ dptr,
    float* __restrict__ t1) {
    __shared__ float dw[64 * 68];
    __shared__ float wsm[64 * 132];
    int bx = blockIdx.x;
    int b = bx >> 6, y = bx & 63;
    int tid = threadIdx.x;
    int d = *dptr;

    for (int idx = tid; idx < 8192; idx += 256) {
        int co = idx >> 6, ci = idx & 63;
        wsm[ci * 132 + co] = pww[idx];
    }

    for (int it = 0; it < 4; ++it) {
        int task = tid + it * 256;
        int ci = task >> 4, xx0 = (task & 15) * 4;
        const float* ip = img + (size_t)(b * 64 + ci) * 16384;
        const float* wd = dww + ci * 9;
        float a0 = 0.f, a1 = 0.f, a2 = 0.f, a3 = 0.f;
        #pragma unroll
        for (int r = 0; r < 3; ++r) {
            int iy = 2 * y + r;
            if (iy >= 128) continue;
            const float* rp = ip + iy * 128 + 2 * xx0;
            float u[9];
            *(f32x4*)&u[0] = *(const f32x4*)rp;
            *(f32x4*)&u[4] = *(const f32x4*)(rp + 4);
            u[8] = (xx0 < 60) ? rp[8] : 0.f;
            #pragma unroll
            for (int s = 0; s < 3; ++s) {
                float w = wd[r * 3 + s];
                a0 += u[s] * w;
                a1 += u[2 + s] * w;
                a2 += u[4 + s] * w;
                a3 += u[6 + s] * w;
            }
        }
        f32x4 st = {a0, a1, a2, a3};
        *(f32x4*)&dw[ci * 68 + xx0] = st;
    }
    __syncthreads();

    int xg = tid & 15, cog = tid >> 4;
    int xx0 = xg * 4, co0 = cog * 8;
    f32x4 acc[8];
    f32x4 zr = {0.f, 0.f, 0.f, 0.f};
    #pragma unroll
    for (int i = 0; i < 8; ++i) acc[i] = zr;
    for (int ci = 0; ci < 64; ++ci) {
        f32x4 dv = *(const f32x4*)&dw[ci * 68 + xx0];
        f32x4 w0 = *(const f32x4*)&wsm[ci * 132 + co0];
        f32x4 w1 = *(const f32x4*)&wsm[ci * 132 + co0 + 4];
        acc[0] += dv * w0.x; acc[1] += dv * w0.y;
        acc[2] += dv * w0.z; acc[3] += dv * w0.w;
        acc[4] += dv * w1.x; acc[5] += dv * w1.y;
        acc[6] += dv * w1.z; acc[7] += dv * w1.w;
    }
    #pragma unroll
    for (int i = 0; i < 8; ++i) {
        int co = co0 + i;
        float sc = bn_g[d * 128 + co] * rsqrtf(bn_v[d * 128 + co] + EPS_BN);
        float mu = bn_m[d * 128 + co], be = bn_b[d * 128 + co];
        f32x4 v = (acc[i] - mu) * sc + be;
        f32x4 r;
        r.x = v.x * fminf(fmaxf(v.x + 3.f, 0.f), 6.f) * (1.f / 6.f);
        r.y = v.y * fminf(fmaxf(v.y + 3.f, 0.f), 6.f) * (1.f / 6.f);
        r.z = v.z * fminf(fmaxf(v.z + 3.f, 0.f), 6.f) * (1.f / 6.f);
        r.w = v.w * fminf(fmaxf(v.w + 3.f, 0.f), 6.f) * (1.f / 6.f);
        *(f32x4*)&t1[(size_t)(b * 128 + co) * 4096 + y * 64 + xx0] = r;
    }
}

// ---------------- ConvPosEnc ----------------
__global__ __launch_bounds__(256) void cpe_kernel(
    const float* __restrict__ t1, const float* __restrict__ cw,
    const float* __restrict__ cb, float* __restrict__ xout) {
    int bx = blockIdx.x;
    int cq = bx & 3, y = (bx >> 2) & 63, b = bx >> 8;
    int c0 = cq * 32;
    __shared__ float s[3 * 32 * 65];
    int tid = threadIdx.x;
    for (int idx = tid; idx < 3 * 32 * 64; idx += 256) {
        int xx = idx & 63;
        int cl = (idx >> 6) & 31;
        int dy = idx >> 11;
        int yy = y + dy - 1;
        float v = 0.f;
        if (yy >= 0 && yy < 64)
            v = t1[(size_t)(b * 128 + c0 + cl) * 4096 + yy * 64 + xx];
        s[(dy * 32 + cl) * 65 + xx] = v;
    }
    __syncthreads();
    for (int idx = tid; idx < 32 * 64; idx += 256) {
        int cl = idx & 31;
        int xx = idx >> 5;
        int c = c0 + cl;
        float center = s[(32 + cl) * 65 + xx];
        float acc = cb[c];
        #pragma unroll
        for (int dy = 0; dy < 3; ++dy) {
            #pragma unroll
            for (int dx = 0; dx < 3; ++dx) {
                int sx = xx + dx - 1;
                if (sx < 0 || sx >= 64) continue;
                acc += s[(dy * 32 + cl) * 65 + sx] * cw[c * 9 + dy * 3 + dx];
            }
        }
        xout[(size_t)(b * 4096 + y * 64 + xx) * 128 + c] = center + acc;
    }
}

// ---------------- fused prep: all weight packs + bias folds + gate ---------
// blocks 0-23 pack_qkv | 24-31 pack_pw | 32-95 pack_w1 | 96-159 pack_w2 |
// 160-161 fold_qkv_bias | 162-165 fold_fc1_bias | 166 gate
__global__ __launch_bounds__(256) void prep_kernel(
    const float* __restrict__ qkv_w, const float* __restrict__ n1_g,
    const float* __restrict__ n1_b, const float* __restrict__ qkv_b,
    const float* __restrict__ pw, const float* __restrict__ f1w,
    const float* __restrict__ n2_g, const float* __restrict__ n2_b,
    const float* __restrict__ f1b, const float* __restrict__ f2w,
    const float* __restrict__ dl, const float* __restrict__ dw1,
    const float* __restrict__ db1, const float* __restrict__ dw2,
    const float* __restrict__ db2, const int* __restrict__ dptr,
    short* __restrict__ qkvp, short* __restrict__ pwp,
    short* __restrict__ w1p, short* __restrict__ w2p,
    float* __restrict__ qbp, float* __restrict__ f1bp,
    float* __restrict__ da) {
    __shared__ float sh[1536];
    int bb = blockIdx.x;
    int tid = threadIdx.x;
    int d = *dptr;
    if (bb < 24) {
        int idx = bb * 256 + tid;
        int l = idx & 63, kk = (idx >> 6) & 3, n = idx >> 8;
        int k0 = kk * 32 + (l >> 4) * 8;
        int c = n * 16 + (l & 15);
        bf16x8 v;
        #pragma unroll
        for (int j = 0; j < 8; ++j)
            v[j] = f2bf(n1_g[d * 128 + k0 + j] * qkv_w[(size_t)(k0 + j) * 384 + c]);
        *(bf16x8*)&qkvp[(size_t)idx * 8] = v;
    } else if (bb < 32) {
        int idx = (bb - 24) * 256 + tid;
        int l = idx & 63, kk = (idx >> 6) & 3, n = idx >> 8;
        int k0 = kk * 32 + (l >> 4) * 8;
        int c = n * 16 + (l & 15);
        bf16x8 v;
        #pragma unroll
        for (int j = 0; j < 8; ++j) v[j] = f2bf(pw[(size_t)(k0 + j) * 128 + c]);
        *(bf16x8*)&pwp[(size_t)idx * 8] = v;
    } else if (bb < 96) {
        int idx = (bb - 32) * 256 + tid;
        int l = idx & 63, kk = (idx >> 6) & 3, n = idx >> 8;
        int k0 = kk * 32 + (l >> 4) * 8;
        int c = n * 16 + (l & 15);
        bf16x8 v;
        #pragma unroll
        for (int j = 0; j < 8; ++j)
            v[j] = f2bf(n2_g[d * 128 + k0 + j] * f1w[(size_t)(k0 + j) * 1024 + c]);
        *(bf16x8*)&w1p[(size_t)idx * 8] = v;
    } else if (bb < 160) {
        int idx = (bb - 96) * 256 + tid;
        int l = idx & 63, kk = (idx >> 6) & 31, n = idx >> 11;
        int k0 = kk * 32 + (l >> 4) * 8;
        int c = n * 16 + (l & 15);
        bf16x8 v;
        #pragma unroll
        for (int j = 0; j < 8; ++j) v[j] = f2bf(f2w[(size_t)(k0 + j) * 128 + c]);
        *(bf16x8*)&w2p[(size_t)idx * 8] = v;
    } else if (bb < 162) {
        int j = (bb - 160) * 256 + tid;
        if (j < 384) {
            float s = qkv_b[j];
            for (int k = 0; k < 128; ++k)
                s += n1_b[d * 128 + k] * qkv_w[(size_t)k * 384 + j];
            qbp[j] = s;
        }
    } else if (bb < 166) {
        int j = (bb - 162) * 256 + tid;
        float s = f1b[j];
        for (int k = 0; k < 128; ++k)
            s += n2_b[d * 128 + k] * f1w[(size_t)k * 1024 + j];
        f1bp[j] = s;
    } else {
        float* hid = sh;          // 512
        float* raw = sh + 512;    // 1024
        for (int idx = tid; idx < 512; idx += 256) {
            int b = idx >> 6, jj = idx & 63;
            float a = db1[jj];
            #pragma unroll
            for (int dd = 0; dd < 4; ++dd)
                a += dl[b * 4 + dd] * dw1[dd * 64 + jj];
            hid[idx] = fmaxf(a, 0.f);
        }
        __syncthreads();
        for (int idx = tid; idx < 1024; idx += 256) {
            int b = idx >> 7, c = idx & 127;
            float a = db2[c];
            for (int jj = 0; jj < 64; ++jj)
                a += hid[b * 64 + jj] * dw2[jj * 128 + c];
            raw[idx] = a;
        }
        __syncthreads();
        if (tid < 128) {
            int b = tid >> 4, ch = tid & 15;
            float mx = -1e30f;
            #pragma unroll
            for (int hh = 0; hh < 8; ++hh)
                mx = fmaxf(mx, raw[b * 128 + hh * 16 + ch]);
            float e[8];
            float s = 0.f;
            #pragma unroll
            for (int hh = 0; hh < 8; ++hh) {
                e[hh] = expf(raw[b * 128 + hh * 16 + ch] - mx);
                s += e[hh];
            }
            float inv = 1.f / s;
            #pragma unroll
            for (int hh = 0; hh < 8; ++hh)
                da[b * 128 + hh * 16 + ch] = e[hh] * inv;
        }
    }
}

// ---------------- MFMA QKV (LN1 fused): 512 thr, 8 waves, wave-split tt ----
__global__ __launch_bounds__(512, 4) void qkv_mfma_kernel(
    const float* __restrict__ x, const short* __restrict__ wp,
    const float* __restrict__ biasp, float* __restrict__ q_img,
    float* __restrict__ k_img, float* __restrict__ v_img) {
    int tb = blockIdx.x * 32;
    int tid = threadIdx.x;
    int lane = tid & 63, wv = tid >> 6;
    int tt = wv & 1, g = wv >> 1;
    int lhi = lane >> 4, llo = lane & 15;
    int b = tb >> 12, n0 = tb & 4095;

    bf16x8 afr[4];
    {
        f32x4 v0[4], v1[4];
        float sum = 0.f;
        #pragma unroll
        for (int kk = 0; kk < 4; ++kk) {
            const float* p = x + (size_t)(tb + tt * 16 + llo) * 128 + kk * 32 + lhi * 8;
            v0[kk] = *(const f32x4*)p;
            v1[kk] = *(const f32x4*)(p + 4);
            sum += v0[kk].x + v0[kk].y + v0[kk].z + v0[kk].w
                 + v1[kk].x + v1[kk].y + v1[kk].z + v1[kk].w;
        }
        sum += __shfl_xor(sum, 16, 64);
        sum += __shfl_xor(sum, 32, 64);
        float mean = sum * (1.f / 128.f);
        float vs = 0.f;
        #pragma unroll
        for (int kk = 0; kk < 4; ++kk) {
            f32x4 a = v0[kk], c = v1[kk];
            float d0 = a.x - mean, d1 = a.y - mean, d2 = a.z - mean, d3 = a.w - mean;
            float d4 = c.x - mean, d5 = c.y - mean, d6 = c.z - mean, d7 = c.w - mean;
            vs += d0*d0 + d1*d1 + d2*d2 + d3*d3 + d4*d4 + d5*d5 + d6*d6 + d7*d7;
        }
        vs += __shfl_xor(vs, 16, 64);
        vs += __shfl_xor(vs, 32, 64);
        float rs = rsqrtf(vs * (1.f / 128.f) + EPS_LN);
        #pragma unroll
        for (int kk = 0; kk < 4; ++kk) {
            bf16x8 o;
            o[0] = f2bf((v0[kk].x - mean) * rs);
            o[1] = f2bf((v0[kk].y - mean) * rs);
            o[2] = f2bf((v0[kk].z - mean) * rs);
            o[3] = f2bf((v0[kk].w - mean) * rs);
            o[4] = f2bf((v1[kk].x - mean) * rs);
            o[5] = f2bf((v1[kk].y - mean) * rs);
            o[6] = f2bf((v1[kk].z - mean) * rs);
            o[7] = f2bf((v1[kk].w - mean) * rs);
            afr[kk] = o;
        }
    }

    f32x4 acc[6];
    f32x4 zr = {0.f, 0.f, 0.f, 0.f};
    #pragma unroll
    for (int i = 0; i < 6; ++i) acc[i] = zr;

    #pragma unroll
    for (int i = 0; i < 6; ++i) {
        int nb = g * 6 + i;
        #pragma unroll
        for (int kk = 0; kk < 4; ++kk) {
            bf16x8 wf = *(const bf16x8*)&wp[((size_t)(nb * 4 + kk) * 64 + lane) * 8];
            acc[i] = __builtin_amdgcn_mfma_f32_16x16x32_bf16(wf, afr[kk], acc[i], 0, 0, 0);
        }
    }

    #pragma unroll
    for (int i = 0; i < 6; ++i) {
        int j0 = (g * 6 + i) * 16;
        f32x4 bv = *(const f32x4*)(biasp + j0 + lhi * 4);
        float* dst = (j0 < 128) ? q_img : ((j0 < 256) ? k_img : v_img);
        int c0 = (j0 & 127) + lhi * 4;
        f32x4 r = acc[i] + bv;
        float* p = dst + (size_t)(b * 128 + c0) * 4096 + n0 + tt * 16 + llo;
        p[0]        = r.x;
        p[4096]     = r.y;
        p[2 * 4096] = r.z;
        p[3 * 4096] = r.w;
    }
}

// ---------------- softmax over N ---------------
__global__ __launch_bounds__(256) void softmax_kernel(float* __restrict__ k_img) {
    __shared__ float red[4];
    float* p = k_img + (size_t)blockIdx.x * 4096;
    int tid = threadIdx.x;
    float v[16];
    float mx = -1e30f;
    #pragma unroll
    for (int i = 0; i < 16; ++i) {
        v[i] = p[tid + i * 256];
        mx = fmaxf(mx, v[i]);
    }
    mx = wave_reduce_max(mx);
    int wid = tid >> 6, lane = tid & 63;
    if (lane == 0) red[wid] = mx;
    __syncthreads();
    mx = fmaxf(fmaxf(red[0], red[1]), fmaxf(red[2], red[3]));
    __syncthreads();
    float sum = 0.f;
    #pragma unroll
    for (int i = 0; i < 16; ++i) {
        v[i] = expf(v[i] - mx);
        sum += v[i];
    }
    sum = wave_reduce_sum(sum);
    if (lane == 0) red[wid] = sum;
    __syncthreads();
    float inv = 1.f / (red[0] + red[1] + red[2] + red[3]);
    #pragma unroll
    for (int i = 0; i < 16; ++i)
        p[tid + i * 256] = v[i] * inv;
}

// ---------------- kv partial: grid 512 = bh*8+chunk, n-chunk of 512 --------
__global__ __launch_bounds__(256) void kv_part_kernel(
    const float* __restrict__ k_img, const float* __restrict__ v_img,
    float* __restrict__ kvp) {
    __shared__ float ks[16 * 132], vs[16 * 132];
    int bc = blockIdx.x;
    int bh = bc >> 3, chunk = bc & 7;
    int b = bh >> 3, h = bh & 7;
    int tid = threadIdx.x;
    int ck = tid >> 4, cv = tid & 15;
    float acc = 0.f;
    const float* kp = k_img + (size_t)(b * 128 + h * 16) * 4096;
    const float* vp = v_img + (size_t)(b * 128 + h * 16) * 4096;
    int nb0 = chunk * 512;
    for (int nb = nb0; nb < nb0 + 512; nb += 128) {
        for (int idx = tid; idx < 2048; idx += 256) {
            int r = idx >> 7, col = idx & 127;
            ks[r * 132 + col] = kp[(size_t)r * 4096 + nb + col];
            vs[r * 132 + col] = vp[(size_t)r * 4096 + nb + col];
        }
        __syncthreads();
        for (int kk = 0; kk < 128; ++kk)
            acc += ks[ck * 132 + kk] * vs[cv * 132 + kk];
        __syncthreads();
    }
    kvp[(size_t)(chunk * 64 + bh) * 256 + ck * 16 + cv] = acc;
}

// ---------------- fa (with inline kvp reduce) ------------------------------
__global__ __launch_bounds__(256) void fa_kernel(
    const float* __restrict__ q_img, const float* __restrict__ kvp,
    float* __restrict__ fa_img) {
    __shared__ float kvs[256];
    int bid = blockIdx.x;
    int bh = bid >> 4, chunk = bid & 15;
    int b = bh >> 3, h = bh & 7;
    int tid = threadIdx.x;
    {
        float s = 0.f;
        #pragma unroll
        for (int c = 0; c < 8; ++c) s += kvp[(size_t)c * 16384 + bh * 256 + tid];
        kvs[tid] = s;
    }
    __syncthreads();
    int n = chunk * 256 + tid;
    const float* qp = q_img + (size_t)(b * 128 + h * 16) * 4096 + n;
    float qv[16];
    #pragma unroll
    for (int ck = 0; ck < 16; ++ck) qv[ck] = qp[(size_t)ck * 4096];
    float* fp = fa_img + (size_t)(b * 128 + h * 16) * 4096 + n;
    #pragma unroll
    for (int cv = 0; cv < 16; ++cv) {
        float s = 0.f;
        #pragma unroll
        for (int ck = 0; ck < 16; ++ck) s += qv[ck] * kvs[ck * 16 + cv];
        fp[(size_t)cv * 4096] = s;
    }
}

// ---------------- conv helper: 4 outputs, compile-time KC (rule #20) -------
template<int KC>
__device__ __forceinline__ void conv4(const float* __restrict__ s,
                                      const float* __restrict__ wsm,
                                      int y, int xx0, float* a4) {
    const int OFF = KC / 2;
    #pragma unroll
    for (int dy = 0; dy < KC; ++dy) {
        int sy = y + dy - OFF;
        if (sy < 0 || sy >= 64) continue;
        const float* r = s + sy * 72;
        float u[12];
        *(f32x4*)&u[0] = *(const f32x4*)&r[xx0];
        *(f32x4*)&u[4] = *(const f32x4*)&r[xx0 + 4];
        *(f32x4*)&u[8] = *(const f32x4*)&r[xx0 + 8];
        #pragma unroll
        for (int dx = 0; dx < KC; ++dx) {
            float w = wsm[dy * KC + dx];
            const int base = dx - OFF + 4;
            a4[0] += u[base + 0] * w;
            a4[1] += u[base + 1] * w;
            a4[2] += u[base + 2] * w;
            a4[3] += u[base + 3] * w;
        }
    }
}

// ---------------- crpe conv + combine (fa precomputed) ---------------------
__global__ __launch_bounds__(256) void att_kernel(
    const float* __restrict__ q_img, const float* __restrict__ v_img,
    const float* __restrict__ fa_img, const float* __restrict__ da,
    const float* __restrict__ w3, const float* __restrict__ b3,
    const float* __restrict__ w5, const float* __restrict__ b5,
    const float* __restrict__ w7, const float* __restrict__ b7,
    float* __restrict__ att) {
    __shared__ float s[64 * 72];
    __shared__ float wsm[49];
    int o = ((blockIdx.x & 7) << 7) | (blockIdx.x >> 3);
    int b = o >> 7, c = o & 127;
    int tid = threadIdx.x;
    const float* vp = v_img + (size_t)(b * 128 + c) * 4096;
    for (int idx = tid; idx < 4096; idx += 256) {
        int row = idx >> 6, xx = idx & 63;
        s[row * 72 + xx + 4] = vp[idx];
    }
    for (int idx = tid; idx < 512; idx += 256) {
        int row = idx >> 3, j = idx & 7;
        s[row * 72 + (j < 4 ? j : 64 + j)] = 0.f;
    }
    int kc; const float* wp; float bias;
    if (c < 32)      { kc = 3; wp = w3 + c * 9;         bias = b3[c]; }
    else if (c < 80) { kc = 5; wp = w5 + (c - 32) * 25; bias = b5[c - 32]; }
    else             { kc = 7; wp = w7 + (c - 80) * 49; bias = b7[c - 80]; }
    if (tid < kc * kc) wsm[tid] = wp[tid];
    float dac = da[b * 128 + c];
    size_t rowbase = (size_t)(b * 128 + c) * 4096;
    __syncthreads();
    for (int it = 0; it < 4; ++it) {
        int task = tid + it * 256;
        int y = task >> 4, xx0 = (task & 15) * 4;
        float a4[4] = {bias, bias, bias, bias};
        if (kc == 3)      conv4<3>(s, wsm, y, xx0, a4);
        else if (kc == 5) conv4<5>(s, wsm, y, xx0, a4);
        else              conv4<7>(s, wsm, y, xx0, a4);
        size_t base = rowbase + y * 64 + xx0;
        f32x4 fav = *(const f32x4*)&fa_img[base];
        f32x4 qv  = *(const f32x4*)&q_img[base];
        f32x4 cv4 = {a4[0], a4[1], a4[2], a4[3]};
        f32x4 r = (fav * 0.25f + qv * cv4) * dac;
        *(f32x4*)&att[base] = r;
    }
}

// ---------------- MFMA proj + residual: A = att (image layout) -------------
__global__ __launch_bounds__(256, 2) void proj_mfma_kernel(
    const float* __restrict__ att, const short* __restrict__ wp,
    const float* __restrict__ bias, const float* __restrict__ xres,
    float* __restrict__ out) {
    __shared__ float As[128 * 33];
    int tb = blockIdx.x * 32;
    int tid = threadIdx.x;
    int lane = tid & 63, wv = tid >> 6;
    int lhi = lane >> 4, llo = lane & 15;
    int b = tb >> 12, n0 = tb & 4095;

    for (int idx = tid; idx < 4096; idx += 256) {
        int c = idx >> 5, t = idx & 31;
        As[c * 33 + t] = att[(size_t)(b * 128 + c) * 4096 + n0 + t];
    }
    __syncthreads();

    bf16x8 afr[2][4];
    #pragma unroll
    for (int tt = 0; tt < 2; ++tt) {
        #pragma unroll
        for (int kk = 0; kk < 4; ++kk) {
            int c0 = kk * 32 + lhi * 8;
            int t = tt * 16 + llo;
            bf16x8 v;
            #pragma unroll
            for (int j = 0; j < 8; ++j) v[j] = f2bf(As[(c0 + j) * 33 + t]);
            afr[tt][kk] = v;
        }
    }

    f32x4 acc[2][2];
    f32x4 zr = {0.f, 0.f, 0.f, 0.f};
    #pragma unroll
    for (int i = 0; i < 2; ++i) { acc[i][0] = zr; acc[i][1] = zr; }

    #pragma unroll
    for (int i = 0; i < 2; ++i) {
        int nb = wv * 2 + i;
        #pragma unroll
        for (int kk = 0; kk < 4; ++kk) {
            bf16x8 wf = *(const bf16x8*)&wp[((size_t)(nb * 4 + kk) * 64 + lane) * 8];
            acc[i][0] = __builtin_amdgcn_mfma_f32_16x16x32_bf16(wf, afr[0][kk], acc[i][0], 0, 0, 0);
            acc[i][1] = __builtin_amdgcn_mfma_f32_16x16x32_bf16(wf, afr[1][kk], acc[i][1], 0, 0, 0);
        }
    }

    #pragma unroll
    for (int i = 0; i < 2; ++i) {
        int j0 = (wv * 2 + i) * 16;
        f32x4 bv = *(const f32x4*)(bias + j0 + lhi * 4);
        #pragma unroll
        for (int tt = 0; tt < 2; ++tt) {
            size_t o = (size_t)(tb + tt * 16 + llo) * 128 + j0 + lhi * 4;
            f32x4 xr = *(const f32x4*)(xres + o);
            *(f32x4*)(out + o) = xr + acc[i][tt] + bv;
        }
    }
}

// ---------------- fused MFMA MLP (LN2 fused): 512 thr, 8 waves -------------
// GEMM1: wave wv owns hn = wv*8..wv*8+7, BOTH token halves (weight frag
// loaded once -> 2 MFMA; halves L2 weight traffic vs 1-tt split).
// GEMM2: wave wv -> cout block wv, both halves. nl loops fully unrolled
// (rule #20 — runtime-indexed acc spills to scratch).
__global__ __launch_bounds__(512, 3) void mlp_mfma_kernel(
    const short* __restrict__ w1p, const float* __restrict__ b1p,
    const short* __restrict__ w2p, const float* __restrict__ b2,
    float* io) {
    __shared__ short hs[32768];
    int tb = blockIdx.x * 32;
    int tid = threadIdx.x;
    int lane = tid & 63, wv = tid >> 6;
    int lhi = lane >> 4, llo = lane & 15;

    bf16x8 afr[2][4];
    #pragma unroll
    for (int tt = 0; tt < 2; ++tt) {
        f32x4 v0[4], v1[4];
        float sum = 0.f;
        #pragma unroll
        for (int kk = 0; kk < 4; ++kk) {
            const float* p = io + (size_t)(tb + tt * 16 + llo) * 128 + kk * 32 + lhi * 8;
            v0[kk] = *(const f32x4*)p;
            v1[kk] = *(const f32x4*)(p + 4);
            sum += v0[kk].x + v0[kk].y + v0[kk].z + v0[kk].w
                 + v1[kk].x + v1[kk].y + v1[kk].z + v1[kk].w;
        }
        sum += __shfl_xor(sum, 16, 64);
        sum += __shfl_xor(sum, 32, 64);
        float mean = sum * (1.f / 128.f);
        float vs = 0.f;
        #pragma unroll
        for (int kk = 0; kk < 4; ++kk) {
            f32x4 a = v0[kk], c = v1[kk];
            float d0 = a.x - mean, d1 = a.y - mean, d2 = a.z - mean, d3 = a.w - mean;
            float d4 = c.x - mean, d5 = c.y - mean, d6 = c.z - mean, d7 = c.w - mean;
            vs += d0*d0 + d1*d1 + d2*d2 + d3*d3 + d4*d4 + d5*d5 + d6*d6 + d7*d7;
        }
        vs += __shfl_xor(vs, 16, 64);
        vs += __shfl_xor(vs, 32, 64);
        float rs = rsqrtf(vs * (1.f / 128.f) + EPS_LN);
        #pragma unroll
        for (int kk = 0; kk < 4; ++kk) {
            bf16x8 o;
            o[0] = f2bf((v0[kk].x - mean) * rs);
            o[1] = f2bf((v0[kk].y - mean) * rs);
            o[2] = f2bf((v0[kk].z - mean) * rs);
            o[3] = f2bf((v0[kk].w - mean) * rs);
            o[4] = f2bf((v1[kk].x - mean) * rs);
            o[5] = f2bf((v1[kk].y - mean) * rs);
            o[6] = f2bf((v1[kk].z - mean) * rs);
            o[7] = f2bf((v1[kk].w - mean) * rs);
            afr[tt][kk] = o;
        }
    }

    f32x4 acc[2][8];
    f32x4 zr = {0.f, 0.f, 0.f, 0.f};
    #pragma unroll
    for (int tt = 0; tt < 2; ++tt)
        #pragma unroll
        for (int nl = 0; nl < 8; ++nl) acc[tt][nl] = zr;

    const short* wbase = w1p + (size_t)(wv * 8) * 4 * 64 * 8;
    #pragma unroll
    for (int nl = 0; nl < 8; ++nl) {
        #pragma unroll
        for (int kk = 0; kk < 4; ++kk) {
            bf16x8 bf = *(const bf16x8*)(wbase + ((size_t)(nl * 4 + kk) * 64 + lane) * 8);
            acc[0][nl] = __builtin_amdgcn_mfma_f32_16x16x32_bf16(bf, afr[0][kk], acc[0][nl], 0, 0, 0);
            acc[1][nl] = __builtin_amdgcn_mfma_f32_16x16x32_bf16(bf, afr[1][kk], acc[1][nl], 0, 0, 0);
        }
    }

    #pragma unroll
    for (int nl = 0; nl < 8; ++nl) {
        int hn = wv * 8 + nl;
        int hc0 = hn * 16 + lhi * 4;
        f32x4 bv = *(const f32x4*)(b1p + hc0);
        int kk2 = hn >> 1;
        int lp = llo + 16 * ((hn & 1) * 2 + (lhi >> 1));
        #pragma unroll
        for (int tt = 0; tt < 2; ++tt) {
            f32x4 a = acc[tt][nl] + bv;
            uint2 wv2;
            wv2.x = pack2bf(gelu_f(a.x), gelu_f(a.y));
            wv2.y = pack2bf(gelu_f(a.z), gelu_f(a.w));
            *(uint2*)((char*)hs + ((size_t)(tt * 32 + kk2) * 64 + lp) * 16 + (lhi & 1) * 8) = wv2;
        }
    }
    __syncthreads();

    f32x4 acc2[2];
    acc2[0] = zr; acc2[1] = zr;

    const short* w2base = w2p + (size_t)wv * 32 * 64 * 8;
    #pragma unroll 4
    for (int kk2 = 0; kk2 < 32; ++kk2) {
        bf16x8 h0 = *(const bf16x8*)&hs[((size_t)(0 * 32 + kk2) * 64 + lane) * 8];
        bf16x8 h1 = *(const bf16x8*)&hs[((size_t)(1 * 32 + kk2) * 64 + lane) * 8];
        bf16x8 w0 = *(const bf16x8*)(w2base + ((size_t)kk2 * 64 + lane) * 8);
        acc2[0] = __builtin_amdgcn_mfma_f32_16x16x32_bf16(w0, h0, acc2[0], 0, 0, 0);
        acc2[1] = __builtin_amdgcn_mfma_f32_16x16x32_bf16(w0, h1, acc2[1], 0, 0, 0);
    }

    int c0 = wv * 16 + lhi * 4;
    f32x4 bv = *(const f32x4*)(b2 + c0);
    #pragma unroll
    for (int tt2 = 0; tt2 < 2; ++tt2) {
        float* op = io + (size_t)(tb + tt2 * 16 + llo) * 128 + c0;
        f32x4 r = *(f32x4*)op;
        r = r + acc2[tt2] + bv;
        *(f32x4*)op = r;
    }
}

extern "C" void kernel_launch(void* const* d_in, const int* in_sizes, int n_in,
                              void* d_out, int out_size, void* d_ws, size_t ws_size,
                              hipStream_t stream) {
    const float* img   = (const float*)d_in[0];
    const float* dl    = (const float*)d_in[1];
    const float* pe_dw = (const float*)d_in[2];
    const float* pe_pw = (const float*)d_in[3];
    const float* bn_g  = (const float*)d_in[4];
    const float* bn_b  = (const float*)d_in[5];
    const float* bn_m  = (const float*)d_in[6];
    const float* bn_v  = (const float*)d_in[7];
    const float* cpe_w = (const float*)d_in[8];
    const float* cpe_b = (const float*)d_in[9];
    const float* n1_g  = (const float*)d_in[10];
    const float* n1_b  = (const float*)d_in[11];
    const float* qkv_w = (const float*)d_in[12];
    const float* qkv_b = (const float*)d_in[13];
    const float* w3    = (const float*)d_in[14];
    const float* b3    = (const float*)d_in[15];
    const float* w5    = (const float*)d_in[16];
    const float* b5    = (const float*)d_in[17];
    const float* w7    = (const float*)d_in[18];
    const float* b7    = (const float*)d_in[19];
    const float* dw1   = (const float*)d_in[20];
    const float* db1   = (const float*)d_in[21];
    const float* dw2   = (const float*)d_in[22];
    const float* db2   = (const float*)d_in[23];
    const float* pw    = (const float*)d_in[24];
    const float* pb    = (const float*)d_in[25];
    const float* n2_g  = (const float*)d_in[26];
    const float* n2_b  = (const float*)d_in[27];
    const float* f1w   = (const float*)d_in[28];
    const float* f1b   = (const float*)d_in[29];
    const float* f2w   = (const float*)d_in[30];
    const float* f2b   = (const float*)d_in[31];
    const int*   dptr  = (const int*)d_in[32];
    float* out = (float*)d_out;

    char* ws = (char*)d_ws;
    const size_t SZ = (size_t)8 * 128 * 4096 * 4;   // 16,777,216 bytes
    float* t1    = (float*)(ws);            // pe out; dead after cpe -> fa_img
    float* x     = (float*)(ws + SZ);       // residual stream after cpe
    float* q_img = (float*)(ws + 2 * SZ);
    float* k_img = (float*)(ws + 3 * SZ);   // att output after kv
    float* v_img = (float*)(ws + 4 * SZ);
    float* da    = (float*)(ws + 5 * SZ + 0x10000);        // 4KB
    short* qkvp  = (short*)(ws + 5 * SZ + 0x20000);        // 96KB
    short* pwp   = (short*)(ws + 5 * SZ + 0x40000);        // 32KB
    float* qbp   = (float*)(ws + 5 * SZ + 0x48000);        // folded qkv bias
    float* f1bp  = (float*)(ws + 5 * SZ + 0x4A000);        // folded fc1 bias
    float* kvp   = (float*)(ws + 5 * SZ + 0x50000);        // 512KB -> 0xD0000
    short* w1p   = (short*)(ws + 5 * SZ + 0xD0000);        // 256KB
    short* w2p   = (short*)(ws + 5 * SZ + 0x110000);       // 256KB -> 0x150000
    float* fa_img = t1;                                    // reuse dead t1

    prep_kernel<<<167, 256, 0, stream>>>(qkv_w, n1_g, n1_b, qkv_b, pw, f1w,
                                         n2_g, n2_b, f1b, f2w, dl, dw1, db1,
                                         dw2, db2, dptr, qkvp, pwp, w1p, w2p,
                                         qbp, f1bp, da);
    pe_kernel<<<512, 256, 0, stream>>>(img, pe_dw, pe_pw, bn_g, bn_b, bn_m, bn_v, dptr, t1);
    cpe_kernel<<<2048, 256, 0, stream>>>(t1, cpe_w, cpe_b, x);
    qkv_mfma_kernel<<<1024, 512, 0, stream>>>(x, qkvp, qbp, q_img, k_img, v_img);
    softmax_kernel<<<1024, 256, 0, stream>>>(k_img);
    kv_part_kernel<<<512, 256, 0, stream>>>(k_img, v_img, kvp);
    fa_kernel<<<1024, 256, 0, stream>>>(q_img, kvp, fa_img);
    att_kernel<<<1024, 256, 0, stream>>>(q_img, v_img, fa_img, da, w3, b3, w5, b5, w7, b7, k_img);
    proj_mfma_kernel<<<1024, 256, 0, stream>>>(k_img, pwp, pb, x, out);
    mlp_mfma_kernel<<<1024, 512, 0, stream>>>(w1p, f1bp, w2p, f2b, out);
}